// Round 8
// baseline (263.886 us; speedup 1.0000x reference)
//
#include <hip/hip_runtime.h>
#include <math.h>

// ---------------------------------------------------------------------------
// EncoderLayer: B=2,S=2048,D=768,H=12,DK=64,DFF=3072
// bf16 MFMA (16x16x32) for all matmuls, fp32 accumulate + fp32 pointwise.
// ---------------------------------------------------------------------------

using bf16   = __bf16;
using bf16x8 = __attribute__((ext_vector_type(8))) __bf16;
using bf16x4 = __attribute__((ext_vector_type(4))) __bf16;
using f32x4  = __attribute__((ext_vector_type(4))) float;

constexpr int S_   = 2048;
constexpr int D_   = 768;
constexpr int DFF_ = 3072;
constexpr int M_   = 4096;   // B*S
constexpr int BH_  = 24;     // B*H

__device__ __forceinline__ f32x4 mfma16(bf16x8 a, bf16x8 b, f32x4 c) {
    return __builtin_amdgcn_mfma_f32_16x16x32_bf16(a, b, c, 0, 0, 0);
}

// async global->LDS, 16B per lane; LDS dest wave-uniform, lane fills base+l*16
__device__ __forceinline__ void gload16(const bf16* g, bf16* l) {
    __builtin_amdgcn_global_load_lds(
        (const __attribute__((address_space(1))) void*)g,
        (__attribute__((address_space(3))) void*)l, 16, 0, 0);
}

template<int N> __device__ __forceinline__ void wait_vmcnt() {
    if constexpr (N == 0)      asm volatile("s_waitcnt vmcnt(0)" ::: "memory");
    else if constexpr (N == 4) asm volatile("s_waitcnt vmcnt(4)" ::: "memory");
    else if constexpr (N == 8) asm volatile("s_waitcnt vmcnt(8)" ::: "memory");
    else static_assert(N == 0, "unsupported vmcnt");
}
__device__ __forceinline__ void wait_lgkm0() {
    asm volatile("s_waitcnt lgkmcnt(0)" ::: "memory");
}

// bijective XCD-cluster swizzle; valid when nwg % 8 == 0
__device__ __forceinline__ int xcd_swz(int orig, int nwg) {
    return (orig & 7) * (nwg >> 3) + (orig >> 3);
}

// ---------------------------------------------------------------------------
// pack x (fp32 -> bf16), 4 elems/thread
// ---------------------------------------------------------------------------
__global__ __launch_bounds__(256)
void pack_x_kernel(const float* __restrict__ x, bf16* __restrict__ xb) {
    const int i = blockIdx.x * 256 + threadIdx.x;
    float4 v = ((const float4*)x)[i];
    bf16x4 o;
    o[0] = (bf16)v.x; o[1] = (bf16)v.y; o[2] = (bf16)v.z; o[3] = (bf16)v.w;
    ((bf16x4*)xb)[i] = o;
}

// ---------------------------------------------------------------------------
// ALL weight transposes in one launch: in [K][N] fp32 -> out [N][K] bf16.
// 64x64 tiles, flat block index -> (matrix, tile).
// ---------------------------------------------------------------------------
__global__ __launch_bounds__(256)
void wt_all_kernel(const float* __restrict__ Wq, const float* __restrict__ Wk,
                   const float* __restrict__ Wv, const float* __restrict__ Wo,
                   const float* __restrict__ W1, const float* __restrict__ W2,
                   bf16* __restrict__ Wqkvt, bf16* __restrict__ Wot,
                   bf16* __restrict__ W1t, bf16* __restrict__ W2t) {
    int bid = blockIdx.x;
    const float* in; bf16* out; int K, N, t;
    if (bid < 576) {                       // Wq/Wk/Wv/Wo: 144 tiles each
        int m = bid / 144; t = bid % 144; K = 768; N = 768;
        in  = (m == 0) ? Wq : (m == 1) ? Wk : (m == 2) ? Wv : Wo;
        out = (m == 3) ? Wot : Wqkvt + (size_t)m * 768 * 768;
    } else if (bid < 1152) {               // W1: [768][3072] -> [3072][768]
        t = bid - 576; K = 768; N = 3072; in = W1; out = W1t;
    } else {                               // W2: [3072][768] -> [768][3072]
        t = bid - 1152; K = 3072; N = 768; in = W2; out = W2t;
    }
    const int ntx = N / 64;
    const int n0 = (t % ntx) * 64, k0 = (t / ntx) * 64;

    __shared__ __align__(16) bf16 T[64][72];
    const int tt = threadIdx.x;
    const int r  = tt >> 2, c0 = (tt & 3) * 16;
    const float* src = in + (size_t)(k0 + r) * N + n0 + c0;
#pragma unroll
    for (int j = 0; j < 16; j += 4) {
        float4 v = *(const float4*)(src + j);
        T[r][c0 + j + 0] = (bf16)v.x;
        T[r][c0 + j + 1] = (bf16)v.y;
        T[r][c0 + j + 2] = (bf16)v.z;
        T[r][c0 + j + 3] = (bf16)v.w;
    }
    __syncthreads();
    bf16x8 o0, o1;
#pragma unroll
    for (int j = 0; j < 8; j++) { o0[j] = T[c0 + j][r]; o1[j] = T[c0 + 8 + j][r]; }
    bf16* dst = out + (size_t)(n0 + r) * K + k0 + c0;
    *(bf16x8*)(dst)     = o0;
    *(bf16x8*)(dst + 8) = o1;
}

// ---------------------------------------------------------------------------
// GEMM: C = A[M,K] @ Bt[N,K]^T, BMxBN tile, BK=64, 4 waves in WRxWC grid.
// Staging: global_load_lds (async 16B) with pre-swizzled global source ->
// fragment-major LDS (one gload16 = one 1KB MFMA fragment); fragment reads
// are frag*1024B + lane*16B -> zero bank conflicts both sides.
// COUNTED-VMCNT deep pipeline (T3+T4): double-buffered LDS, tiles t and t+1
// in flight; per step: s_waitcnt vmcnt(NPT) [tile t landed, t+1 still
// flying] -> s_barrier -> compute(t) -> lgkmcnt(0)+s_barrier -> restage
// buffer with tile t+2. vmcnt never drains to 0 until the peeled last tile.
// 1D grid + bijective XCD swizzle (same-A-panel blocks share an XCD L2).
// EPI: 0=QKV (+bias, fused Q/K row-L2-norm, V written transposed),
//      1=Wo(+bias+fp32 resid)->bf16, 2=FFN1 gelu->bf16,
//      3=FFN2(+bias+bf16 resid)->bf16
// ---------------------------------------------------------------------------
template<int EPI, int K, int BM, int BN, int WR, int WC>
__global__ __launch_bounds__(256)
void gemm_bt(const bf16* __restrict__ A, const bf16* __restrict__ Bt,
             const float* __restrict__ bias0, const float* __restrict__ bias1,
             const float* __restrict__ bias2, const float* __restrict__ residf,
             const bf16* __restrict__ residb, bf16* __restrict__ outb,
             bf16* __restrict__ qo, bf16* __restrict__ ko, bf16* __restrict__ vo) {
    constexpr int MR = BM / WR / 16;
    constexpr int NR = BN / WC / 16;
    constexpr int FA = (BM / 16) * 2;   // 1KB fragments per K-tile of A
    constexpr int FB = (BN / 16) * 2;
    constexpr int NPT = FA / 4 + FB / 4; // this wave's gloads per tile
    constexpr int NCOL = (EPI == 0) ? 2304 : (EPI == 2) ? 3072 : 768;
    constexpr int NBX  = NCOL / BN;
    __shared__ __align__(16) bf16 Al[2 * FA * 512];
    __shared__ __align__(16) bf16 Bl[2 * FB * 512];
    const int tid  = threadIdx.x;
    const int lane = tid & 63, w = tid >> 6;
    const int wr = w / WC, wc = w % WC;
    const int wg = xcd_swz(blockIdx.x, gridDim.x);
    const int m0 = (wg / NBX) * BM, n0 = (wg % NBX) * BN;
    const int g = lane >> 4, q = lane & 15;

    f32x4 acc[MR][NR] = {};

    // per-lane swizzled global base: row += q, col += g*8
    const bf16* gaA = A  + (long)(m0 + q) * K + g * 8;
    const bf16* gaB = Bt + (long)(n0 + q) * K + g * 8;

    auto stage = [&](int buf, int kt) {
#pragma unroll
        for (int fi = 0; fi < FA; fi++)
            if ((fi & 3) == w)
                gload16(gaA + (long)(fi >> 1) * 16 * K + kt + (fi & 1) * 32,
                        &Al[buf * FA * 512 + fi * 512]);
#pragma unroll
        for (int fi = 0; fi < FB; fi++)
            if ((fi & 3) == w)
                gload16(gaB + (long)(fi >> 1) * 16 * K + kt + (fi & 1) * 32,
                        &Bl[buf * FB * 512 + fi * 512]);
    };
    auto compute = [&](int buf) {
#pragma unroll
        for (int c = 0; c < 2; c++) {
            bf16x8 af[MR], bfr[NR];
#pragma unroll
            for (int i = 0; i < MR; i++)
                af[i] = *(const bf16x8*)
                    &Al[buf * FA * 512 + ((((wr * (BM / WR)) >> 4) + i) * 2 + c) * 512 + lane * 8];
#pragma unroll
            for (int i = 0; i < NR; i++)
                bfr[i] = *(const bf16x8*)
                    &Bl[buf * FB * 512 + ((((wc * (BN / WC)) >> 4) + i) * 2 + c) * 512 + lane * 8];
#pragma unroll
            for (int mi = 0; mi < MR; mi++)
#pragma unroll
                for (int ni = 0; ni < NR; ni++)
                    acc[mi][ni] = mfma16(af[mi], bfr[ni], acc[mi][ni]);
        }
    };

    // --- counted-vmcnt pipeline: tiles t and t+1 always in flight ---
    stage(0, 0);
    stage(1, 64);
    int cur = 0;
    for (int kt = 0; kt < K - 64; kt += 64) {
        wait_vmcnt<NPT>();                 // tile kt landed; kt+64 in flight
        __builtin_amdgcn_s_barrier();
        compute(cur);
        wait_lgkm0();
        __builtin_amdgcn_s_barrier();
        if (kt + 128 < K) stage(cur, kt + 128);
        cur ^= 1;
    }
    wait_vmcnt<0>();                       // last tile
    __builtin_amdgcn_s_barrier();
    compute(cur);

    // epilogue: C/D frag layout col = lane&15, row = (lane>>4)*4 + r
#pragma unroll
    for (int mi = 0; mi < MR; mi++) {
        if (EPI == 0) {
            // one wave spans exactly one head's 64 cols (BN/WC == 64)
            const int col0  = n0 + wc * 64;
            const int which = (col0 >= 1536) ? 2 : (col0 >= 768 ? 1 : 0);
            const int row0  = m0 + wr * (BM / WR) + mi * 16 + g * 4;
            float val[NR][4];
#pragma unroll
            for (int ni = 0; ni < NR; ni++) {
                const int dd = col0 + ni * 16 + q - which * 768;
                const float bias = (which == 0 ? bias0 : which == 1 ? bias1 : bias2)[dd];
#pragma unroll
                for (int r = 0; r < 4; r++) val[ni][r] = acc[mi][ni][r] + bias;
            }
            if (which <= 1) {   // fused per-row L2 norm over the head's 64 dims
#pragma unroll
                for (int r = 0; r < 4; r++) {
                    float ss = val[0][r] * val[0][r];
#pragma unroll
                    for (int ni = 1; ni < NR; ni++) ss += val[ni][r] * val[ni][r];
                    ss += __shfl_xor(ss, 1);
                    ss += __shfl_xor(ss, 2);
                    ss += __shfl_xor(ss, 4);
                    ss += __shfl_xor(ss, 8);
                    const float rn = 1.0f / fmaxf(sqrtf(ss), 1e-12f);
#pragma unroll
                    for (int ni = 0; ni < NR; ni++) val[ni][r] *= rn;
                }
            }
            const int dd0 = col0 - which * 768;
            const int hh  = dd0 >> 6;
            const long bh = (long)(row0 >> 11) * 12 + hh;
#pragma unroll
            for (int ni = 0; ni < NR; ni++) {
                const int dk = ni * 16 + q;
                if (which == 2) {
                    bf16x4 pv;
#pragma unroll
                    for (int r = 0; r < 4; r++) pv[r] = (bf16)val[ni][r];
                    *(bf16x4*)&vo[(bh * 64 + dk) * 2048 + (row0 & 2047)] = pv;
                } else {
                    bf16* dst = (which == 0) ? qo : ko;
#pragma unroll
                    for (int r = 0; r < 4; r++)
                        dst[(bh * 2048 + ((row0 + r) & 2047)) * 64 + dk] = (bf16)val[ni][r];
                }
            }
        } else {
#pragma unroll
            for (int ni = 0; ni < NR; ni++) {
                const int col  = n0 + wc * (BN / WC) + ni * 16 + q;
                const int row0 = m0 + wr * (BM / WR) + mi * 16 + g * 4;
                const float bias = bias0[col];
                if (EPI == 1) {          // + fp32 residual -> bf16
#pragma unroll
                    for (int r = 0; r < 4; r++) {
                        const int row = row0 + r;
                        outb[(long)row * 768 + col] =
                            (bf16)(acc[mi][ni][r] + bias + residf[(long)row * 768 + col]);
                    }
                } else if (EPI == 3) {   // + bf16 residual -> bf16
#pragma unroll
                    for (int r = 0; r < 4; r++) {
                        const int row = row0 + r;
                        outb[(long)row * 768 + col] =
                            (bf16)(acc[mi][ni][r] + bias + (float)residb[(long)row * 768 + col]);
                    }
                } else {                 // EPI == 2: exact GELU -> bf16
#pragma unroll
                    for (int r = 0; r < 4; r++) {
                        const float v  = acc[mi][ni][r] + bias;
                        const float gl = 0.5f * v * (1.0f + erff(v * 0.70710678118654752f));
                        outb[(long)(row0 + r) * 3072 + col] = (bf16)gl;
                    }
                }
            }
        }
    }
}

// ---------------------------------------------------------------------------
// Attention (no softmax): O = (Qn Kn^T)^2 @ V  per (b,h).
// Block = 4 waves x 16 q-rows = 64 q-rows; 64-key tiles; dbuf LDS staging,
// one barrier per tile, named A/B register sets, loop unrolled x2.
// Swapped QK^T -> P k-contiguous in wave-private padded LDS -> PV A-frag.
// 1D grid + XCD swizzle (same-bh blocks share K/V in one XCD L2).
// ---------------------------------------------------------------------------
__global__ __launch_bounds__(256, 2)
void attn_kernel(const bf16* __restrict__ Qn, const bf16* __restrict__ Kn,
                 const bf16* __restrict__ Vt, bf16* __restrict__ AO) {
    const int wg  = xcd_swz(blockIdx.x, gridDim.x);
    const int bh  = wg >> 5;
    const int tid = threadIdx.x, lane = tid & 63, w = tid >> 6;
    const int g = lane >> 4, q15 = lane & 15;
    const int qbase = (wg & 31) * 64 + w * 16;

    __shared__ __align__(16) bf16 Kl[2][64][72];
    __shared__ __align__(16) bf16 Vl[2][64][72];
    __shared__ __align__(16) bf16 Pl[4][16][72];
    bf16 (*Pw)[72] = Pl[w];

    const bf16* Qp = Qn + (long)bh * S_ * 64;
    const bf16* Kp = Kn + (long)bh * S_ * 64;
    const bf16* Vp = Vt + (long)bh * 64 * S_;

    const int srow = tid >> 3, scol = (tid & 7) * 8;   // staging coords

    bf16x8 qf0 = *(const bf16x8*)&Qp[(long)(qbase + q15) * 64 + g * 8];
    bf16x8 qf1 = *(const bf16x8*)&Qp[(long)(qbase + q15) * 64 + 32 + g * 8];

    f32x4 o[4] = {};

    bf16x8 aK0, aK1, aV0, aV1, bK0, bK1, bV0, bV1;
    auto gloadA = [&](int kt) {
        aK0 = *(const bf16x8*)&Kp[(long)(kt + srow) * 64 + scol];
        aK1 = *(const bf16x8*)&Kp[(long)(kt + 32 + srow) * 64 + scol];
        aV0 = *(const bf16x8*)&Vp[(long)srow * S_ + kt + scol];
        aV1 = *(const bf16x8*)&Vp[(long)(32 + srow) * S_ + kt + scol];
    };
    auto gloadB = [&](int kt) {
        bK0 = *(const bf16x8*)&Kp[(long)(kt + srow) * 64 + scol];
        bK1 = *(const bf16x8*)&Kp[(long)(kt + 32 + srow) * 64 + scol];
        bV0 = *(const bf16x8*)&Vp[(long)srow * S_ + kt + scol];
        bV1 = *(const bf16x8*)&Vp[(long)(32 + srow) * S_ + kt + scol];
    };
    auto stageA = [&](int buf) {
        *(bf16x8*)&Kl[buf][srow][scol]      = aK0;
        *(bf16x8*)&Kl[buf][32 + srow][scol] = aK1;
        *(bf16x8*)&Vl[buf][srow][scol]      = aV0;
        *(bf16x8*)&Vl[buf][32 + srow][scol] = aV1;
    };
    auto stageB = [&](int buf) {
        *(bf16x8*)&Kl[buf][srow][scol]      = bK0;
        *(bf16x8*)&Kl[buf][32 + srow][scol] = bK1;
        *(bf16x8*)&Vl[buf][srow][scol]      = bV0;
        *(bf16x8*)&Vl[buf][32 + srow][scol] = bV1;
    };

    auto compute = [&](int cur) {
        bf16x8 kf[4][2];
#pragma unroll
        for (int ni = 0; ni < 4; ni++)
#pragma unroll
            for (int c = 0; c < 2; c++)
                kf[ni][c] = *(const bf16x8*)&Kl[cur][ni * 16 + q15][c * 32 + g * 8];
        f32x4 s[4];
#pragma unroll
        for (int ni = 0; ni < 4; ni++) {
            s[ni] = mfma16(kf[ni][0], qf0, f32x4{0.f, 0.f, 0.f, 0.f});
            s[ni] = mfma16(kf[ni][1], qf1, s[ni]);
        }
#pragma unroll
        for (int ni = 0; ni < 4; ni++) {
            bf16x4 p4;
#pragma unroll
            for (int r = 0; r < 4; r++) { float v = s[ni][r]; p4[r] = (bf16)(v * v); }
            *(bf16x4*)&Pw[q15][ni * 16 + g * 4] = p4;
        }
        bf16x8 pf0 = *(const bf16x8*)&Pw[q15][g * 8];
        bf16x8 pf1 = *(const bf16x8*)&Pw[q15][32 + g * 8];
        bf16x8 vf[4][2];
#pragma unroll
        for (int ni = 0; ni < 4; ni++)
#pragma unroll
            for (int c = 0; c < 2; c++)
                vf[ni][c] = *(const bf16x8*)&Vl[cur][ni * 16 + q15][c * 32 + g * 8];
#pragma unroll
        for (int ni = 0; ni < 4; ni++) {
            o[ni] = mfma16(pf0, vf[ni][0], o[ni]);
            o[ni] = mfma16(pf1, vf[ni][1], o[ni]);
        }
    };

    gloadA(0);
    stageA(0);
    gloadB(64);
    __syncthreads();
    for (int t = 0; t <= 28; t += 2) {
        stageB(1);
        gloadA((t + 2) * 64);
        compute(0);
        __syncthreads();
        stageA(0);
        if (t + 3 < 32) gloadB((t + 3) * 64);
        compute(1);
        __syncthreads();
    }
    stageB(1);
    compute(0);
    __syncthreads();
    compute(1);

    const int b = bh / 12, h = bh % 12;
#pragma unroll
    for (int ni = 0; ni < 4; ni++)
#pragma unroll
        for (int r = 0; r < 4; r++) {
            const int s = qbase + g * 4 + r;
            AO[((long)b * S_ + s) * D_ + h * 64 + ni * 16 + q15] = (bf16)o[ni][r];
        }
}

// ---------------------------------------------------------------------------
// LayerNorm over D=768 (bf16 input). One block per row, 256 threads.
// WB=true: write bf16 only (mid-layer). WB=false: write fp32 (final out).
// ---------------------------------------------------------------------------
template<bool WB>
__global__ __launch_bounds__(256)
void ln_kernel(const bf16* __restrict__ y, const float* __restrict__ gamma,
               const float* __restrict__ beta, float* __restrict__ xo,
               bf16* __restrict__ xob) {
    __shared__ float sa[4], sb[4];
    const int row = blockIdx.x, t = threadIdx.x;
    const bf16* yr = y + (long)row * 768;
    float v0 = (float)yr[t], v1 = (float)yr[t + 256], v2 = (float)yr[t + 512];
    float s  = v0 + v1 + v2;
    float ss = v0 * v0 + v1 * v1 + v2 * v2;
#pragma unroll
    for (int o = 32; o; o >>= 1) { s += __shfl_xor(s, o); ss += __shfl_xor(ss, o); }
    if ((t & 63) == 0) { sa[t >> 6] = s; sb[t >> 6] = ss; }
    __syncthreads();
    s  = sa[0] + sa[1] + sa[2] + sa[3];
    ss = sb[0] + sb[1] + sb[2] + sb[3];
    const float mu   = s * (1.0f / 768.0f);
    const float var  = ss * (1.0f / 768.0f) - mu * mu;
    const float rstd = rsqrtf(var + 1e-5f);
#pragma unroll
    for (int i = 0; i < 3; i++) {
        const int c = t + i * 256;
        const float vv = (i == 0) ? v0 : (i == 1) ? v1 : v2;
        const float ov = (vv - mu) * rstd * gamma[c] + beta[c];
        if (WB) xob[(long)row * 768 + c] = (bf16)ov;
        else    xo[(long)row * 768 + c] = ov;
    }
}

// ---------------------------------------------------------------------------
extern "C" void kernel_launch(void* const* d_in, const int* in_sizes, int n_in,
                              void* d_out, int out_size, void* d_ws, size_t ws_size,
                              hipStream_t stream) {
    const float* x     = (const float*)d_in[0];
    const float* Wq    = (const float*)d_in[1];
    const float* bq    = (const float*)d_in[2];
    const float* Wk    = (const float*)d_in[3];
    const float* bk    = (const float*)d_in[4];
    const float* Wv    = (const float*)d_in[5];
    const float* bv    = (const float*)d_in[6];
    const float* Wo    = (const float*)d_in[7];
    const float* bo    = (const float*)d_in[8];
    const float* W1    = (const float*)d_in[9];
    const float* b1    = (const float*)d_in[10];
    const float* W2    = (const float*)d_in[11];
    const float* b2    = (const float*)d_in[12];
    const float* gamma = (const float*)d_in[13];
    const float* beta  = (const float*)d_in[14];

    char* p = (char*)d_ws;
    auto alloc = [&](size_t bytes) -> void* {
        void* r = p;
        p += (bytes + 255) & ~(size_t)255;
        return r;
    };
    bf16*  Xb    = (bf16*)alloc((size_t)M_ * D_ * 2);
    bf16*  Wqkvt = (bf16*)alloc((size_t)2304 * 768 * 2);
    bf16*  Wot   = (bf16*)alloc((size_t)768 * 768 * 2);
    bf16*  W1t   = (bf16*)alloc((size_t)3072 * 768 * 2);
    bf16*  W2t   = (bf16*)alloc((size_t)768 * 3072 * 2);
    bf16*  Qh    = (bf16*)alloc((size_t)BH_ * S_ * 64 * 2);
    bf16*  Kh    = (bf16*)alloc((size_t)BH_ * S_ * 64 * 2);
    bf16*  Vt    = (bf16*)alloc((size_t)BH_ * S_ * 64 * 2);
    bf16*  AO    = (bf16*)alloc((size_t)M_ * D_ * 2);
    bf16*  y1b   = (bf16*)alloc((size_t)M_ * D_ * 2);
    bf16*  x1b   = (bf16*)alloc((size_t)M_ * D_ * 2);
    bf16*  hbuf  = (bf16*)alloc((size_t)M_ * DFF_ * 2);
    bf16*  y2b   = y1b;  // y1b dead after LN1

    // pack + transpose weights (one launch)
    pack_x_kernel<<<(M_ * D_) / 1024, 256, 0, stream>>>(x, Xb);
    wt_all_kernel<<<1728, 256, 0, stream>>>(Wq, Wk, Wv, Wo, W1, W2,
                                            Wqkvt, Wot, W1t, W2t);

    // QKV projection (+fused Q/K L2-norm) -> Qh/Kh [bh][s][dk], Vt [bh][dk][s]
    gemm_bt<0, 768, 128, 128, 2, 2><<<18 * 32, 256, 0, stream>>>(
        Xb, Wqkvt, bq, bk, bv, nullptr, nullptr, nullptr, Qh, Kh, Vt);

    // attention
    attn_kernel<<<32 * BH_, 256, 0, stream>>>(Qh, Kh, Vt, AO);

    // out projection + residual -> bf16, LN1  (64x64, 768 blocks)
    gemm_bt<1, 768, 64, 64, 2, 2><<<12 * 64, 256, 0, stream>>>(
        AO, Wot, bo, nullptr, nullptr, x, nullptr, y1b, nullptr, nullptr, nullptr);
    ln_kernel<true><<<M_, 256, 0, stream>>>(y1b, gamma, beta, nullptr, x1b);

    // FFN
    gemm_bt<2, 768, 128, 128, 2, 2><<<24 * 32, 256, 0, stream>>>(
        x1b, W1t, b1, nullptr, nullptr, nullptr, nullptr, hbuf, nullptr, nullptr, nullptr);
    gemm_bt<3, 3072, 64, 64, 2, 2><<<12 * 64, 256, 0, stream>>>(
        hbuf, W2t, b2, nullptr, nullptr, nullptr, x1b, y2b, nullptr, nullptr, nullptr);
    ln_kernel<false><<<M_, 256, 0, stream>>>(y2b, gamma, beta, (float*)d_out, nullptr);
}

// Round 9
// 221.130 us; speedup vs baseline: 1.1934x; 1.1934x over previous
//
#include <hip/hip_runtime.h>
#include <math.h>

// ---------------------------------------------------------------------------
// EncoderLayer: B=2,S=2048,D=768,H=12,DK=64,DFF=3072
// bf16 MFMA (16x16x32) for all matmuls, fp32 accumulate + fp32 pointwise.
// ---------------------------------------------------------------------------

using bf16   = __bf16;
using bf16x8 = __attribute__((ext_vector_type(8))) __bf16;
using bf16x4 = __attribute__((ext_vector_type(4))) __bf16;
using f32x4  = __attribute__((ext_vector_type(4))) float;

constexpr int S_   = 2048;
constexpr int D_   = 768;
constexpr int DFF_ = 3072;
constexpr int M_   = 4096;   // B*S
constexpr int BH_  = 24;     // B*H

__device__ __forceinline__ f32x4 mfma16(bf16x8 a, bf16x8 b, f32x4 c) {
    return __builtin_amdgcn_mfma_f32_16x16x32_bf16(a, b, c, 0, 0, 0);
}

// async global->LDS, 16B per lane; LDS dest wave-uniform, lane fills base+l*16
__device__ __forceinline__ void gload16(const bf16* g, bf16* l) {
    __builtin_amdgcn_global_load_lds(
        (const __attribute__((address_space(1))) void*)g,
        (__attribute__((address_space(3))) void*)l, 16, 0, 0);
}

template<int N> __device__ __forceinline__ void wait_vmcnt() {
    if constexpr (N == 0)      asm volatile("s_waitcnt vmcnt(0)" ::: "memory");
    else if constexpr (N == 4) asm volatile("s_waitcnt vmcnt(4)" ::: "memory");
    else if constexpr (N == 8) asm volatile("s_waitcnt vmcnt(8)" ::: "memory");
    else static_assert(N == 0, "unsupported vmcnt");
}
__device__ __forceinline__ void wait_lgkm0() {
    asm volatile("s_waitcnt lgkmcnt(0)" ::: "memory");
}

// bijective XCD-cluster swizzle; valid when nwg % 8 == 0
__device__ __forceinline__ int xcd_swz(int orig, int nwg) {
    return (orig & 7) * (nwg >> 3) + (orig >> 3);
}

// ---------------------------------------------------------------------------
// pack x (fp32 -> bf16), 4 elems/thread
// ---------------------------------------------------------------------------
__global__ __launch_bounds__(256)
void pack_x_kernel(const float* __restrict__ x, bf16* __restrict__ xb) {
    const int i = blockIdx.x * 256 + threadIdx.x;
    float4 v = ((const float4*)x)[i];
    bf16x4 o;
    o[0] = (bf16)v.x; o[1] = (bf16)v.y; o[2] = (bf16)v.z; o[3] = (bf16)v.w;
    ((bf16x4*)xb)[i] = o;
}

// ---------------------------------------------------------------------------
// ALL weight transposes in one launch: in [K][N] fp32 -> out [N][K] bf16.
// 64x64 tiles, flat block index -> (matrix, tile).
// ---------------------------------------------------------------------------
__global__ __launch_bounds__(256)
void wt_all_kernel(const float* __restrict__ Wq, const float* __restrict__ Wk,
                   const float* __restrict__ Wv, const float* __restrict__ Wo,
                   const float* __restrict__ W1, const float* __restrict__ W2,
                   bf16* __restrict__ Wqkvt, bf16* __restrict__ Wot,
                   bf16* __restrict__ W1t, bf16* __restrict__ W2t) {
    int bid = blockIdx.x;
    const float* in; bf16* out; int K, N, t;
    if (bid < 576) {                       // Wq/Wk/Wv/Wo: 144 tiles each
        int m = bid / 144; t = bid % 144; K = 768; N = 768;
        in  = (m == 0) ? Wq : (m == 1) ? Wk : (m == 2) ? Wv : Wo;
        out = (m == 3) ? Wot : Wqkvt + (size_t)m * 768 * 768;
    } else if (bid < 1152) {               // W1: [768][3072] -> [3072][768]
        t = bid - 576; K = 768; N = 3072; in = W1; out = W1t;
    } else {                               // W2: [3072][768] -> [768][3072]
        t = bid - 1152; K = 3072; N = 768; in = W2; out = W2t;
    }
    const int ntx = N / 64;
    const int n0 = (t % ntx) * 64, k0 = (t / ntx) * 64;

    __shared__ __align__(16) bf16 T[64][72];
    const int tt = threadIdx.x;
    const int r  = tt >> 2, c0 = (tt & 3) * 16;
    const float* src = in + (size_t)(k0 + r) * N + n0 + c0;
#pragma unroll
    for (int j = 0; j < 16; j += 4) {
        float4 v = *(const float4*)(src + j);
        T[r][c0 + j + 0] = (bf16)v.x;
        T[r][c0 + j + 1] = (bf16)v.y;
        T[r][c0 + j + 2] = (bf16)v.z;
        T[r][c0 + j + 3] = (bf16)v.w;
    }
    __syncthreads();
    bf16x8 o0, o1;
#pragma unroll
    for (int j = 0; j < 8; j++) { o0[j] = T[c0 + j][r]; o1[j] = T[c0 + 8 + j][r]; }
    bf16* dst = out + (size_t)(n0 + r) * K + k0 + c0;
    *(bf16x8*)(dst)     = o0;
    *(bf16x8*)(dst + 8) = o1;
}

// ---------------------------------------------------------------------------
// GEMM: C = A[M,K] @ Bt[N,K]^T, BMxBN tile, BK=64, 4 waves in WRxWC grid.
// m97-EXACT staging: global_load_lds 16B/lane, lane l -> row l>>3, 16B-chunk
// l&7 -> each gload16 = 8 contiguous 128B segments (fully coalesced), LDS
// linear [row][64].  Fragment ds_read_b128 from linear LDS (m97 accepts the
// bank aliasing; HW-verified 874 TF reference).
// DBUF=false: single-buffer 2-barrier m97 loop (128^2 kernels; 32KB LDS).
// DBUF=true : counted-vmcnt double-buffer, tiles t,t+1 in flight (64^2
//             kernels; 32KB LDS total, no occupancy cost).
// 1D grid + bijective XCD swizzle.
// EPI: 0=QKV (+bias, fused Q/K row-L2-norm, V written transposed),
//      1=Wo(+bias+fp32 resid)->bf16, 2=FFN1 gelu->bf16,
//      3=FFN2(+bias+bf16 resid)->bf16
// ---------------------------------------------------------------------------
template<int EPI, int K, int BM, int BN, int WR, int WC, bool DBUF>
__global__ __launch_bounds__(256)
void gemm_bt(const bf16* __restrict__ A, const bf16* __restrict__ Bt,
             const float* __restrict__ bias0, const float* __restrict__ bias1,
             const float* __restrict__ bias2, const float* __restrict__ residf,
             const bf16* __restrict__ residb, bf16* __restrict__ outb,
             bf16* __restrict__ qo, bf16* __restrict__ ko, bf16* __restrict__ vo) {
    constexpr int MR  = BM / WR / 16;
    constexpr int NR  = BN / WC / 16;
    constexpr int GA  = BM / 32;          // gload16 per wave for A tile
    constexpr int GB  = BN / 32;
    constexpr int NPT = GA + GB;          // this wave's loads per K-tile
    constexpr int NCOL = (EPI == 0) ? 2304 : (EPI == 2) ? 3072 : 768;
    constexpr int NBX  = NCOL / BN;
    __shared__ __align__(16) bf16 Al[(DBUF ? 2 : 1) * BM * 64];
    __shared__ __align__(16) bf16 Bl[(DBUF ? 2 : 1) * BN * 64];
    const int tid  = threadIdx.x;
    const int lane = tid & 63, w = tid >> 6;
    const int wr = w / WC, wc = w % WC;
    const int wg = xcd_swz(blockIdx.x, gridDim.x);
    const int m0 = (wg / NBX) * BM, n0 = (wg % NBX) * BN;
    const int g = lane >> 4, q = lane & 15;
    const int srow = lane >> 3, schunk = (lane & 7) * 8;   // staging coords

    f32x4 acc[MR][NR] = {};

    const bf16* gaA = A  + (long)(m0 + w * (BM / 4) + srow) * K + schunk;
    const bf16* gaB = Bt + (long)(n0 + w * (BN / 4) + srow) * K + schunk;

    auto stage = [&](int buf, int kt) {
#pragma unroll
        for (int i = 0; i < GA; i++)
            gload16(gaA + kt + (long)i * 8 * K,
                    &Al[buf * BM * 64 + (w * (BM / 4) + i * 8) * 64]);
#pragma unroll
        for (int i = 0; i < GB; i++)
            gload16(gaB + kt + (long)i * 8 * K,
                    &Bl[buf * BN * 64 + (w * (BN / 4) + i * 8) * 64]);
    };
    auto compute = [&](int buf) {
#pragma unroll
        for (int c = 0; c < 2; c++) {
            bf16x8 af[MR], bfr[NR];
#pragma unroll
            for (int i = 0; i < MR; i++)
                af[i] = *(const bf16x8*)
                    &Al[buf * BM * 64 + (wr * (BM / WR) + i * 16 + q) * 64 + c * 32 + g * 8];
#pragma unroll
            for (int i = 0; i < NR; i++)
                bfr[i] = *(const bf16x8*)
                    &Bl[buf * BN * 64 + (wc * (BN / WC) + i * 16 + q) * 64 + c * 32 + g * 8];
#pragma unroll
            for (int mi = 0; mi < MR; mi++)
#pragma unroll
                for (int ni = 0; ni < NR; ni++)
                    acc[mi][ni] = mfma16(af[mi], bfr[ni], acc[mi][ni]);
        }
    };

    if (DBUF) {
        // counted-vmcnt pipeline: tiles t and t+1 always in flight
        stage(0, 0);
        stage(1, 64);
        int cur = 0;
        for (int kt = 0; kt < K - 64; kt += 64) {
            wait_vmcnt<NPT>();             // tile kt landed; kt+64 in flight
            __builtin_amdgcn_s_barrier();
            compute(cur);
            wait_lgkm0();
            __builtin_amdgcn_s_barrier();
            if (kt + 128 < K) stage(cur, kt + 128);
            cur ^= 1;
        }
        wait_vmcnt<0>();
        __builtin_amdgcn_s_barrier();
        compute(cur);
    } else {
        // m97 2-barrier single-buffer loop
        for (int kt = 0; kt < K; kt += 64) {
            __syncthreads();
            stage(0, kt);
            __syncthreads();               // compiler drains vmcnt here
            compute(0);
        }
    }

    // epilogue: C/D frag layout col = lane&15, row = (lane>>4)*4 + r
#pragma unroll
    for (int mi = 0; mi < MR; mi++) {
        if (EPI == 0) {
            // one wave spans exactly one head's 64 cols (BN/WC == 64)
            const int col0  = n0 + wc * 64;
            const int which = (col0 >= 1536) ? 2 : (col0 >= 768 ? 1 : 0);
            const int row0  = m0 + wr * (BM / WR) + mi * 16 + g * 4;
            float val[NR][4];
#pragma unroll
            for (int ni = 0; ni < NR; ni++) {
                const int dd = col0 + ni * 16 + q - which * 768;
                const float bias = (which == 0 ? bias0 : which == 1 ? bias1 : bias2)[dd];
#pragma unroll
                for (int r = 0; r < 4; r++) val[ni][r] = acc[mi][ni][r] + bias;
            }
            if (which <= 1) {   // fused per-row L2 norm over the head's 64 dims
#pragma unroll
                for (int r = 0; r < 4; r++) {
                    float ss = val[0][r] * val[0][r];
#pragma unroll
                    for (int ni = 1; ni < NR; ni++) ss += val[ni][r] * val[ni][r];
                    ss += __shfl_xor(ss, 1);
                    ss += __shfl_xor(ss, 2);
                    ss += __shfl_xor(ss, 4);
                    ss += __shfl_xor(ss, 8);
                    const float rn = 1.0f / fmaxf(sqrtf(ss), 1e-12f);
#pragma unroll
                    for (int ni = 0; ni < NR; ni++) val[ni][r] *= rn;
                }
            }
            const int dd0 = col0 - which * 768;
            const int hh  = dd0 >> 6;
            const long bh = (long)(row0 >> 11) * 12 + hh;
#pragma unroll
            for (int ni = 0; ni < NR; ni++) {
                const int dk = ni * 16 + q;
                if (which == 2) {
                    bf16x4 pv;
#pragma unroll
                    for (int r = 0; r < 4; r++) pv[r] = (bf16)val[ni][r];
                    *(bf16x4*)&vo[(bh * 64 + dk) * 2048 + (row0 & 2047)] = pv;
                } else {
                    bf16* dst = (which == 0) ? qo : ko;
#pragma unroll
                    for (int r = 0; r < 4; r++)
                        dst[(bh * 2048 + ((row0 + r) & 2047)) * 64 + dk] = (bf16)val[ni][r];
                }
            }
        } else {
#pragma unroll
            for (int ni = 0; ni < NR; ni++) {
                const int col  = n0 + wc * (BN / WC) + ni * 16 + q;
                const int row0 = m0 + wr * (BM / WR) + mi * 16 + g * 4;
                const float bias = bias0[col];
                if (EPI == 1) {          // + fp32 residual -> bf16
#pragma unroll
                    for (int r = 0; r < 4; r++) {
                        const int row = row0 + r;
                        outb[(long)row * 768 + col] =
                            (bf16)(acc[mi][ni][r] + bias + residf[(long)row * 768 + col]);
                    }
                } else if (EPI == 3) {   // + bf16 residual -> bf16
#pragma unroll
                    for (int r = 0; r < 4; r++) {
                        const int row = row0 + r;
                        outb[(long)row * 768 + col] =
                            (bf16)(acc[mi][ni][r] + bias + (float)residb[(long)row * 768 + col]);
                    }
                } else {                 // EPI == 2: exact GELU -> bf16
#pragma unroll
                    for (int r = 0; r < 4; r++) {
                        const float v  = acc[mi][ni][r] + bias;
                        const float gl = 0.5f * v * (1.0f + erff(v * 0.70710678118654752f));
                        outb[(long)(row0 + r) * 3072 + col] = (bf16)gl;
                    }
                }
            }
        }
    }
}

// ---------------------------------------------------------------------------
// Attention (no softmax): O = (Qn Kn^T)^2 @ V  per (b,h).
// Block = 4 waves x 16 q-rows = 64 q-rows; 64-key tiles; dbuf LDS staging,
// one barrier per tile, named A/B register sets, loop unrolled x2.
// Swapped QK^T -> P k-contiguous in wave-private padded LDS -> PV A-frag.
// 1D grid + XCD swizzle (same-bh blocks share K/V in one XCD L2).
// ---------------------------------------------------------------------------
__global__ __launch_bounds__(256, 2)
void attn_kernel(const bf16* __restrict__ Qn, const bf16* __restrict__ Kn,
                 const bf16* __restrict__ Vt, bf16* __restrict__ AO) {
    const int wg  = xcd_swz(blockIdx.x, gridDim.x);
    const int bh  = wg >> 5;
    const int tid = threadIdx.x, lane = tid & 63, w = tid >> 6;
    const int g = lane >> 4, q15 = lane & 15;
    const int qbase = (wg & 31) * 64 + w * 16;

    __shared__ __align__(16) bf16 Kl[2][64][72];
    __shared__ __align__(16) bf16 Vl[2][64][72];
    __shared__ __align__(16) bf16 Pl[4][16][72];
    bf16 (*Pw)[72] = Pl[w];

    const bf16* Qp = Qn + (long)bh * S_ * 64;
    const bf16* Kp = Kn + (long)bh * S_ * 64;
    const bf16* Vp = Vt + (long)bh * 64 * S_;

    const int srow = tid >> 3, scol = (tid & 7) * 8;   // staging coords

    bf16x8 qf0 = *(const bf16x8*)&Qp[(long)(qbase + q15) * 64 + g * 8];
    bf16x8 qf1 = *(const bf16x8*)&Qp[(long)(qbase + q15) * 64 + 32 + g * 8];

    f32x4 o[4] = {};

    bf16x8 aK0, aK1, aV0, aV1, bK0, bK1, bV0, bV1;
    auto gloadA = [&](int kt) {
        aK0 = *(const bf16x8*)&Kp[(long)(kt + srow) * 64 + scol];
        aK1 = *(const bf16x8*)&Kp[(long)(kt + 32 + srow) * 64 + scol];
        aV0 = *(const bf16x8*)&Vp[(long)srow * S_ + kt + scol];
        aV1 = *(const bf16x8*)&Vp[(long)(32 + srow) * S_ + kt + scol];
    };
    auto gloadB = [&](int kt) {
        bK0 = *(const bf16x8*)&Kp[(long)(kt + srow) * 64 + scol];
        bK1 = *(const bf16x8*)&Kp[(long)(kt + 32 + srow) * 64 + scol];
        bV0 = *(const bf16x8*)&Vp[(long)srow * S_ + kt + scol];
        bV1 = *(const bf16x8*)&Vp[(long)(32 + srow) * S_ + kt + scol];
    };
    auto stageA = [&](int buf) {
        *(bf16x8*)&Kl[buf][srow][scol]      = aK0;
        *(bf16x8*)&Kl[buf][32 + srow][scol] = aK1;
        *(bf16x8*)&Vl[buf][srow][scol]      = aV0;
        *(bf16x8*)&Vl[buf][32 + srow][scol] = aV1;
    };
    auto stageB = [&](int buf) {
        *(bf16x8*)&Kl[buf][srow][scol]      = bK0;
        *(bf16x8*)&Kl[buf][32 + srow][scol] = bK1;
        *(bf16x8*)&Vl[buf][srow][scol]      = bV0;
        *(bf16x8*)&Vl[buf][32 + srow][scol] = bV1;
    };

    auto compute = [&](int cur) {
        bf16x8 kf[4][2];
#pragma unroll
        for (int ni = 0; ni < 4; ni++)
#pragma unroll
            for (int c = 0; c < 2; c++)
                kf[ni][c] = *(const bf16x8*)&Kl[cur][ni * 16 + q15][c * 32 + g * 8];
        f32x4 s[4];
#pragma unroll
        for (int ni = 0; ni < 4; ni++) {
            s[ni] = mfma16(kf[ni][0], qf0, f32x4{0.f, 0.f, 0.f, 0.f});
            s[ni] = mfma16(kf[ni][1], qf1, s[ni]);
        }
#pragma unroll
        for (int ni = 0; ni < 4; ni++) {
            bf16x4 p4;
#pragma unroll
            for (int r = 0; r < 4; r++) { float v = s[ni][r]; p4[r] = (bf16)(v * v); }
            *(bf16x4*)&Pw[q15][ni * 16 + g * 4] = p4;
        }
        bf16x8 pf0 = *(const bf16x8*)&Pw[q15][g * 8];
        bf16x8 pf1 = *(const bf16x8*)&Pw[q15][32 + g * 8];
        bf16x8 vf[4][2];
#pragma unroll
        for (int ni = 0; ni < 4; ni++)
#pragma unroll
            for (int c = 0; c < 2; c++)
                vf[ni][c] = *(const bf16x8*)&Vl[cur][ni * 16 + q15][c * 32 + g * 8];
#pragma unroll
        for (int ni = 0; ni < 4; ni++) {
            o[ni] = mfma16(pf0, vf[ni][0], o[ni]);
            o[ni] = mfma16(pf1, vf[ni][1], o[ni]);
        }
    };

    gloadA(0);
    stageA(0);
    gloadB(64);
    __syncthreads();
    for (int t = 0; t <= 28; t += 2) {
        stageB(1);
        gloadA((t + 2) * 64);
        compute(0);
        __syncthreads();
        stageA(0);
        if (t + 3 < 32) gloadB((t + 3) * 64);
        compute(1);
        __syncthreads();
    }
    stageB(1);
    compute(0);
    __syncthreads();
    compute(1);

    const int b = bh / 12, h = bh % 12;
#pragma unroll
    for (int ni = 0; ni < 4; ni++)
#pragma unroll
        for (int r = 0; r < 4; r++) {
            const int s = qbase + g * 4 + r;
            AO[((long)b * S_ + s) * D_ + h * 64 + ni * 16 + q15] = (bf16)o[ni][r];
        }
}

// ---------------------------------------------------------------------------
// LayerNorm over D=768 (bf16 input). One block per row, 256 threads.
// WB=true: write bf16 only (mid-layer). WB=false: write fp32 (final out).
// ---------------------------------------------------------------------------
template<bool WB>
__global__ __launch_bounds__(256)
void ln_kernel(const bf16* __restrict__ y, const float* __restrict__ gamma,
               const float* __restrict__ beta, float* __restrict__ xo,
               bf16* __restrict__ xob) {
    __shared__ float sa[4], sb[4];
    const int row = blockIdx.x, t = threadIdx.x;
    const bf16* yr = y + (long)row * 768;
    float v0 = (float)yr[t], v1 = (float)yr[t + 256], v2 = (float)yr[t + 512];
    float s  = v0 + v1 + v2;
    float ss = v0 * v0 + v1 * v1 + v2 * v2;
#pragma unroll
    for (int o = 32; o; o >>= 1) { s += __shfl_xor(s, o); ss += __shfl_xor(ss, o); }
    if ((t & 63) == 0) { sa[t >> 6] = s; sb[t >> 6] = ss; }
    __syncthreads();
    s  = sa[0] + sa[1] + sa[2] + sa[3];
    ss = sb[0] + sb[1] + sb[2] + sb[3];
    const float mu   = s * (1.0f / 768.0f);
    const float var  = ss * (1.0f / 768.0f) - mu * mu;
    const float rstd = rsqrtf(var + 1e-5f);
#pragma unroll
    for (int i = 0; i < 3; i++) {
        const int c = t + i * 256;
        const float vv = (i == 0) ? v0 : (i == 1) ? v1 : v2;
        const float ov = (vv - mu) * rstd * gamma[c] + beta[c];
        if (WB) xob[(long)row * 768 + c] = (bf16)ov;
        else    xo[(long)row * 768 + c] = ov;
    }
}

// ---------------------------------------------------------------------------
extern "C" void kernel_launch(void* const* d_in, const int* in_sizes, int n_in,
                              void* d_out, int out_size, void* d_ws, size_t ws_size,
                              hipStream_t stream) {
    const float* x     = (const float*)d_in[0];
    const float* Wq    = (const float*)d_in[1];
    const float* bq    = (const float*)d_in[2];
    const float* Wk    = (const float*)d_in[3];
    const float* bk    = (const float*)d_in[4];
    const float* Wv    = (const float*)d_in[5];
    const float* bv    = (const float*)d_in[6];
    const float* Wo    = (const float*)d_in[7];
    const float* bo    = (const float*)d_in[8];
    const float* W1    = (const float*)d_in[9];
    const float* b1    = (const float*)d_in[10];
    const float* W2    = (const float*)d_in[11];
    const float* b2    = (const float*)d_in[12];
    const float* gamma = (const float*)d_in[13];
    const float* beta  = (const float*)d_in[14];

    char* p = (char*)d_ws;
    auto alloc = [&](size_t bytes) -> void* {
        void* r = p;
        p += (bytes + 255) & ~(size_t)255;
        return r;
    };
    bf16*  Xb    = (bf16*)alloc((size_t)M_ * D_ * 2);
    bf16*  Wqkvt = (bf16*)alloc((size_t)2304 * 768 * 2);
    bf16*  Wot   = (bf16*)alloc((size_t)768 * 768 * 2);
    bf16*  W1t   = (bf16*)alloc((size_t)3072 * 768 * 2);
    bf16*  W2t   = (bf16*)alloc((size_t)768 * 3072 * 2);
    bf16*  Qh    = (bf16*)alloc((size_t)BH_ * S_ * 64 * 2);
    bf16*  Kh    = (bf16*)alloc((size_t)BH_ * S_ * 64 * 2);
    bf16*  Vt    = (bf16*)alloc((size_t)BH_ * S_ * 64 * 2);
    bf16*  AO    = (bf16*)alloc((size_t)M_ * D_ * 2);
    bf16*  y1b   = (bf16*)alloc((size_t)M_ * D_ * 2);
    bf16*  x1b   = (bf16*)alloc((size_t)M_ * D_ * 2);
    bf16*  hbuf  = (bf16*)alloc((size_t)M_ * DFF_ * 2);
    bf16*  y2b   = y1b;  // y1b dead after LN1

    // pack + transpose weights (one launch)
    pack_x_kernel<<<(M_ * D_) / 1024, 256, 0, stream>>>(x, Xb);
    wt_all_kernel<<<1728, 256, 0, stream>>>(Wq, Wk, Wv, Wo, W1, W2,
                                            Wqkvt, Wot, W1t, W2t);

    // QKV projection (+fused Q/K L2-norm) -> Qh/Kh [bh][s][dk], Vt [bh][dk][s]
    gemm_bt<0, 768, 128, 128, 2, 2, false><<<18 * 32, 256, 0, stream>>>(
        Xb, Wqkvt, bq, bk, bv, nullptr, nullptr, nullptr, Qh, Kh, Vt);

    // attention
    attn_kernel<<<32 * BH_, 256, 0, stream>>>(Qh, Kh, Vt, AO);

    // out projection + residual -> bf16, LN1  (64x64 counted-vmcnt dbuf)
    gemm_bt<1, 768, 64, 64, 2, 2, true><<<12 * 64, 256, 0, stream>>>(
        AO, Wot, bo, nullptr, nullptr, x, nullptr, y1b, nullptr, nullptr, nullptr);
    ln_kernel<true><<<M_, 256, 0, stream>>>(y1b, gamma, beta, nullptr, x1b);

    // FFN
    gemm_bt<2, 768, 128, 128, 2, 2, false><<<24 * 32, 256, 0, stream>>>(
        x1b, W1t, b1, nullptr, nullptr, nullptr, nullptr, hbuf, nullptr, nullptr, nullptr);
    gemm_bt<3, 3072, 64, 64, 2, 2, true><<<12 * 64, 256, 0, stream>>>(
        hbuf, W2t, b2, nullptr, nullptr, nullptr, x1b, y2b, nullptr, nullptr, nullptr);
    ln_kernel<false><<<M_, 256, 0, stream>>>(y2b, gamma, beta, (float*)d_out, nullptr);
}

// Round 10
// 206.040 us; speedup vs baseline: 1.2807x; 1.0732x over previous
//
#include <hip/hip_runtime.h>
#include <math.h>

// ---------------------------------------------------------------------------
// EncoderLayer: B=2,S=2048,D=768,H=12,DK=64,DFF=3072
// bf16 MFMA (16x16x32) for all matmuls, fp32 accumulate + fp32 pointwise.
// ---------------------------------------------------------------------------

using bf16   = __bf16;
using bf16x8 = __attribute__((ext_vector_type(8))) __bf16;
using bf16x4 = __attribute__((ext_vector_type(4))) __bf16;
using f32x4  = __attribute__((ext_vector_type(4))) float;

constexpr int S_   = 2048;
constexpr int D_   = 768;
constexpr int DFF_ = 3072;
constexpr int M_   = 4096;   // B*S
constexpr int BH_  = 24;     // B*H

__device__ __forceinline__ f32x4 mfma16(bf16x8 a, bf16x8 b, f32x4 c) {
    return __builtin_amdgcn_mfma_f32_16x16x32_bf16(a, b, c, 0, 0, 0);
}

// async global->LDS, 16B per lane; LDS dest wave-uniform, lane fills base+l*16
__device__ __forceinline__ void gload16(const bf16* g, bf16* l) {
    __builtin_amdgcn_global_load_lds(
        (const __attribute__((address_space(1))) void*)g,
        (__attribute__((address_space(3))) void*)l, 16, 0, 0);
}

template<int N> __device__ __forceinline__ void wait_vmcnt() {
    if constexpr (N == 0)      asm volatile("s_waitcnt vmcnt(0)" ::: "memory");
    else if constexpr (N == 4) asm volatile("s_waitcnt vmcnt(4)" ::: "memory");
    else if constexpr (N == 8) asm volatile("s_waitcnt vmcnt(8)" ::: "memory");
    else static_assert(N == 0, "unsupported vmcnt");
}
__device__ __forceinline__ void wait_lgkm0() {
    asm volatile("s_waitcnt lgkmcnt(0)" ::: "memory");
}

// bijective XCD-cluster swizzle; valid when nwg % 8 == 0
__device__ __forceinline__ int xcd_swz(int orig, int nwg) {
    return (orig & 7) * (nwg >> 3) + (orig >> 3);
}

// fast GELU (tanh form): v * sigmoid(1.5957691*(v + 0.044715 v^3)).
// |err| vs exact erf-GELU < ~1e-3 << 0.103 threshold; ~9 VALU vs erff ~28.
__device__ __forceinline__ float gelu_f(float v) {
    float y = 1.5957691f * (v + 0.044715f * v * v * v);
    return v / (1.0f + __expf(-y));
}

// ---------------------------------------------------------------------------
// pack x (fp32 -> bf16), 4 elems/thread
// ---------------------------------------------------------------------------
__global__ __launch_bounds__(256)
void pack_x_kernel(const float* __restrict__ x, bf16* __restrict__ xb) {
    const int i = blockIdx.x * 256 + threadIdx.x;
    float4 v = ((const float4*)x)[i];
    bf16x4 o;
    o[0] = (bf16)v.x; o[1] = (bf16)v.y; o[2] = (bf16)v.z; o[3] = (bf16)v.w;
    ((bf16x4*)xb)[i] = o;
}

// ---------------------------------------------------------------------------
// ALL weight transposes in one launch: in [K][N] fp32 -> out [N][K] bf16.
// 64x64 tiles, flat block index -> (matrix, tile).
// ---------------------------------------------------------------------------
__global__ __launch_bounds__(256)
void wt_all_kernel(const float* __restrict__ Wq, const float* __restrict__ Wk,
                   const float* __restrict__ Wv, const float* __restrict__ Wo,
                   const float* __restrict__ W1, const float* __restrict__ W2,
                   bf16* __restrict__ Wqkvt, bf16* __restrict__ Wot,
                   bf16* __restrict__ W1t, bf16* __restrict__ W2t) {
    int bid = blockIdx.x;
    const float* in; bf16* out; int K, N, t;
    if (bid < 576) {                       // Wq/Wk/Wv/Wo: 144 tiles each
        int m = bid / 144; t = bid % 144; K = 768; N = 768;
        in  = (m == 0) ? Wq : (m == 1) ? Wk : (m == 2) ? Wv : Wo;
        out = (m == 3) ? Wot : Wqkvt + (size_t)m * 768 * 768;
    } else if (bid < 1152) {               // W1: [768][3072] -> [3072][768]
        t = bid - 576; K = 768; N = 3072; in = W1; out = W1t;
    } else {                               // W2: [3072][768] -> [768][3072]
        t = bid - 1152; K = 3072; N = 768; in = W2; out = W2t;
    }
    const int ntx = N / 64;
    const int n0 = (t % ntx) * 64, k0 = (t / ntx) * 64;

    __shared__ __align__(16) bf16 T[64][72];
    const int tt = threadIdx.x;
    const int r  = tt >> 2, c0 = (tt & 3) * 16;
    const float* src = in + (size_t)(k0 + r) * N + n0 + c0;
#pragma unroll
    for (int j = 0; j < 16; j += 4) {
        float4 v = *(const float4*)(src + j);
        T[r][c0 + j + 0] = (bf16)v.x;
        T[r][c0 + j + 1] = (bf16)v.y;
        T[r][c0 + j + 2] = (bf16)v.z;
        T[r][c0 + j + 3] = (bf16)v.w;
    }
    __syncthreads();
    bf16x8 o0, o1;
#pragma unroll
    for (int j = 0; j < 8; j++) { o0[j] = T[c0 + j][r]; o1[j] = T[c0 + 8 + j][r]; }
    bf16* dst = out + (size_t)(n0 + r) * K + k0 + c0;
    *(bf16x8*)(dst)     = o0;
    *(bf16x8*)(dst + 8) = o1;
}

// ---------------------------------------------------------------------------
// GEMM: C = A[M,K] @ Bt[N,K]^T, BMxBN tile, BK=64, 4 waves in WRxWC grid.
// m97-EXACT staging: global_load_lds 16B/lane, lane l -> row l>>3, 16B-chunk
// l&7 -> each gload16 = 8 contiguous 128B segments (fully coalesced), LDS
// linear [row][64].
// Counted-vmcnt double-buffer pipeline (validated on 64^2 in R9): tiles t
// and t+1 always in flight; s_waitcnt vmcnt(NPT) -> barrier -> compute(t)
// -> lgkmcnt(0) -> barrier -> restage with t+2. Never drains to 0 until the
// peeled last tile.
// 1D grid + bijective XCD swizzle.
// EPI: 0=QKV (+bias, fused Q/K row-L2-norm, V written transposed),
//      1=Wo(+bias+fp32 resid)->bf16, 2=FFN1 fast-gelu->bf16,
//      3=FFN2(+bias+bf16 resid)->bf16
// ---------------------------------------------------------------------------
template<int EPI, int K, int BM, int BN, int WR, int WC>
__global__ __launch_bounds__(256)
void gemm_bt(const bf16* __restrict__ A, const bf16* __restrict__ Bt,
             const float* __restrict__ bias0, const float* __restrict__ bias1,
             const float* __restrict__ bias2, const float* __restrict__ residf,
             const bf16* __restrict__ residb, bf16* __restrict__ outb,
             bf16* __restrict__ qo, bf16* __restrict__ ko, bf16* __restrict__ vo) {
    constexpr int MR  = BM / WR / 16;
    constexpr int NR  = BN / WC / 16;
    constexpr int GA  = BM / 32;          // gload16 per wave for A tile
    constexpr int GB  = BN / 32;
    constexpr int NPT = GA + GB;          // this wave's loads per K-tile
    constexpr int NCOL = (EPI == 0) ? 2304 : (EPI == 2) ? 3072 : 768;
    constexpr int NBX  = NCOL / BN;
    __shared__ __align__(16) bf16 Al[2 * BM * 64];
    __shared__ __align__(16) bf16 Bl[2 * BN * 64];
    const int tid  = threadIdx.x;
    const int lane = tid & 63, w = tid >> 6;
    const int wr = w / WC, wc = w % WC;
    const int wg = xcd_swz(blockIdx.x, gridDim.x);
    const int m0 = (wg / NBX) * BM, n0 = (wg % NBX) * BN;
    const int g = lane >> 4, q = lane & 15;
    const int srow = lane >> 3, schunk = (lane & 7) * 8;   // staging coords

    f32x4 acc[MR][NR] = {};

    const bf16* gaA = A  + (long)(m0 + w * (BM / 4) + srow) * K + schunk;
    const bf16* gaB = Bt + (long)(n0 + w * (BN / 4) + srow) * K + schunk;

    auto stage = [&](int buf, int kt) {
#pragma unroll
        for (int i = 0; i < GA; i++)
            gload16(gaA + kt + (long)i * 8 * K,
                    &Al[buf * BM * 64 + (w * (BM / 4) + i * 8) * 64]);
#pragma unroll
        for (int i = 0; i < GB; i++)
            gload16(gaB + kt + (long)i * 8 * K,
                    &Bl[buf * BN * 64 + (w * (BN / 4) + i * 8) * 64]);
    };
    auto compute = [&](int buf) {
#pragma unroll
        for (int c = 0; c < 2; c++) {
            bf16x8 af[MR], bfr[NR];
#pragma unroll
            for (int i = 0; i < MR; i++)
                af[i] = *(const bf16x8*)
                    &Al[buf * BM * 64 + (wr * (BM / WR) + i * 16 + q) * 64 + c * 32 + g * 8];
#pragma unroll
            for (int i = 0; i < NR; i++)
                bfr[i] = *(const bf16x8*)
                    &Bl[buf * BN * 64 + (wc * (BN / WC) + i * 16 + q) * 64 + c * 32 + g * 8];
#pragma unroll
            for (int mi = 0; mi < MR; mi++)
#pragma unroll
                for (int ni = 0; ni < NR; ni++)
                    acc[mi][ni] = mfma16(af[mi], bfr[ni], acc[mi][ni]);
        }
    };

    // counted-vmcnt pipeline: tiles t and t+1 always in flight
    stage(0, 0);
    stage(1, 64);
    int cur = 0;
    for (int kt = 0; kt < K - 64; kt += 64) {
        wait_vmcnt<NPT>();                 // tile kt landed; kt+64 in flight
        __builtin_amdgcn_s_barrier();
        compute(cur);
        wait_lgkm0();
        __builtin_amdgcn_s_barrier();
        if (kt + 128 < K) stage(cur, kt + 128);
        cur ^= 1;
    }
    wait_vmcnt<0>();
    __builtin_amdgcn_s_barrier();
    compute(cur);

    // epilogue: C/D frag layout col = lane&15, row = (lane>>4)*4 + r
#pragma unroll
    for (int mi = 0; mi < MR; mi++) {
        if (EPI == 0) {
            // one wave spans exactly one head's 64 cols (BN/WC == 64)
            const int col0  = n0 + wc * 64;
            const int which = (col0 >= 1536) ? 2 : (col0 >= 768 ? 1 : 0);
            const int row0  = m0 + wr * (BM / WR) + mi * 16 + g * 4;
            float val[NR][4];
#pragma unroll
            for (int ni = 0; ni < NR; ni++) {
                const int dd = col0 + ni * 16 + q - which * 768;
                const float bias = (which == 0 ? bias0 : which == 1 ? bias1 : bias2)[dd];
#pragma unroll
                for (int r = 0; r < 4; r++) val[ni][r] = acc[mi][ni][r] + bias;
            }
            if (which <= 1) {   // fused per-row L2 norm over the head's 64 dims
#pragma unroll
                for (int r = 0; r < 4; r++) {
                    float ss = val[0][r] * val[0][r];
#pragma unroll
                    for (int ni = 1; ni < NR; ni++) ss += val[ni][r] * val[ni][r];
                    ss += __shfl_xor(ss, 1);
                    ss += __shfl_xor(ss, 2);
                    ss += __shfl_xor(ss, 4);
                    ss += __shfl_xor(ss, 8);
                    const float rn = 1.0f / fmaxf(sqrtf(ss), 1e-12f);
#pragma unroll
                    for (int ni = 0; ni < NR; ni++) val[ni][r] *= rn;
                }
            }
            const int dd0 = col0 - which * 768;
            const int hh  = dd0 >> 6;
            const long bh = (long)(row0 >> 11) * 12 + hh;
#pragma unroll
            for (int ni = 0; ni < NR; ni++) {
                const int dk = ni * 16 + q;
                if (which == 2) {
                    bf16x4 pv;
#pragma unroll
                    for (int r = 0; r < 4; r++) pv[r] = (bf16)val[ni][r];
                    *(bf16x4*)&vo[(bh * 64 + dk) * 2048 + (row0 & 2047)] = pv;
                } else {
                    bf16* dst = (which == 0) ? qo : ko;
#pragma unroll
                    for (int r = 0; r < 4; r++)
                        dst[(bh * 2048 + ((row0 + r) & 2047)) * 64 + dk] = (bf16)val[ni][r];
                }
            }
        } else {
#pragma unroll
            for (int ni = 0; ni < NR; ni++) {
                const int col  = n0 + wc * (BN / WC) + ni * 16 + q;
                const int row0 = m0 + wr * (BM / WR) + mi * 16 + g * 4;
                const float bias = bias0[col];
                if (EPI == 1) {          // + fp32 residual -> bf16
#pragma unroll
                    for (int r = 0; r < 4; r++) {
                        const int row = row0 + r;
                        outb[(long)row * 768 + col] =
                            (bf16)(acc[mi][ni][r] + bias + residf[(long)row * 768 + col]);
                    }
                } else if (EPI == 3) {   // + bf16 residual -> bf16
#pragma unroll
                    for (int r = 0; r < 4; r++) {
                        const int row = row0 + r;
                        outb[(long)row * 768 + col] =
                            (bf16)(acc[mi][ni][r] + bias + (float)residb[(long)row * 768 + col]);
                    }
                } else {                 // EPI == 2: fast GELU -> bf16
#pragma unroll
                    for (int r = 0; r < 4; r++) {
                        const float v = acc[mi][ni][r] + bias;
                        outb[(long)(row0 + r) * 3072 + col] = (bf16)gelu_f(v);
                    }
                }
            }
        }
    }
}

// ---------------------------------------------------------------------------
// Attention (no softmax): O = (Qn Kn^T)^2 @ V  per (b,h).
// Block = 4 waves x 16 q-rows = 64 q-rows; 64-key tiles; dbuf LDS staging,
// one barrier per tile, named A/B register sets, loop unrolled x2.
// Swapped QK^T -> P k-contiguous in wave-private padded LDS -> PV A-frag.
// 1D grid + XCD swizzle (same-bh blocks share K/V in one XCD L2).
// ---------------------------------------------------------------------------
__global__ __launch_bounds__(256, 2)
void attn_kernel(const bf16* __restrict__ Qn, const bf16* __restrict__ Kn,
                 const bf16* __restrict__ Vt, bf16* __restrict__ AO) {
    const int wg  = xcd_swz(blockIdx.x, gridDim.x);
    const int bh  = wg >> 5;
    const int tid = threadIdx.x, lane = tid & 63, w = tid >> 6;
    const int g = lane >> 4, q15 = lane & 15;
    const int qbase = (wg & 31) * 64 + w * 16;

    __shared__ __align__(16) bf16 Kl[2][64][72];
    __shared__ __align__(16) bf16 Vl[2][64][72];
    __shared__ __align__(16) bf16 Pl[4][16][72];
    bf16 (*Pw)[72] = Pl[w];

    const bf16* Qp = Qn + (long)bh * S_ * 64;
    const bf16* Kp = Kn + (long)bh * S_ * 64;
    const bf16* Vp = Vt + (long)bh * 64 * S_;

    const int srow = tid >> 3, scol = (tid & 7) * 8;   // staging coords

    bf16x8 qf0 = *(const bf16x8*)&Qp[(long)(qbase + q15) * 64 + g * 8];
    bf16x8 qf1 = *(const bf16x8*)&Qp[(long)(qbase + q15) * 64 + 32 + g * 8];

    f32x4 o[4] = {};

    bf16x8 aK0, aK1, aV0, aV1, bK0, bK1, bV0, bV1;
    auto gloadA = [&](int kt) {
        aK0 = *(const bf16x8*)&Kp[(long)(kt + srow) * 64 + scol];
        aK1 = *(const bf16x8*)&Kp[(long)(kt + 32 + srow) * 64 + scol];
        aV0 = *(const bf16x8*)&Vp[(long)srow * S_ + kt + scol];
        aV1 = *(const bf16x8*)&Vp[(long)(32 + srow) * S_ + kt + scol];
    };
    auto gloadB = [&](int kt) {
        bK0 = *(const bf16x8*)&Kp[(long)(kt + srow) * 64 + scol];
        bK1 = *(const bf16x8*)&Kp[(long)(kt + 32 + srow) * 64 + scol];
        bV0 = *(const bf16x8*)&Vp[(long)srow * S_ + kt + scol];
        bV1 = *(const bf16x8*)&Vp[(long)(32 + srow) * S_ + kt + scol];
    };
    auto stageA = [&](int buf) {
        *(bf16x8*)&Kl[buf][srow][scol]      = aK0;
        *(bf16x8*)&Kl[buf][32 + srow][scol] = aK1;
        *(bf16x8*)&Vl[buf][srow][scol]      = aV0;
        *(bf16x8*)&Vl[buf][32 + srow][scol] = aV1;
    };
    auto stageB = [&](int buf) {
        *(bf16x8*)&Kl[buf][srow][scol]      = bK0;
        *(bf16x8*)&Kl[buf][32 + srow][scol] = bK1;
        *(bf16x8*)&Vl[buf][srow][scol]      = bV0;
        *(bf16x8*)&Vl[buf][32 + srow][scol] = bV1;
    };

    auto compute = [&](int cur) {
        bf16x8 kf[4][2];
#pragma unroll
        for (int ni = 0; ni < 4; ni++)
#pragma unroll
            for (int c = 0; c < 2; c++)
                kf[ni][c] = *(const bf16x8*)&Kl[cur][ni * 16 + q15][c * 32 + g * 8];
        f32x4 s[4];
#pragma unroll
        for (int ni = 0; ni < 4; ni++) {
            s[ni] = mfma16(kf[ni][0], qf0, f32x4{0.f, 0.f, 0.f, 0.f});
            s[ni] = mfma16(kf[ni][1], qf1, s[ni]);
        }
#pragma unroll
        for (int ni = 0; ni < 4; ni++) {
            bf16x4 p4;
#pragma unroll
            for (int r = 0; r < 4; r++) { float v = s[ni][r]; p4[r] = (bf16)(v * v); }
            *(bf16x4*)&Pw[q15][ni * 16 + g * 4] = p4;
        }
        bf16x8 pf0 = *(const bf16x8*)&Pw[q15][g * 8];
        bf16x8 pf1 = *(const bf16x8*)&Pw[q15][32 + g * 8];
        bf16x8 vf[4][2];
#pragma unroll
        for (int ni = 0; ni < 4; ni++)
#pragma unroll
            for (int c = 0; c < 2; c++)
                vf[ni][c] = *(const bf16x8*)&Vl[cur][ni * 16 + q15][c * 32 + g * 8];
#pragma unroll
        for (int ni = 0; ni < 4; ni++) {
            o[ni] = mfma16(pf0, vf[ni][0], o[ni]);
            o[ni] = mfma16(pf1, vf[ni][1], o[ni]);
        }
    };

    gloadA(0);
    stageA(0);
    gloadB(64);
    __syncthreads();
    for (int t = 0; t <= 28; t += 2) {
        stageB(1);
        gloadA((t + 2) * 64);
        compute(0);
        __syncthreads();
        stageA(0);
        if (t + 3 < 32) gloadB((t + 3) * 64);
        compute(1);
        __syncthreads();
    }
    stageB(1);
    compute(0);
    __syncthreads();
    compute(1);

    const int b = bh / 12, h = bh % 12;
#pragma unroll
    for (int ni = 0; ni < 4; ni++)
#pragma unroll
        for (int r = 0; r < 4; r++) {
            const int s = qbase + g * 4 + r;
            AO[((long)b * S_ + s) * D_ + h * 64 + ni * 16 + q15] = (bf16)o[ni][r];
        }
}

// ---------------------------------------------------------------------------
// LayerNorm over D=768 (bf16 input). One block per row, 256 threads.
// WB=true: write bf16 only (mid-layer). WB=false: write fp32 (final out).
// ---------------------------------------------------------------------------
template<bool WB>
__global__ __launch_bounds__(256)
void ln_kernel(const bf16* __restrict__ y, const float* __restrict__ gamma,
               const float* __restrict__ beta, float* __restrict__ xo,
               bf16* __restrict__ xob) {
    __shared__ float sa[4], sb[4];
    const int row = blockIdx.x, t = threadIdx.x;
    const bf16* yr = y + (long)row * 768;
    float v0 = (float)yr[t], v1 = (float)yr[t + 256], v2 = (float)yr[t + 512];
    float s  = v0 + v1 + v2;
    float ss = v0 * v0 + v1 * v1 + v2 * v2;
#pragma unroll
    for (int o = 32; o; o >>= 1) { s += __shfl_xor(s, o); ss += __shfl_xor(ss, o); }
    if ((t & 63) == 0) { sa[t >> 6] = s; sb[t >> 6] = ss; }
    __syncthreads();
    s  = sa[0] + sa[1] + sa[2] + sa[3];
    ss = sb[0] + sb[1] + sb[2] + sb[3];
    const float mu   = s * (1.0f / 768.0f);
    const float var  = ss * (1.0f / 768.0f) - mu * mu;
    const float rstd = rsqrtf(var + 1e-5f);
#pragma unroll
    for (int i = 0; i < 3; i++) {
        const int c = t + i * 256;
        const float vv = (i == 0) ? v0 : (i == 1) ? v1 : v2;
        const float ov = (vv - mu) * rstd * gamma[c] + beta[c];
        if (WB) xob[(long)row * 768 + c] = (bf16)ov;
        else    xo[(long)row * 768 + c] = ov;
    }
}

// ---------------------------------------------------------------------------
extern "C" void kernel_launch(void* const* d_in, const int* in_sizes, int n_in,
                              void* d_out, int out_size, void* d_ws, size_t ws_size,
                              hipStream_t stream) {
    const float* x     = (const float*)d_in[0];
    const float* Wq    = (const float*)d_in[1];
    const float* bq    = (const float*)d_in[2];
    const float* Wk    = (const float*)d_in[3];
    const float* bk    = (const float*)d_in[4];
    const float* Wv    = (const float*)d_in[5];
    const float* bv    = (const float*)d_in[6];
    const float* Wo    = (const float*)d_in[7];
    const float* bo    = (const float*)d_in[8];
    const float* W1    = (const float*)d_in[9];
    const float* b1    = (const float*)d_in[10];
    const float* W2    = (const float*)d_in[11];
    const float* b2    = (const float*)d_in[12];
    const float* gamma = (const float*)d_in[13];
    const float* beta  = (const float*)d_in[14];

    char* p = (char*)d_ws;
    auto alloc = [&](size_t bytes) -> void* {
        void* r = p;
        p += (bytes + 255) & ~(size_t)255;
        return r;
    };
    bf16*  Xb    = (bf16*)alloc((size_t)M_ * D_ * 2);
    bf16*  Wqkvt = (bf16*)alloc((size_t)2304 * 768 * 2);
    bf16*  Wot   = (bf16*)alloc((size_t)768 * 768 * 2);
    bf16*  W1t   = (bf16*)alloc((size_t)3072 * 768 * 2);
    bf16*  W2t   = (bf16*)alloc((size_t)768 * 3072 * 2);
    bf16*  Qh    = (bf16*)alloc((size_t)BH_ * S_ * 64 * 2);
    bf16*  Kh    = (bf16*)alloc((size_t)BH_ * S_ * 64 * 2);
    bf16*  Vt    = (bf16*)alloc((size_t)BH_ * S_ * 64 * 2);
    bf16*  AO    = (bf16*)alloc((size_t)M_ * D_ * 2);
    bf16*  y1b   = (bf16*)alloc((size_t)M_ * D_ * 2);
    bf16*  x1b   = (bf16*)alloc((size_t)M_ * D_ * 2);
    bf16*  hbuf  = (bf16*)alloc((size_t)M_ * DFF_ * 2);
    bf16*  y2b   = y1b;  // y1b dead after LN1

    // pack + transpose weights (one launch)
    pack_x_kernel<<<(M_ * D_) / 1024, 256, 0, stream>>>(x, Xb);
    wt_all_kernel<<<1728, 256, 0, stream>>>(Wq, Wk, Wv, Wo, W1, W2,
                                            Wqkvt, Wot, W1t, W2t);

    // QKV projection (+fused Q/K L2-norm) -> Qh/Kh [bh][s][dk], Vt [bh][dk][s]
    gemm_bt<0, 768, 128, 128, 2, 2><<<18 * 32, 256, 0, stream>>>(
        Xb, Wqkvt, bq, bk, bv, nullptr, nullptr, nullptr, Qh, Kh, Vt);

    // attention
    attn_kernel<<<32 * BH_, 256, 0, stream>>>(Qh, Kh, Vt, AO);

    // out projection + residual -> bf16, LN1  (64x64 counted-vmcnt dbuf)
    gemm_bt<1, 768, 64, 64, 2, 2><<<12 * 64, 256, 0, stream>>>(
        AO, Wot, bo, nullptr, nullptr, x, nullptr, y1b, nullptr, nullptr, nullptr);
    ln_kernel<true><<<M_, 256, 0, stream>>>(y1b, gamma, beta, nullptr, x1b);

    // FFN
    gemm_bt<2, 768, 128, 128, 2, 2><<<24 * 32, 256, 0, stream>>>(
        x1b, W1t, b1, nullptr, nullptr, nullptr, nullptr, hbuf, nullptr, nullptr, nullptr);
    gemm_bt<3, 3072, 64, 64, 2, 2><<<12 * 64, 256, 0, stream>>>(
        hbuf, W2t, b2, nullptr, nullptr, nullptr, x1b, y2b, nullptr, nullptr, nullptr);
    ln_kernel<false><<<M_, 256, 0, stream>>>(y2b, gamma, beta, (float*)d_out, nullptr);
}

// Round 11
// 204.597 us; speedup vs baseline: 1.2898x; 1.0071x over previous
//
#include <hip/hip_runtime.h>
#include <math.h>

// ---------------------------------------------------------------------------
// EncoderLayer: B=2,S=2048,D=768,H=12,DK=64,DFF=3072
// bf16 MFMA (16x16x32) for all matmuls, fp32 accumulate + fp32 pointwise.
// ---------------------------------------------------------------------------

using bf16   = __bf16;
using bf16x8 = __attribute__((ext_vector_type(8))) __bf16;
using bf16x4 = __attribute__((ext_vector_type(4))) __bf16;
using f32x4  = __attribute__((ext_vector_type(4))) float;

constexpr int S_   = 2048;
constexpr int D_   = 768;
constexpr int DFF_ = 3072;
constexpr int M_   = 4096;   // B*S
constexpr int BH_  = 24;     // B*H

__device__ __forceinline__ f32x4 mfma16(bf16x8 a, bf16x8 b, f32x4 c) {
    return __builtin_amdgcn_mfma_f32_16x16x32_bf16(a, b, c, 0, 0, 0);
}

// async global->LDS, 16B per lane; LDS dest wave-uniform, lane fills base+l*16
__device__ __forceinline__ void gload16(const bf16* g, bf16* l) {
    __builtin_amdgcn_global_load_lds(
        (const __attribute__((address_space(1))) void*)g,
        (__attribute__((address_space(3))) void*)l, 16, 0, 0);
}

template<int N> __device__ __forceinline__ void wait_vmcnt() {
    if constexpr (N == 0)      asm volatile("s_waitcnt vmcnt(0)" ::: "memory");
    else if constexpr (N == 4) asm volatile("s_waitcnt vmcnt(4)" ::: "memory");
    else if constexpr (N == 8) asm volatile("s_waitcnt vmcnt(8)" ::: "memory");
    else static_assert(N == 0, "unsupported vmcnt");
}
__device__ __forceinline__ void wait_lgkm0() {
    asm volatile("s_waitcnt lgkmcnt(0)" ::: "memory");
}

// bijective XCD-cluster swizzle; valid when nwg % 8 == 0
__device__ __forceinline__ int xcd_swz(int orig, int nwg) {
    return (orig & 7) * (nwg >> 3) + (orig >> 3);
}

// fast GELU (tanh form): v * sigmoid(1.5957691*(v + 0.044715 v^3)).
// |err| vs exact erf-GELU < ~1e-3 << 0.103 threshold; ~9 VALU vs erff ~28.
__device__ __forceinline__ float gelu_f(float v) {
    float y = 1.5957691f * (v + 0.044715f * v * v * v);
    return v / (1.0f + __expf(-y));
}

// ---------------------------------------------------------------------------
// pack x (fp32 -> bf16), 4 elems/thread
// ---------------------------------------------------------------------------
__global__ __launch_bounds__(256)
void pack_x_kernel(const float* __restrict__ x, bf16* __restrict__ xb) {
    const int i = blockIdx.x * 256 + threadIdx.x;
    float4 v = ((const float4*)x)[i];
    bf16x4 o;
    o[0] = (bf16)v.x; o[1] = (bf16)v.y; o[2] = (bf16)v.z; o[3] = (bf16)v.w;
    ((bf16x4*)xb)[i] = o;
}

// ---------------------------------------------------------------------------
// ALL weight transposes in one launch: in [K][N] fp32 -> out [N][K] bf16.
// 64x64 tiles, flat block index -> (matrix, tile).
// ---------------------------------------------------------------------------
__global__ __launch_bounds__(256)
void wt_all_kernel(const float* __restrict__ Wq, const float* __restrict__ Wk,
                   const float* __restrict__ Wv, const float* __restrict__ Wo,
                   const float* __restrict__ W1, const float* __restrict__ W2,
                   bf16* __restrict__ Wqkvt, bf16* __restrict__ Wot,
                   bf16* __restrict__ W1t, bf16* __restrict__ W2t) {
    int bid = blockIdx.x;
    const float* in; bf16* out; int K, N, t;
    if (bid < 576) {                       // Wq/Wk/Wv/Wo: 144 tiles each
        int m = bid / 144; t = bid % 144; K = 768; N = 768;
        in  = (m == 0) ? Wq : (m == 1) ? Wk : (m == 2) ? Wv : Wo;
        out = (m == 3) ? Wot : Wqkvt + (size_t)m * 768 * 768;
    } else if (bid < 1152) {               // W1: [768][3072] -> [3072][768]
        t = bid - 576; K = 768; N = 3072; in = W1; out = W1t;
    } else {                               // W2: [3072][768] -> [768][3072]
        t = bid - 1152; K = 3072; N = 768; in = W2; out = W2t;
    }
    const int ntx = N / 64;
    const int n0 = (t % ntx) * 64, k0 = (t / ntx) * 64;

    __shared__ __align__(16) bf16 T[64][72];
    const int tt = threadIdx.x;
    const int r  = tt >> 2, c0 = (tt & 3) * 16;
    const float* src = in + (size_t)(k0 + r) * N + n0 + c0;
#pragma unroll
    for (int j = 0; j < 16; j += 4) {
        float4 v = *(const float4*)(src + j);
        T[r][c0 + j + 0] = (bf16)v.x;
        T[r][c0 + j + 1] = (bf16)v.y;
        T[r][c0 + j + 2] = (bf16)v.z;
        T[r][c0 + j + 3] = (bf16)v.w;
    }
    __syncthreads();
    bf16x8 o0, o1;
#pragma unroll
    for (int j = 0; j < 8; j++) { o0[j] = T[c0 + j][r]; o1[j] = T[c0 + 8 + j][r]; }
    bf16* dst = out + (size_t)(n0 + r) * K + k0 + c0;
    *(bf16x8*)(dst)     = o0;
    *(bf16x8*)(dst + 8) = o1;
}

// ---------------------------------------------------------------------------
// GEMM: C = A[M,K] @ Bt[N,K]^T, BMxBN tile, BK=64, 4 waves in WRxWC grid.
// m97-EXACT staging (coalesced 128B segments), LDS linear [row][64].
// Counted-vmcnt double-buffer pipeline: tiles t,t+1 always in flight.
// 1D grid + bijective XCD swizzle.
// EPI: 0=QKV (+bias, fused Q/K row-L2-norm, V written transposed),
//      1=Wo(+bias+fp32 resid)->bf16, 2=FFN1 fast-gelu->bf16,
//      3=FFN2(+bias+bf16 resid)->bf16
// ---------------------------------------------------------------------------
template<int EPI, int K, int BM, int BN, int WR, int WC>
__global__ __launch_bounds__(256)
void gemm_bt(const bf16* __restrict__ A, const bf16* __restrict__ Bt,
             const float* __restrict__ bias0, const float* __restrict__ bias1,
             const float* __restrict__ bias2, const float* __restrict__ residf,
             const bf16* __restrict__ residb, bf16* __restrict__ outb,
             bf16* __restrict__ qo, bf16* __restrict__ ko, bf16* __restrict__ vo) {
    constexpr int MR  = BM / WR / 16;
    constexpr int NR  = BN / WC / 16;
    constexpr int GA  = BM / 32;          // gload16 per wave for A tile
    constexpr int GB  = BN / 32;
    constexpr int NPT = GA + GB;          // this wave's loads per K-tile
    constexpr int NCOL = (EPI == 0) ? 2304 : (EPI == 2) ? 3072 : 768;
    constexpr int NBX  = NCOL / BN;
    __shared__ __align__(16) bf16 Al[2 * BM * 64];
    __shared__ __align__(16) bf16 Bl[2 * BN * 64];
    const int tid  = threadIdx.x;
    const int lane = tid & 63, w = tid >> 6;
    const int wr = w / WC, wc = w % WC;
    const int wg = xcd_swz(blockIdx.x, gridDim.x);
    const int m0 = (wg / NBX) * BM, n0 = (wg % NBX) * BN;
    const int g = lane >> 4, q = lane & 15;
    const int srow = lane >> 3, schunk = (lane & 7) * 8;   // staging coords

    f32x4 acc[MR][NR] = {};

    const bf16* gaA = A  + (long)(m0 + w * (BM / 4) + srow) * K + schunk;
    const bf16* gaB = Bt + (long)(n0 + w * (BN / 4) + srow) * K + schunk;

    auto stage = [&](int buf, int kt) {
#pragma unroll
        for (int i = 0; i < GA; i++)
            gload16(gaA + kt + (long)i * 8 * K,
                    &Al[buf * BM * 64 + (w * (BM / 4) + i * 8) * 64]);
#pragma unroll
        for (int i = 0; i < GB; i++)
            gload16(gaB + kt + (long)i * 8 * K,
                    &Bl[buf * BN * 64 + (w * (BN / 4) + i * 8) * 64]);
    };
    auto compute = [&](int buf) {
#pragma unroll
        for (int c = 0; c < 2; c++) {
            bf16x8 af[MR], bfr[NR];
#pragma unroll
            for (int i = 0; i < MR; i++)
                af[i] = *(const bf16x8*)
                    &Al[buf * BM * 64 + (wr * (BM / WR) + i * 16 + q) * 64 + c * 32 + g * 8];
#pragma unroll
            for (int i = 0; i < NR; i++)
                bfr[i] = *(const bf16x8*)
                    &Bl[buf * BN * 64 + (wc * (BN / WC) + i * 16 + q) * 64 + c * 32 + g * 8];
#pragma unroll
            for (int mi = 0; mi < MR; mi++)
#pragma unroll
                for (int ni = 0; ni < NR; ni++)
                    acc[mi][ni] = mfma16(af[mi], bfr[ni], acc[mi][ni]);
        }
    };

    // counted-vmcnt pipeline: tiles t and t+1 always in flight
    stage(0, 0);
    stage(1, 64);
    int cur = 0;
    for (int kt = 0; kt < K - 64; kt += 64) {
        wait_vmcnt<NPT>();                 // tile kt landed; kt+64 in flight
        __builtin_amdgcn_s_barrier();
        compute(cur);
        wait_lgkm0();
        __builtin_amdgcn_s_barrier();
        if (kt + 128 < K) stage(cur, kt + 128);
        cur ^= 1;
    }
    wait_vmcnt<0>();
    __builtin_amdgcn_s_barrier();
    compute(cur);

    // epilogue: C/D frag layout col = lane&15, row = (lane>>4)*4 + r
#pragma unroll
    for (int mi = 0; mi < MR; mi++) {
        if (EPI == 0) {
            // one wave spans exactly one head's 64 cols (BN/WC == 64)
            const int col0  = n0 + wc * 64;
            const int which = (col0 >= 1536) ? 2 : (col0 >= 768 ? 1 : 0);
            const int row0  = m0 + wr * (BM / WR) + mi * 16 + g * 4;
            float val[NR][4];
#pragma unroll
            for (int ni = 0; ni < NR; ni++) {
                const int dd = col0 + ni * 16 + q - which * 768;
                const float bias = (which == 0 ? bias0 : which == 1 ? bias1 : bias2)[dd];
#pragma unroll
                for (int r = 0; r < 4; r++) val[ni][r] = acc[mi][ni][r] + bias;
            }
            if (which <= 1) {   // fused per-row L2 norm over the head's 64 dims
#pragma unroll
                for (int r = 0; r < 4; r++) {
                    float ss = val[0][r] * val[0][r];
#pragma unroll
                    for (int ni = 1; ni < NR; ni++) ss += val[ni][r] * val[ni][r];
                    ss += __shfl_xor(ss, 1);
                    ss += __shfl_xor(ss, 2);
                    ss += __shfl_xor(ss, 4);
                    ss += __shfl_xor(ss, 8);
                    const float rn = 1.0f / fmaxf(sqrtf(ss), 1e-12f);
#pragma unroll
                    for (int ni = 0; ni < NR; ni++) val[ni][r] *= rn;
                }
            }
            const int dd0 = col0 - which * 768;
            const int hh  = dd0 >> 6;
            const long bh = (long)(row0 >> 11) * 12 + hh;
#pragma unroll
            for (int ni = 0; ni < NR; ni++) {
                const int dk = ni * 16 + q;
                if (which == 2) {
                    bf16x4 pv;
#pragma unroll
                    for (int r = 0; r < 4; r++) pv[r] = (bf16)val[ni][r];
                    *(bf16x4*)&vo[(bh * 64 + dk) * 2048 + (row0 & 2047)] = pv;
                } else {
                    bf16* dst = (which == 0) ? qo : ko;
#pragma unroll
                    for (int r = 0; r < 4; r++)
                        dst[(bh * 2048 + ((row0 + r) & 2047)) * 64 + dk] = (bf16)val[ni][r];
                }
            }
        } else {
#pragma unroll
            for (int ni = 0; ni < NR; ni++) {
                const int col  = n0 + wc * (BN / WC) + ni * 16 + q;
                const int row0 = m0 + wr * (BM / WR) + mi * 16 + g * 4;
                const float bias = bias0[col];
                if (EPI == 1) {          // + fp32 residual -> bf16
#pragma unroll
                    for (int r = 0; r < 4; r++) {
                        const int row = row0 + r;
                        outb[(long)row * 768 + col] =
                            (bf16)(acc[mi][ni][r] + bias + residf[(long)row * 768 + col]);
                    }
                } else if (EPI == 3) {   // + bf16 residual -> bf16
#pragma unroll
                    for (int r = 0; r < 4; r++) {
                        const int row = row0 + r;
                        outb[(long)row * 768 + col] =
                            (bf16)(acc[mi][ni][r] + bias + (float)residb[(long)row * 768 + col]);
                    }
                } else {                 // EPI == 2: fast GELU -> bf16
#pragma unroll
                    for (int r = 0; r < 4; r++) {
                        const float v = acc[mi][ni][r] + bias;
                        outb[(long)(row0 + r) * 3072 + col] = (bf16)gelu_f(v);
                    }
                }
            }
        }
    }
}

// ---------------------------------------------------------------------------
// Attention (no softmax): O = (Qn Kn^T)^2 @ V  per (b,h).
// Block = 4 waves x 32 q-rows = 128 q-rows; 64-key tiles; dbuf LDS staging.
// Each wave computes TWO 16-row Q fragments (mi=0,1) against the shared
// K/V tiles: 32 MFMA per tile per wave vs 20 b128-equiv LDS ops (was 16:22)
// -> ~2x arithmetic intensity per LDS byte.
// Swapped QK^T -> P k-contiguous in wave-private padded LDS -> PV A-frag.
// 1D grid (16 qblocks x 24 bh) + XCD swizzle (same-bh blocks share K/V L2).
// ---------------------------------------------------------------------------
__global__ __launch_bounds__(256, 2)
void attn_kernel(const bf16* __restrict__ Qn, const bf16* __restrict__ Kn,
                 const bf16* __restrict__ Vt, bf16* __restrict__ AO) {
    const int wg  = xcd_swz(blockIdx.x, gridDim.x);
    const int bh  = wg >> 4;
    const int tid = threadIdx.x, lane = tid & 63, w = tid >> 6;
    const int g = lane >> 4, q15 = lane & 15;
    const int qbase = (wg & 15) * 128 + w * 32;

    __shared__ __align__(16) bf16 Kl[2][64][72];
    __shared__ __align__(16) bf16 Vl[2][64][72];
    __shared__ __align__(16) bf16 Pl[4][32][72];
    bf16 (*Pw)[72] = Pl[w];

    const bf16* Qp = Qn + (long)bh * S_ * 64;
    const bf16* Kp = Kn + (long)bh * S_ * 64;
    const bf16* Vp = Vt + (long)bh * 64 * S_;

    const int srow = tid >> 3, scol = (tid & 7) * 8;   // staging coords

    bf16x8 qf00 = *(const bf16x8*)&Qp[(long)(qbase + q15) * 64 + g * 8];
    bf16x8 qf01 = *(const bf16x8*)&Qp[(long)(qbase + q15) * 64 + 32 + g * 8];
    bf16x8 qf10 = *(const bf16x8*)&Qp[(long)(qbase + 16 + q15) * 64 + g * 8];
    bf16x8 qf11 = *(const bf16x8*)&Qp[(long)(qbase + 16 + q15) * 64 + 32 + g * 8];

    f32x4 o0[4] = {}, o1[4] = {};

    bf16x8 aK0, aK1, aV0, aV1, bK0, bK1, bV0, bV1;
    auto gloadA = [&](int kt) {
        aK0 = *(const bf16x8*)&Kp[(long)(kt + srow) * 64 + scol];
        aK1 = *(const bf16x8*)&Kp[(long)(kt + 32 + srow) * 64 + scol];
        aV0 = *(const bf16x8*)&Vp[(long)srow * S_ + kt + scol];
        aV1 = *(const bf16x8*)&Vp[(long)(32 + srow) * S_ + kt + scol];
    };
    auto gloadB = [&](int kt) {
        bK0 = *(const bf16x8*)&Kp[(long)(kt + srow) * 64 + scol];
        bK1 = *(const bf16x8*)&Kp[(long)(kt + 32 + srow) * 64 + scol];
        bV0 = *(const bf16x8*)&Vp[(long)srow * S_ + kt + scol];
        bV1 = *(const bf16x8*)&Vp[(long)(32 + srow) * S_ + kt + scol];
    };
    auto stageA = [&](int buf) {
        *(bf16x8*)&Kl[buf][srow][scol]      = aK0;
        *(bf16x8*)&Kl[buf][32 + srow][scol] = aK1;
        *(bf16x8*)&Vl[buf][srow][scol]      = aV0;
        *(bf16x8*)&Vl[buf][32 + srow][scol] = aV1;
    };
    auto stageB = [&](int buf) {
        *(bf16x8*)&Kl[buf][srow][scol]      = bK0;
        *(bf16x8*)&Kl[buf][32 + srow][scol] = bK1;
        *(bf16x8*)&Vl[buf][srow][scol]      = bV0;
        *(bf16x8*)&Vl[buf][32 + srow][scol] = bV1;
    };

    auto compute = [&](int cur) {
        bf16x8 kf[4][2];
#pragma unroll
        for (int ni = 0; ni < 4; ni++)
#pragma unroll
            for (int c = 0; c < 2; c++)
                kf[ni][c] = *(const bf16x8*)&Kl[cur][ni * 16 + q15][c * 32 + g * 8];
        f32x4 s0[4], s1[4];
#pragma unroll
        for (int ni = 0; ni < 4; ni++) {
            s0[ni] = mfma16(kf[ni][0], qf00, f32x4{0.f, 0.f, 0.f, 0.f});
            s0[ni] = mfma16(kf[ni][1], qf01, s0[ni]);
            s1[ni] = mfma16(kf[ni][0], qf10, f32x4{0.f, 0.f, 0.f, 0.f});
            s1[ni] = mfma16(kf[ni][1], qf11, s1[ni]);
        }
#pragma unroll
        for (int ni = 0; ni < 4; ni++) {
            bf16x4 p0, p1;
#pragma unroll
            for (int r = 0; r < 4; r++) {
                float v0 = s0[ni][r]; p0[r] = (bf16)(v0 * v0);
                float v1 = s1[ni][r]; p1[r] = (bf16)(v1 * v1);
            }
            *(bf16x4*)&Pw[q15][ni * 16 + g * 4]      = p0;
            *(bf16x4*)&Pw[16 + q15][ni * 16 + g * 4] = p1;
        }
        bf16x8 pf00 = *(const bf16x8*)&Pw[q15][g * 8];
        bf16x8 pf01 = *(const bf16x8*)&Pw[q15][32 + g * 8];
        bf16x8 pf10 = *(const bf16x8*)&Pw[16 + q15][g * 8];
        bf16x8 pf11 = *(const bf16x8*)&Pw[16 + q15][32 + g * 8];
        bf16x8 vf[4][2];
#pragma unroll
        for (int ni = 0; ni < 4; ni++)
#pragma unroll
            for (int c = 0; c < 2; c++)
                vf[ni][c] = *(const bf16x8*)&Vl[cur][ni * 16 + q15][c * 32 + g * 8];
#pragma unroll
        for (int ni = 0; ni < 4; ni++) {
            o0[ni] = mfma16(pf00, vf[ni][0], o0[ni]);
            o0[ni] = mfma16(pf01, vf[ni][1], o0[ni]);
            o1[ni] = mfma16(pf10, vf[ni][0], o1[ni]);
            o1[ni] = mfma16(pf11, vf[ni][1], o1[ni]);
        }
    };

    gloadA(0);
    stageA(0);
    gloadB(64);
    __syncthreads();
    for (int t = 0; t <= 28; t += 2) {
        stageB(1);
        gloadA((t + 2) * 64);
        compute(0);
        __syncthreads();
        stageA(0);
        if (t + 3 < 32) gloadB((t + 3) * 64);
        compute(1);
        __syncthreads();
    }
    stageB(1);
    compute(0);
    __syncthreads();
    compute(1);

    const int b = bh / 12, h = bh % 12;
#pragma unroll
    for (int ni = 0; ni < 4; ni++)
#pragma unroll
        for (int r = 0; r < 4; r++) {
            const int s0r = qbase + g * 4 + r;
            AO[((long)b * S_ + s0r) * D_ + h * 64 + ni * 16 + q15] = (bf16)o0[ni][r];
            const int s1r = qbase + 16 + g * 4 + r;
            AO[((long)b * S_ + s1r) * D_ + h * 64 + ni * 16 + q15] = (bf16)o1[ni][r];
        }
}

// ---------------------------------------------------------------------------
// LayerNorm over D=768 (bf16 input). One block per row, 256 threads.
// WB=true: write bf16 only (mid-layer). WB=false: write fp32 (final out).
// ---------------------------------------------------------------------------
template<bool WB>
__global__ __launch_bounds__(256)
void ln_kernel(const bf16* __restrict__ y, const float* __restrict__ gamma,
               const float* __restrict__ beta, float* __restrict__ xo,
               bf16* __restrict__ xob) {
    __shared__ float sa[4], sb[4];
    const int row = blockIdx.x, t = threadIdx.x;
    const bf16* yr = y + (long)row * 768;
    float v0 = (float)yr[t], v1 = (float)yr[t + 256], v2 = (float)yr[t + 512];
    float s  = v0 + v1 + v2;
    float ss = v0 * v0 + v1 * v1 + v2 * v2;
#pragma unroll
    for (int o = 32; o; o >>= 1) { s += __shfl_xor(s, o); ss += __shfl_xor(ss, o); }
    if ((t & 63) == 0) { sa[t >> 6] = s; sb[t >> 6] = ss; }
    __syncthreads();
    s  = sa[0] + sa[1] + sa[2] + sa[3];
    ss = sb[0] + sb[1] + sb[2] + sb[3];
    const float mu   = s * (1.0f / 768.0f);
    const float var  = ss * (1.0f / 768.0f) - mu * mu;
    const float rstd = rsqrtf(var + 1e-5f);
#pragma unroll
    for (int i = 0; i < 3; i++) {
        const int c = t + i * 256;
        const float vv = (i == 0) ? v0 : (i == 1) ? v1 : v2;
        const float ov = (vv - mu) * rstd * gamma[c] + beta[c];
        if (WB) xob[(long)row * 768 + c] = (bf16)ov;
        else    xo[(long)row * 768 + c] = ov;
    }
}

// ---------------------------------------------------------------------------
extern "C" void kernel_launch(void* const* d_in, const int* in_sizes, int n_in,
                              void* d_out, int out_size, void* d_ws, size_t ws_size,
                              hipStream_t stream) {
    const float* x     = (const float*)d_in[0];
    const float* Wq    = (const float*)d_in[1];
    const float* bq    = (const float*)d_in[2];
    const float* Wk    = (const float*)d_in[3];
    const float* bk    = (const float*)d_in[4];
    const float* Wv    = (const float*)d_in[5];
    const float* bv    = (const float*)d_in[6];
    const float* Wo    = (const float*)d_in[7];
    const float* bo    = (const float*)d_in[8];
    const float* W1    = (const float*)d_in[9];
    const float* b1    = (const float*)d_in[10];
    const float* W2    = (const float*)d_in[11];
    const float* b2    = (const float*)d_in[12];
    const float* gamma = (const float*)d_in[13];
    const float* beta  = (const float*)d_in[14];

    char* p = (char*)d_ws;
    auto alloc = [&](size_t bytes) -> void* {
        void* r = p;
        p += (bytes + 255) & ~(size_t)255;
        return r;
    };
    bf16*  Xb    = (bf16*)alloc((size_t)M_ * D_ * 2);
    bf16*  Wqkvt = (bf16*)alloc((size_t)2304 * 768 * 2);
    bf16*  Wot   = (bf16*)alloc((size_t)768 * 768 * 2);
    bf16*  W1t   = (bf16*)alloc((size_t)3072 * 768 * 2);
    bf16*  W2t   = (bf16*)alloc((size_t)768 * 3072 * 2);
    bf16*  Qh    = (bf16*)alloc((size_t)BH_ * S_ * 64 * 2);
    bf16*  Kh    = (bf16*)alloc((size_t)BH_ * S_ * 64 * 2);
    bf16*  Vt    = (bf16*)alloc((size_t)BH_ * S_ * 64 * 2);
    bf16*  AO    = (bf16*)alloc((size_t)M_ * D_ * 2);
    bf16*  y1b   = (bf16*)alloc((size_t)M_ * D_ * 2);
    bf16*  x1b   = (bf16*)alloc((size_t)M_ * D_ * 2);
    bf16*  hbuf  = (bf16*)alloc((size_t)M_ * DFF_ * 2);
    bf16*  y2b   = y1b;  // y1b dead after LN1

    // pack + transpose weights (one launch)
    pack_x_kernel<<<(M_ * D_) / 1024, 256, 0, stream>>>(x, Xb);
    wt_all_kernel<<<1728, 256, 0, stream>>>(Wq, Wk, Wv, Wo, W1, W2,
                                            Wqkvt, Wot, W1t, W2t);

    // QKV projection (+fused Q/K L2-norm) -> Qh/Kh [bh][s][dk], Vt [bh][dk][s]
    gemm_bt<0, 768, 128, 128, 2, 2><<<18 * 32, 256, 0, stream>>>(
        Xb, Wqkvt, bq, bk, bv, nullptr, nullptr, nullptr, Qh, Kh, Vt);

    // attention (128 q-rows per block, 16 blocks per bh)
    attn_kernel<<<16 * BH_, 256, 0, stream>>>(Qh, Kh, Vt, AO);

    // out projection + residual -> bf16, LN1  (64x64 counted-vmcnt dbuf)
    gemm_bt<1, 768, 64, 64, 2, 2><<<12 * 64, 256, 0, stream>>>(
        AO, Wot, bo, nullptr, nullptr, x, nullptr, y1b, nullptr, nullptr, nullptr);
    ln_kernel<true><<<M_, 256, 0, stream>>>(y1b, gamma, beta, nullptr, x1b);

    // FFN
    gemm_bt<2, 768, 128, 128, 2, 2><<<24 * 32, 256, 0, stream>>>(
        x1b, W1t, b1, nullptr, nullptr, nullptr, nullptr, hbuf, nullptr, nullptr, nullptr);
    gemm_bt<3, 3072, 64, 64, 2, 2><<<12 * 64, 256, 0, stream>>>(
        hbuf, W2t, b2, nullptr, nullptr, nullptr, x1b, y2b, nullptr, nullptr, nullptr);
    ln_kernel<false><<<M_, 256, 0, stream>>>(y2b, gamma, beta, (float*)d_out, nullptr);
}

// Round 12
// 180.945 us; speedup vs baseline: 1.4584x; 1.1307x over previous
//
#include <hip/hip_runtime.h>
#include <math.h>

// ---------------------------------------------------------------------------
// EncoderLayer: B=2,S=2048,D=768,H=12,DK=64,DFF=3072
// bf16 MFMA (16x16x32) for all matmuls, fp32 accumulate + fp32 pointwise.
// ---------------------------------------------------------------------------

using bf16   = __bf16;
using bf16x8 = __attribute__((ext_vector_type(8))) __bf16;
using bf16x4 = __attribute__((ext_vector_type(4))) __bf16;
using f32x4  = __attribute__((ext_vector_type(4))) float;

constexpr int S_   = 2048;
constexpr int D_   = 768;
constexpr int DFF_ = 3072;
constexpr int M_   = 4096;   // B*S
constexpr int BH_  = 24;     // B*H

__device__ __forceinline__ f32x4 mfma16(bf16x8 a, bf16x8 b, f32x4 c) {
    return __builtin_amdgcn_mfma_f32_16x16x32_bf16(a, b, c, 0, 0, 0);
}

// async global->LDS, 16B per lane; LDS dest wave-uniform, lane fills base+l*16
__device__ __forceinline__ void gload16(const bf16* g, bf16* l) {
    __builtin_amdgcn_global_load_lds(
        (const __attribute__((address_space(1))) void*)g,
        (__attribute__((address_space(3))) void*)l, 16, 0, 0);
}

template<int N> __device__ __forceinline__ void wait_vmcnt() {
    if constexpr (N == 0)      asm volatile("s_waitcnt vmcnt(0)" ::: "memory");
    else if constexpr (N == 4) asm volatile("s_waitcnt vmcnt(4)" ::: "memory");
    else if constexpr (N == 8) asm volatile("s_waitcnt vmcnt(8)" ::: "memory");
    else static_assert(N == 0, "unsupported vmcnt");
}
__device__ __forceinline__ void wait_lgkm0() {
    asm volatile("s_waitcnt lgkmcnt(0)" ::: "memory");
}

// bijective XCD-cluster swizzle; valid when nwg % 8 == 0
__device__ __forceinline__ int xcd_swz(int orig, int nwg) {
    return (orig & 7) * (nwg >> 3) + (orig >> 3);
}

// fast GELU (tanh form): v * sigmoid(1.5957691*(v + 0.044715 v^3)).
// |err| vs exact erf-GELU < ~1e-3 << 0.103 threshold; ~9 VALU vs erff ~28.
__device__ __forceinline__ float gelu_f(float v) {
    float y = 1.5957691f * (v + 0.044715f * v * v * v);
    return v / (1.0f + __expf(-y));
}

// ---------------------------------------------------------------------------
// pack x (fp32 -> bf16), 4 elems/thread
// ---------------------------------------------------------------------------
__global__ __launch_bounds__(256)
void pack_x_kernel(const float* __restrict__ x, bf16* __restrict__ xb) {
    const int i = blockIdx.x * 256 + threadIdx.x;
    float4 v = ((const float4*)x)[i];
    bf16x4 o;
    o[0] = (bf16)v.x; o[1] = (bf16)v.y; o[2] = (bf16)v.z; o[3] = (bf16)v.w;
    ((bf16x4*)xb)[i] = o;
}

// ---------------------------------------------------------------------------
// ALL weight transposes in one launch: in [K][N] fp32 -> out [N][K] bf16.
// 64x64 tiles, flat block index -> (matrix, tile).
// ---------------------------------------------------------------------------
__global__ __launch_bounds__(256)
void wt_all_kernel(const float* __restrict__ Wq, const float* __restrict__ Wk,
                   const float* __restrict__ Wv, const float* __restrict__ Wo,
                   const float* __restrict__ W1, const float* __restrict__ W2,
                   bf16* __restrict__ Wqkvt, bf16* __restrict__ Wot,
                   bf16* __restrict__ W1t, bf16* __restrict__ W2t) {
    int bid = blockIdx.x;
    const float* in; bf16* out; int K, N, t;
    if (bid < 576) {                       // Wq/Wk/Wv/Wo: 144 tiles each
        int m = bid / 144; t = bid % 144; K = 768; N = 768;
        in  = (m == 0) ? Wq : (m == 1) ? Wk : (m == 2) ? Wv : Wo;
        out = (m == 3) ? Wot : Wqkvt + (size_t)m * 768 * 768;
    } else if (bid < 1152) {               // W1: [768][3072] -> [3072][768]
        t = bid - 576; K = 768; N = 3072; in = W1; out = W1t;
    } else {                               // W2: [3072][768] -> [768][3072]
        t = bid - 1152; K = 3072; N = 768; in = W2; out = W2t;
    }
    const int ntx = N / 64;
    const int n0 = (t % ntx) * 64, k0 = (t / ntx) * 64;

    __shared__ __align__(16) bf16 T[64][72];
    const int tt = threadIdx.x;
    const int r  = tt >> 2, c0 = (tt & 3) * 16;
    const float* src = in + (size_t)(k0 + r) * N + n0 + c0;
#pragma unroll
    for (int j = 0; j < 16; j += 4) {
        float4 v = *(const float4*)(src + j);
        T[r][c0 + j + 0] = (bf16)v.x;
        T[r][c0 + j + 1] = (bf16)v.y;
        T[r][c0 + j + 2] = (bf16)v.z;
        T[r][c0 + j + 3] = (bf16)v.w;
    }
    __syncthreads();
    bf16x8 o0, o1;
#pragma unroll
    for (int j = 0; j < 8; j++) { o0[j] = T[c0 + j][r]; o1[j] = T[c0 + 8 + j][r]; }
    bf16* dst = out + (size_t)(n0 + r) * K + k0 + c0;
    *(bf16x8*)(dst)     = o0;
    *(bf16x8*)(dst + 8) = o1;
}

// ---------------------------------------------------------------------------
// GEMM: C = A[M,K] @ Bt[N,K]^T, BMxBN tile, BK=64, 4 waves in WRxWC grid.
// Staging: global_load_lds 16B/lane, coalesced 128B segments, with a
// WITHIN-SEGMENT XOR SWIZZLE (rule #21 both-sides pattern):
//   lane l sources global chunk (l&7)^((l>>3)&7) of its row ->
//   LDS[row][chunk] = global[row][chunk ^ (row&7)]  (linear LDS, HW write).
//   Fragment read of global[row][c*4+g] -> LDS chunk (c*4+g)^(q&7): the 16
//   q-lanes spread over all 8 chunk slots -> 2-way bank aliasing (free),
//   vs 16-way (5.7x) for the unswizzled layout. Coalescing unchanged
//   (permutation stays inside each 128B segment).
// Counted-vmcnt double-buffer pipeline: tiles t,t+1 always in flight.
// 1D grid + bijective XCD swizzle.
// EPI: 0=QKV (+bias, fused Q/K row-L2-norm, V written transposed),
//      1=Wo(+bias+fp32 resid)->bf16, 2=FFN1 fast-gelu->bf16,
//      3=FFN2(+bias+bf16 resid)->bf16
// ---------------------------------------------------------------------------
template<int EPI, int K, int BM, int BN, int WR, int WC>
__global__ __launch_bounds__(256)
void gemm_bt(const bf16* __restrict__ A, const bf16* __restrict__ Bt,
             const float* __restrict__ bias0, const float* __restrict__ bias1,
             const float* __restrict__ bias2, const float* __restrict__ residf,
             const bf16* __restrict__ residb, bf16* __restrict__ outb,
             bf16* __restrict__ qo, bf16* __restrict__ ko, bf16* __restrict__ vo) {
    constexpr int MR  = BM / WR / 16;
    constexpr int NR  = BN / WC / 16;
    constexpr int GA  = BM / 32;          // gload16 per wave for A tile
    constexpr int GB  = BN / 32;
    constexpr int NPT = GA + GB;          // this wave's loads per K-tile
    constexpr int NCOL = (EPI == 0) ? 2304 : (EPI == 2) ? 3072 : 768;
    constexpr int NBX  = NCOL / BN;
    __shared__ __align__(16) bf16 Al[2 * BM * 64];
    __shared__ __align__(16) bf16 Bl[2 * BN * 64];
    const int tid  = threadIdx.x;
    const int lane = tid & 63, w = tid >> 6;
    const int wr = w / WC, wc = w % WC;
    const int wg = xcd_swz(blockIdx.x, gridDim.x);
    const int m0 = (wg / NBX) * BM, n0 = (wg % NBX) * BN;
    const int g = lane >> 4, q = lane & 15;
    const int srow = lane >> 3;
    // within-segment XOR-swizzled source chunk (elements)
    const int schunk = (((lane & 7) ^ ((lane >> 3) & 7))) * 8;

    f32x4 acc[MR][NR] = {};

    const bf16* gaA = A  + (long)(m0 + w * (BM / 4) + srow) * K + schunk;
    const bf16* gaB = Bt + (long)(n0 + w * (BN / 4) + srow) * K + schunk;

    auto stage = [&](int buf, int kt) {
#pragma unroll
        for (int i = 0; i < GA; i++)
            gload16(gaA + kt + (long)i * 8 * K,
                    &Al[buf * BM * 64 + (w * (BM / 4) + i * 8) * 64]);
#pragma unroll
        for (int i = 0; i < GB; i++)
            gload16(gaB + kt + (long)i * 8 * K,
                    &Bl[buf * BN * 64 + (w * (BN / 4) + i * 8) * 64]);
    };
    auto compute = [&](int buf) {
#pragma unroll
        for (int c = 0; c < 2; c++) {
            // swizzled read: chunk (c*4+g) of row lives at chunk^(row&7)
            const int rch = ((c * 4 + g) ^ (q & 7)) * 8;
            bf16x8 af[MR], bfr[NR];
#pragma unroll
            for (int i = 0; i < MR; i++)
                af[i] = *(const bf16x8*)
                    &Al[buf * BM * 64 + (wr * (BM / WR) + i * 16 + q) * 64 + rch];
#pragma unroll
            for (int i = 0; i < NR; i++)
                bfr[i] = *(const bf16x8*)
                    &Bl[buf * BN * 64 + (wc * (BN / WC) + i * 16 + q) * 64 + rch];
#pragma unroll
            for (int mi = 0; mi < MR; mi++)
#pragma unroll
                for (int ni = 0; ni < NR; ni++)
                    acc[mi][ni] = mfma16(af[mi], bfr[ni], acc[mi][ni]);
        }
    };

    // counted-vmcnt pipeline: tiles t and t+1 always in flight
    stage(0, 0);
    stage(1, 64);
    int cur = 0;
    for (int kt = 0; kt < K - 64; kt += 64) {
        wait_vmcnt<NPT>();                 // tile kt landed; kt+64 in flight
        __builtin_amdgcn_s_barrier();
        compute(cur);
        wait_lgkm0();
        __builtin_amdgcn_s_barrier();
        if (kt + 128 < K) stage(cur, kt + 128);
        cur ^= 1;
    }
    wait_vmcnt<0>();
    __builtin_amdgcn_s_barrier();
    compute(cur);

    // epilogue: C/D frag layout col = lane&15, row = (lane>>4)*4 + r
#pragma unroll
    for (int mi = 0; mi < MR; mi++) {
        if (EPI == 0) {
            // one wave spans exactly one head's 64 cols (BN/WC == 64)
            const int col0  = n0 + wc * 64;
            const int which = (col0 >= 1536) ? 2 : (col0 >= 768 ? 1 : 0);
            const int row0  = m0 + wr * (BM / WR) + mi * 16 + g * 4;
            float val[NR][4];
#pragma unroll
            for (int ni = 0; ni < NR; ni++) {
                const int dd = col0 + ni * 16 + q - which * 768;
                const float bias = (which == 0 ? bias0 : which == 1 ? bias1 : bias2)[dd];
#pragma unroll
                for (int r = 0; r < 4; r++) val[ni][r] = acc[mi][ni][r] + bias;
            }
            if (which <= 1) {   // fused per-row L2 norm over the head's 64 dims
#pragma unroll
                for (int r = 0; r < 4; r++) {
                    float ss = val[0][r] * val[0][r];
#pragma unroll
                    for (int ni = 1; ni < NR; ni++) ss += val[ni][r] * val[ni][r];
                    ss += __shfl_xor(ss, 1);
                    ss += __shfl_xor(ss, 2);
                    ss += __shfl_xor(ss, 4);
                    ss += __shfl_xor(ss, 8);
                    const float rn = 1.0f / fmaxf(sqrtf(ss), 1e-12f);
#pragma unroll
                    for (int ni = 0; ni < NR; ni++) val[ni][r] *= rn;
                }
            }
            const int dd0 = col0 - which * 768;
            const int hh  = dd0 >> 6;
            const long bh = (long)(row0 >> 11) * 12 + hh;
#pragma unroll
            for (int ni = 0; ni < NR; ni++) {
                const int dk = ni * 16 + q;
                if (which == 2) {
                    bf16x4 pv;
#pragma unroll
                    for (int r = 0; r < 4; r++) pv[r] = (bf16)val[ni][r];
                    *(bf16x4*)&vo[(bh * 64 + dk) * 2048 + (row0 & 2047)] = pv;
                } else {
                    bf16* dst = (which == 0) ? qo : ko;
#pragma unroll
                    for (int r = 0; r < 4; r++)
                        dst[(bh * 2048 + ((row0 + r) & 2047)) * 64 + dk] = (bf16)val[ni][r];
                }
            }
        } else {
#pragma unroll
            for (int ni = 0; ni < NR; ni++) {
                const int col  = n0 + wc * (BN / WC) + ni * 16 + q;
                const int row0 = m0 + wr * (BM / WR) + mi * 16 + g * 4;
                const float bias = bias0[col];
                if (EPI == 1) {          // + fp32 residual -> bf16
#pragma unroll
                    for (int r = 0; r < 4; r++) {
                        const int row = row0 + r;
                        outb[(long)row * 768 + col] =
                            (bf16)(acc[mi][ni][r] + bias + residf[(long)row * 768 + col]);
                    }
                } else if (EPI == 3) {   // + bf16 residual -> bf16
#pragma unroll
                    for (int r = 0; r < 4; r++) {
                        const int row = row0 + r;
                        outb[(long)row * 768 + col] =
                            (bf16)(acc[mi][ni][r] + bias + (float)residb[(long)row * 768 + col]);
                    }
                } else {                 // EPI == 2: fast GELU -> bf16
#pragma unroll
                    for (int r = 0; r < 4; r++) {
                        const float v = acc[mi][ni][r] + bias;
                        outb[(long)(row0 + r) * 3072 + col] = (bf16)gelu_f(v);
                    }
                }
            }
        }
    }
}

// ---------------------------------------------------------------------------
// Attention (no softmax): O = (Qn Kn^T)^2 @ V  per (b,h).
// Block = 4 waves x 32 q-rows = 128 q-rows; 64-key tiles; dbuf LDS staging.
// Each wave computes TWO 16-row Q fragments against the shared K/V tiles.
// Swapped QK^T -> P k-contiguous in wave-private padded LDS -> PV A-frag.
// 1D grid (16 qblocks x 24 bh) + XCD swizzle.
// ---------------------------------------------------------------------------
__global__ __launch_bounds__(256, 2)
void attn_kernel(const bf16* __restrict__ Qn, const bf16* __restrict__ Kn,
                 const bf16* __restrict__ Vt, bf16* __restrict__ AO) {
    const int wg  = xcd_swz(blockIdx.x, gridDim.x);
    const int bh  = wg >> 4;
    const int tid = threadIdx.x, lane = tid & 63, w = tid >> 6;
    const int g = lane >> 4, q15 = lane & 15;
    const int qbase = (wg & 15) * 128 + w * 32;

    __shared__ __align__(16) bf16 Kl[2][64][72];
    __shared__ __align__(16) bf16 Vl[2][64][72];
    __shared__ __align__(16) bf16 Pl[4][32][72];
    bf16 (*Pw)[72] = Pl[w];

    const bf16* Qp = Qn + (long)bh * S_ * 64;
    const bf16* Kp = Kn + (long)bh * S_ * 64;
    const bf16* Vp = Vt + (long)bh * 64 * S_;

    const int srow = tid >> 3, scol = (tid & 7) * 8;   // staging coords

    bf16x8 qf00 = *(const bf16x8*)&Qp[(long)(qbase + q15) * 64 + g * 8];
    bf16x8 qf01 = *(const bf16x8*)&Qp[(long)(qbase + q15) * 64 + 32 + g * 8];
    bf16x8 qf10 = *(const bf16x8*)&Qp[(long)(qbase + 16 + q15) * 64 + g * 8];
    bf16x8 qf11 = *(const bf16x8*)&Qp[(long)(qbase + 16 + q15) * 64 + 32 + g * 8];

    f32x4 o0[4] = {}, o1[4] = {};

    bf16x8 aK0, aK1, aV0, aV1, bK0, bK1, bV0, bV1;
    auto gloadA = [&](int kt) {
        aK0 = *(const bf16x8*)&Kp[(long)(kt + srow) * 64 + scol];
        aK1 = *(const bf16x8*)&Kp[(long)(kt + 32 + srow) * 64 + scol];
        aV0 = *(const bf16x8*)&Vp[(long)srow * S_ + kt + scol];
        aV1 = *(const bf16x8*)&Vp[(long)(32 + srow) * S_ + kt + scol];
    };
    auto gloadB = [&](int kt) {
        bK0 = *(const bf16x8*)&Kp[(long)(kt + srow) * 64 + scol];
        bK1 = *(const bf16x8*)&Kp[(long)(kt + 32 + srow) * 64 + scol];
        bV0 = *(const bf16x8*)&Vp[(long)srow * S_ + kt + scol];
        bV1 = *(const bf16x8*)&Vp[(long)(32 + srow) * S_ + kt + scol];
    };
    auto stageA = [&](int buf) {
        *(bf16x8*)&Kl[buf][srow][scol]      = aK0;
        *(bf16x8*)&Kl[buf][32 + srow][scol] = aK1;
        *(bf16x8*)&Vl[buf][srow][scol]      = aV0;
        *(bf16x8*)&Vl[buf][32 + srow][scol] = aV1;
    };
    auto stageB = [&](int buf) {
        *(bf16x8*)&Kl[buf][srow][scol]      = bK0;
        *(bf16x8*)&Kl[buf][32 + srow][scol] = bK1;
        *(bf16x8*)&Vl[buf][srow][scol]      = bV0;
        *(bf16x8*)&Vl[buf][32 + srow][scol] = bV1;
    };

    auto compute = [&](int cur) {
        bf16x8 kf[4][2];
#pragma unroll
        for (int ni = 0; ni < 4; ni++)
#pragma unroll
            for (int c = 0; c < 2; c++)
                kf[ni][c] = *(const bf16x8*)&Kl[cur][ni * 16 + q15][c * 32 + g * 8];
        f32x4 s0[4], s1[4];
#pragma unroll
        for (int ni = 0; ni < 4; ni++) {
            s0[ni] = mfma16(kf[ni][0], qf00, f32x4{0.f, 0.f, 0.f, 0.f});
            s0[ni] = mfma16(kf[ni][1], qf01, s0[ni]);
            s1[ni] = mfma16(kf[ni][0], qf10, f32x4{0.f, 0.f, 0.f, 0.f});
            s1[ni] = mfma16(kf[ni][1], qf11, s1[ni]);
        }
#pragma unroll
        for (int ni = 0; ni < 4; ni++) {
            bf16x4 p0, p1;
#pragma unroll
            for (int r = 0; r < 4; r++) {
                float v0 = s0[ni][r]; p0[r] = (bf16)(v0 * v0);
                float v1 = s1[ni][r]; p1[r] = (bf16)(v1 * v1);
            }
            *(bf16x4*)&Pw[q15][ni * 16 + g * 4]      = p0;
            *(bf16x4*)&Pw[16 + q15][ni * 16 + g * 4] = p1;
        }
        bf16x8 pf00 = *(const bf16x8*)&Pw[q15][g * 8];
        bf16x8 pf01 = *(const bf16x8*)&Pw[q15][32 + g * 8];
        bf16x8 pf10 = *(const bf16x8*)&Pw[16 + q15][g * 8];
        bf16x8 pf11 = *(const bf16x8*)&Pw[16 + q15][32 + g * 8];
        bf16x8 vf[4][2];
#pragma unroll
        for (int ni = 0; ni < 4; ni++)
#pragma unroll
            for (int c = 0; c < 2; c++)
                vf[ni][c] = *(const bf16x8*)&Vl[cur][ni * 16 + q15][c * 32 + g * 8];
#pragma unroll
        for (int ni = 0; ni < 4; ni++) {
            o0[ni] = mfma16(pf00, vf[ni][0], o0[ni]);
            o0[ni] = mfma16(pf01, vf[ni][1], o0[ni]);
            o1[ni] = mfma16(pf10, vf[ni][0], o1[ni]);
            o1[ni] = mfma16(pf11, vf[ni][1], o1[ni]);
        }
    };

    gloadA(0);
    stageA(0);
    gloadB(64);
    __syncthreads();
    for (int t = 0; t <= 28; t += 2) {
        stageB(1);
        gloadA((t + 2) * 64);
        compute(0);
        __syncthreads();
        stageA(0);
        if (t + 3 < 32) gloadB((t + 3) * 64);
        compute(1);
        __syncthreads();
    }
    stageB(1);
    compute(0);
    __syncthreads();
    compute(1);

    const int b = bh / 12, h = bh % 12;
#pragma unroll
    for (int ni = 0; ni < 4; ni++)
#pragma unroll
        for (int r = 0; r < 4; r++) {
            const int s0r = qbase + g * 4 + r;
            AO[((long)b * S_ + s0r) * D_ + h * 64 + ni * 16 + q15] = (bf16)o0[ni][r];
            const int s1r = qbase + 16 + g * 4 + r;
            AO[((long)b * S_ + s1r) * D_ + h * 64 + ni * 16 + q15] = (bf16)o1[ni][r];
        }
}

// ---------------------------------------------------------------------------
// LayerNorm over D=768 (bf16 input). One block per row, 256 threads.
// WB=true: write bf16 only (mid-layer). WB=false: write fp32 (final out).
// ---------------------------------------------------------------------------
template<bool WB>
__global__ __launch_bounds__(256)
void ln_kernel(const bf16* __restrict__ y, const float* __restrict__ gamma,
               const float* __restrict__ beta, float* __restrict__ xo,
               bf16* __restrict__ xob) {
    __shared__ float sa[4], sb[4];
    const int row = blockIdx.x, t = threadIdx.x;
    const bf16* yr = y + (long)row * 768;
    float v0 = (float)yr[t], v1 = (float)yr[t + 256], v2 = (float)yr[t + 512];
    float s  = v0 + v1 + v2;
    float ss = v0 * v0 + v1 * v1 + v2 * v2;
#pragma unroll
    for (int o = 32; o; o >>= 1) { s += __shfl_xor(s, o); ss += __shfl_xor(ss, o); }
    if ((t & 63) == 0) { sa[t >> 6] = s; sb[t >> 6] = ss; }
    __syncthreads();
    s  = sa[0] + sa[1] + sa[2] + sa[3];
    ss = sb[0] + sb[1] + sb[2] + sb[3];
    const float mu   = s * (1.0f / 768.0f);
    const float var  = ss * (1.0f / 768.0f) - mu * mu;
    const float rstd = rsqrtf(var + 1e-5f);
#pragma unroll
    for (int i = 0; i < 3; i++) {
        const int c = t + i * 256;
        const float vv = (i == 0) ? v0 : (i == 1) ? v1 : v2;
        const float ov = (vv - mu) * rstd * gamma[c] + beta[c];
        if (WB) xob[(long)row * 768 + c] = (bf16)ov;
        else    xo[(long)row * 768 + c] = ov;
    }
}

// ---------------------------------------------------------------------------
extern "C" void kernel_launch(void* const* d_in, const int* in_sizes, int n_in,
                              void* d_out, int out_size, void* d_ws, size_t ws_size,
                              hipStream_t stream) {
    const float* x     = (const float*)d_in[0];
    const float* Wq    = (const float*)d_in[1];
    const float* bq    = (const float*)d_in[2];
    const float* Wk    = (const float*)d_in[3];
    const float* bk    = (const float*)d_in[4];
    const float* Wv    = (const float*)d_in[5];
    const float* bv    = (const float*)d_in[6];
    const float* Wo    = (const float*)d_in[7];
    const float* bo    = (const float*)d_in[8];
    const float* W1    = (const float*)d_in[9];
    const float* b1    = (const float*)d_in[10];
    const float* W2    = (const float*)d_in[11];
    const float* b2    = (const float*)d_in[12];
    const float* gamma = (const float*)d_in[13];
    const float* beta  = (const float*)d_in[14];

    char* p = (char*)d_ws;
    auto alloc = [&](size_t bytes) -> void* {
        void* r = p;
        p += (bytes + 255) & ~(size_t)255;
        return r;
    };
    bf16*  Xb    = (bf16*)alloc((size_t)M_ * D_ * 2);
    bf16*  Wqkvt = (bf16*)alloc((size_t)2304 * 768 * 2);
    bf16*  Wot   = (bf16*)alloc((size_t)768 * 768 * 2);
    bf16*  W1t   = (bf16*)alloc((size_t)3072 * 768 * 2);
    bf16*  W2t   = (bf16*)alloc((size_t)768 * 3072 * 2);
    bf16*  Qh    = (bf16*)alloc((size_t)BH_ * S_ * 64 * 2);
    bf16*  Kh    = (bf16*)alloc((size_t)BH_ * S_ * 64 * 2);
    bf16*  Vt    = (bf16*)alloc((size_t)BH_ * S_ * 64 * 2);
    bf16*  AO    = (bf16*)alloc((size_t)M_ * D_ * 2);
    bf16*  y1b   = (bf16*)alloc((size_t)M_ * D_ * 2);
    bf16*  x1b   = (bf16*)alloc((size_t)M_ * D_ * 2);
    bf16*  hbuf  = (bf16*)alloc((size_t)M_ * DFF_ * 2);
    bf16*  y2b   = y1b;  // y1b dead after LN1

    // pack + transpose weights (one launch)
    pack_x_kernel<<<(M_ * D_) / 1024, 256, 0, stream>>>(x, Xb);
    wt_all_kernel<<<1728, 256, 0, stream>>>(Wq, Wk, Wv, Wo, W1, W2,
                                            Wqkvt, Wot, W1t, W2t);

    // QKV projection (+fused Q/K L2-norm) -> Qh/Kh [bh][s][dk], Vt [bh][dk][s]
    gemm_bt<0, 768, 128, 128, 2, 2><<<18 * 32, 256, 0, stream>>>(
        Xb, Wqkvt, bq, bk, bv, nullptr, nullptr, nullptr, Qh, Kh, Vt);

    // attention (128 q-rows per block, 16 blocks per bh)
    attn_kernel<<<16 * BH_, 256, 0, stream>>>(Qh, Kh, Vt, AO);

    // out projection + residual -> bf16, LN1  (64x64 counted-vmcnt dbuf)
    gemm_bt<1, 768, 64, 64, 2, 2><<<12 * 64, 256, 0, stream>>>(
        AO, Wot, bo, nullptr, nullptr, x, nullptr, y1b, nullptr, nullptr, nullptr);
    ln_kernel<true><<<M_, 256, 0, stream>>>(y1b, gamma, beta, nullptr, x1b);

    // FFN
    gemm_bt<2, 768, 128, 128, 2, 2><<<24 * 32, 256, 0, stream>>>(
        x1b, W1t, b1, nullptr, nullptr, nullptr, nullptr, hbuf, nullptr, nullptr, nullptr);
    gemm_bt<3, 3072, 64, 64, 2, 2><<<12 * 64, 256, 0, stream>>>(
        hbuf, W2t, b2, nullptr, nullptr, nullptr, x1b, y2b, nullptr, nullptr, nullptr);
    ln_kernel<false><<<M_, 256, 0, stream>>>(y2b, gamma, beta, (float*)d_out, nullptr);
}

// Round 13
// 175.119 us; speedup vs baseline: 1.5069x; 1.0333x over previous
//
#include <hip/hip_runtime.h>
#include <math.h>

using bf16   = __bf16;
using bf16x8 = __attribute__((ext_vector_type(8))) __bf16;
using bf16x4 = __attribute__((ext_vector_type(4))) __bf16;
using f32x4  = __attribute__((ext_vector_type(4))) float;

constexpr int S_   = 2048;
constexpr int D_   = 768;
constexpr int DFF_ = 3072;
constexpr int M_   = 4096;   // B*S
constexpr int BH_  = 24;     // B*H

__device__ __forceinline__ f32x4 mfma16(bf16x8 a, bf16x8 b, f32x4 c) {
    return __builtin_amdgcn_mfma_f32_16x16x32_bf16(a, b, c, 0, 0, 0);
}

__device__ __forceinline__ void gload16(const bf16* g, bf16* l) {
    __builtin_amdgcn_global_load_lds(
        (const __attribute__((address_space(1))) void*)g,
        (__attribute__((address_space(3))) void*)l, 16, 0, 0);
}

template<int N> __device__ __forceinline__ void wait_vmcnt() {
    if constexpr (N == 0)      asm volatile("s_waitcnt vmcnt(0)" ::: "memory");
    else if constexpr (N == 4) asm volatile("s_waitcnt vmcnt(4)" ::: "memory");
    else if constexpr (N == 8) asm volatile("s_waitcnt vmcnt(8)" ::: "memory");
    else static_assert(N == 0, "unsupported vmcnt");
}
__device__ __forceinline__ void wait_lgkm0() {
    asm volatile("s_waitcnt lgkmcnt(0)" ::: "memory");
}

__device__ __forceinline__ int xcd_swz(int orig, int nwg) {
    return (orig & 7) * (nwg >> 3) + (orig >> 3);
}

__device__ __forceinline__ float gelu_f(float v) {
    float y = 1.5957691f * (v + 0.044715f * v * v * v);
    return v / (1.0f + __expf(-y));
}

__global__ __launch_bounds__(256)
void pack_x_kernel(const float* __restrict__ x, bf16* __restrict__ xb) {
    const int i = blockIdx.x * 256 + threadIdx.x;
    float4 v = ((const float4*)x)[i];
    bf16x4 o;
    o[0] = (bf16)v.x; o[1] = (bf16)v.y; o[2] = (bf16)v.z; o[3] = (bf16)v.w;
    ((bf16x4*)xb)[i] = o;
}

__global__ __launch_bounds__(256)
void merge_ao_kernel(const bf16* __restrict__ a, const bf16* __restrict__ b,
                     bf16* __restrict__ o) {
    const long i = ((long)blockIdx.x * 256 + threadIdx.x) * 8;
    bf16x8 va = *(const bf16x8*)&a[i];
    bf16x8 vb = *(const bf16x8*)&b[i];
    bf16x8 vo;
#pragma unroll
    for (int j = 0; j < 8; j++) vo[j] = (bf16)((float)va[j] + (float)vb[j]);
    *(bf16x8*)&o[i] = vo;
}

__global__ __launch_bounds__(256)
void wt_all_kernel(const float* __restrict__ Wq, const float* __restrict__ Wk,
                   const float* __restrict__ Wv, const float* __restrict__ Wo,
                   const float* __restrict__ W1, const float* __restrict__ W2,
                   bf16* __restrict__ Wqkvt, bf16* __restrict__ Wot,
                   bf16* __restrict__ W1t, bf16* __restrict__ W2t) {
    int bid = blockIdx.x;
    const float* in; bf16* out; int K, N, t;
    if (bid < 576) {
        int m = bid / 144; t = bid % 144; K = 768; N = 768;
        in  = (m == 0) ? Wq : (m == 1) ? Wk : (m == 2) ? Wv : Wo;
        out = (m == 3) ? Wot : Wqkvt + (size_t)m * 768 * 768;
    } else if (bid < 1152) {
        t = bid - 576; K = 768; N = 3072; in = W1; out = W1t;
    } else {
        t = bid - 1152; K = 3072; N = 768; in = W2; out = W2t;
    }
    const int ntx = N / 64;
    const int n0 = (t % ntx) * 64, k0 = (t / ntx) * 64;

    __shared__ __align__(16) bf16 T[64][72];
    const int tt = threadIdx.x;
    const int r  = tt >> 2, c0 = (tt & 3) * 16;
    const float* src = in + (size_t)(k0 + r) * N + n0 + c0;
#pragma unroll
    for (int j = 0; j < 16; j += 4) {
        float4 v = *(const float4*)(src + j);
        T[r][c0 + j + 0] = (bf16)v.x;
        T[r][c0 + j + 1] = (bf16)v.y;
        T[r][c0 + j + 2] = (bf16)v.z;
        T[r][c0 + j + 3] = (bf16)v.w;
    }
    __syncthreads();
    bf16x8 o0, o1;
#pragma unroll
    for (int j = 0; j < 8; j++) { o0[j] = T[c0 + j][r]; o1[j] = T[c0 + 8 + j][r]; }
    bf16* dst = out + (size_t)(n0 + r) * K + k0 + c0;
    *(bf16x8*)(dst)     = o0;
    *(bf16x8*)(dst + 8) = o1;
}

template<int EPI, int K, int BM, int BN, int WR, int WC>
__global__ __launch_bounds__(256)
void gemm_bt(const bf16* __restrict__ A, const bf16* __restrict__ Bt,
             const float* __restrict__ bias0, const float* __restrict__ bias1,
             const float* __restrict__ bias2, const float* __restrict__ residf,
             const bf16* __restrict__ residb, bf16* __restrict__ outb,
             bf16* __restrict__ qo, bf16* __restrict__ ko, bf16* __restrict__ vo) {
    constexpr int MR  = BM / WR / 16;
    constexpr int NR  = BN / WC / 16;
    constexpr int GA  = BM / 32;
    constexpr int GB  = BN / 32;
    constexpr int NPT = GA + GB;
    constexpr int NCOL = (EPI == 0) ? 2304 : (EPI == 2) ? 3072 : 768;
    constexpr int NBX  = NCOL / BN;
    __shared__ __align__(16) bf16 Al[2 * BM * 64];
    __shared__ __align__(16) bf16 Bl[2 * BN * 64];
    const int tid  = threadIdx.x;
    const int lane = tid & 63, w = tid >> 6;
    const int wr = w / WC, wc = w % WC;
    const int wg = xcd_swz(blockIdx.x, gridDim.x);
    const int m0 = (wg / NBX) * BM, n0 = (wg % NBX) * BN;
    const int g = lane >> 4, q = lane & 15;
    const int srow = lane >> 3;
    const int schunk = (((lane & 7) ^ ((lane >> 3) & 7))) * 8;

    f32x4 acc[MR][NR] = {};

    const bf16* gaA = A  + (long)(m0 + w * (BM / 4) + srow) * K + schunk;
    const bf16* gaB = Bt + (long)(n0 + w * (BN / 4) + srow) * K + schunk;

    auto stage = [&](int buf, int kt) {
#pragma unroll
        for (int i = 0; i < GA; i++)
            gload16(gaA + kt + (long)i * 8 * K,
                    &Al[buf * BM * 64 + (w * (BM / 4) + i * 8) * 64]);
#pragma unroll
        for (int i = 0; i < GB; i++)
            gload16(gaB + kt + (long)i * 8 * K,
                    &Bl[buf * BN * 64 + (w * (BN / 4) + i * 8) * 64]);
    };
    auto compute = [&](int buf) {
#pragma unroll
        for (int c = 0; c < 2; c++) {
            const int rch = ((c * 4 + g) ^ (q & 7)) * 8;
            bf16x8 af[MR], bfr[NR];
#pragma unroll
            for (int i = 0; i < MR; i++)
                af[i] = *(const bf16x8*)
                    &Al[buf * BM * 64 + (wr * (BM / WR) + i * 16 + q) * 64 + rch];
#pragma unroll
            for (int i = 0; i < NR; i++)
                bfr[i] = *(const bf16x8*)
                    &Bl[buf * BN * 64 + (wc * (BN / WC) + i * 16 + q) * 64 + rch];
#pragma unroll
            for (int mi = 0; mi < MR; mi++)
#pragma unroll
                for (int ni = 0; ni < NR; ni++)
                    acc[mi][ni] = mfma16(af[mi], bfr[ni], acc[mi][ni]);
        }
    };

    stage(0, 0);
    stage(1, 64);
    int cur = 0;
    for (int kt = 0; kt < K - 64; kt += 64) {
        wait_vmcnt<NPT>();
        __builtin_amdgcn_s_barrier();
        compute(cur);
        wait_lgkm0();
        __builtin_amdgcn_s_barrier();
        if (kt + 128 < K) stage(cur, kt + 128);
        cur ^= 1;
    }
    wait_vmcnt<0>();
    __builtin_amdgcn_s_barrier();
    compute(cur);

#pragma unroll
    for (int mi = 0; mi < MR; mi++) {
        if (EPI == 0) {
            const int col0  = n0 + wc * 64;
            const int which = (col0 >= 1536) ? 2 : (col0 >= 768 ? 1 : 0);
            const int row0  = m0 + wr * (BM / WR) + mi * 16 + g * 4;
            float val[NR][4];
#pragma unroll
            for (int ni = 0; ni < NR; ni++) {
                const int dd = col0 + ni * 16 + q - which * 768;
                const float bias = (which == 0 ? bias0 : which == 1 ? bias1 : bias2)[dd];
#pragma unroll
                for (int r = 0; r < 4; r++) val[ni][r] = acc[mi][ni][r] + bias;
            }
            if (which <= 1) {
#pragma unroll
                for (int r = 0; r < 4; r++) {
                    float ss = val[0][r] * val[0][r];
#pragma unroll
                    for (int ni = 1; ni < NR; ni++) ss += val[ni][r] * val[ni][r];
                    ss += __shfl_xor(ss, 1);
                    ss += __shfl_xor(ss, 2);
                    ss += __shfl_xor(ss, 4);
                    ss += __shfl_xor(ss, 8);
                    const float rn = 1.0f / fmaxf(sqrtf(ss), 1e-12f);
#pragma unroll
                    for (int ni = 0; ni < NR; ni++) val[ni][r] *= rn;
                }
            }
            const int dd0 = col0 - which * 768;
            const int hh  = dd0 >> 6;
            const long bh = (long)(row0 >> 11) * 12 + hh;
#pragma unroll
            for (int ni = 0; ni < NR; ni++) {
                const int dk = ni * 16 + q;
                if (which == 2) {
                    bf16x4 pv;
#pragma unroll
                    for (int r = 0; r < 4; r++) pv[r] = (bf16)val[ni][r];
                    *(bf16x4*)&vo[(bh * 64 + dk) * 2048 + (row0 & 2047)] = pv;
                } else {
                    bf16* dst = (which == 0) ? qo : ko;
#pragma unroll
                    for (int r = 0; r < 4; r++)
                        dst[(bh * 2048 + ((row0 + r) & 2047)) * 64 + dk] = (bf16)val[ni][r];
                }
            }
        } else {
#pragma unroll
            for (int ni = 0; ni < NR; ni++) {
                const int col  = n0 + wc * (BN / WC) + ni * 16 + q;
                const int row0 = m0 + wr * (BM / WR) + mi * 16 + g * 4;
                const float bias = bias0[col];
                if (EPI == 1) {
#pragma unroll
                    for (int r = 0; r < 4; r++) {
                        const int row = row0 + r;
                        outb[(long)row * 768 + col] =
                            (bf16)(acc[mi][ni][r] + bias + residf[(long)row * 768 + col]);
                    }
                } else if (EPI == 3) {
#pragma unroll
                    for (int r = 0; r < 4; r++) {
                        const int row = row0 + r;
                        outb[(long)row * 768 + col] =
                            (bf16)(acc[mi][ni][r] + bias + (float)residb[(long)row * 768 + col]);
                    }
                } else {
#pragma unroll
                    for (int r = 0; r < 4; r++) {
                        const float v = acc[mi][ni][r] + bias;
                        outb[(long)(row0 + r) * 3072 + col] = (bf16)gelu_f(v);
                    }
                }
            }
        }
    }
}

// ---------------------------------------------------------------------------
// Attention split-K over keys (PV is linear, no softmax). Grid = 768 blocks
// (2 kv-halves x 16 qblocks x 24 bh) = 3 blocks/CU at LDS 45KB.
// Block = 4 waves x 32 q-rows; 16 key-tiles of 64; dbuf K/V staging.
// P round-trip reuses one [16][72] wave-private buffer for both q-halves
// sequentially (per-wave DS ops are in-order). Partial O -> AOp[kvhalf].
// ---------------------------------------------------------------------------
__global__ __launch_bounds__(256, 3)
void attn_kernel(const bf16* __restrict__ Qn, const bf16* __restrict__ Kn,
                 const bf16* __restrict__ Vt, bf16* __restrict__ AOp) {
    const int wg  = xcd_swz(blockIdx.x, gridDim.x);
    const int bh  = wg >> 5;
    const int rem = wg & 31;
    const int kvhalf = rem >> 4;
    const int qblk   = rem & 15;
    const int tid = threadIdx.x, lane = tid & 63, w = tid >> 6;
    const int g = lane >> 4, q15 = lane & 15;
    const int qbase = qblk * 128 + w * 32;
    const int kv0   = kvhalf * 1024;
    constexpr int NT = 16;

    __shared__ __align__(16) bf16 Kl[2][64][72];
    __shared__ __align__(16) bf16 Vl[2][64][72];
    __shared__ __align__(16) bf16 Pl[4][16][72];
    bf16 (*Pw)[72] = Pl[w];

    const bf16* Qp = Qn + (long)bh * S_ * 64;
    const bf16* Kp = Kn + (long)bh * S_ * 64 + (long)kv0 * 64;
    const bf16* Vp = Vt + (long)bh * 64 * S_ + kv0;
    bf16* AOo = AOp + (long)kvhalf * M_ * D_;

    const int srow = tid >> 3, scol = (tid & 7) * 8;

    bf16x8 qf00 = *(const bf16x8*)&Qp[(long)(qbase + q15) * 64 + g * 8];
    bf16x8 qf01 = *(const bf16x8*)&Qp[(long)(qbase + q15) * 64 + 32 + g * 8];
    bf16x8 qf10 = *(const bf16x8*)&Qp[(long)(qbase + 16 + q15) * 64 + g * 8];
    bf16x8 qf11 = *(const bf16x8*)&Qp[(long)(qbase + 16 + q15) * 64 + 32 + g * 8];

    f32x4 o0[4] = {}, o1[4] = {};

    bf16x8 aK0, aK1, aV0, aV1, bK0, bK1, bV0, bV1;
    auto gloadA = [&](int kt) {
        aK0 = *(const bf16x8*)&Kp[(long)(kt + srow) * 64 + scol];
        aK1 = *(const bf16x8*)&Kp[(long)(kt + 32 + srow) * 64 + scol];
        aV0 = *(const bf16x8*)&Vp[(long)srow * S_ + kt + scol];
        aV1 = *(const bf16x8*)&Vp[(long)(32 + srow) * S_ + kt + scol];
    };
    auto gloadB = [&](int kt) {
        bK0 = *(const bf16x8*)&Kp[(long)(kt + srow) * 64 + scol];
        bK1 = *(const bf16x8*)&Kp[(long)(kt + 32 + srow) * 64 + scol];
        bV0 = *(const bf16x8*)&Vp[(long)srow * S_ + kt + scol];
        bV1 = *(const bf16x8*)&Vp[(long)(32 + srow) * S_ + kt + scol];
    };
    auto stageA = [&](int buf) {
        *(bf16x8*)&Kl[buf][srow][scol]      = aK0;
        *(bf16x8*)&Kl[buf][32 + srow][scol] = aK1;
        *(bf16x8*)&Vl[buf][srow][scol]      = aV0;
        *(bf16x8*)&Vl[buf][32 + srow][scol] = aV1;
    };
    auto stageB = [&](int buf) {
        *(bf16x8*)&Kl[buf][srow][scol]      = bK0;
        *(bf16x8*)&Kl[buf][32 + srow][scol] = bK1;
        *(bf16x8*)&Vl[buf][srow][scol]      = bV0;
        *(bf16x8*)&Vl[buf][32 + srow][scol] = bV1;
    };

    auto compute = [&](int cur) {
        bf16x8 kf[4][2];
#pragma unroll
        for (int ni = 0; ni < 4; ni++)
#pragma unroll
            for (int c = 0; c < 2; c++)
                kf[ni][c] = *(const bf16x8*)&Kl[cur][ni * 16 + q15][c * 32 + g * 8];
        f32x4 s0[4], s1[4];
#pragma unroll
        for (int ni = 0; ni < 4; ni++) {
            s0[ni] = mfma16(kf[ni][0], qf00, f32x4{0.f, 0.f, 0.f, 0.f});
            s0[ni] = mfma16(kf[ni][1], qf01, s0[ni]);
            s1[ni] = mfma16(kf[ni][0], qf10, f32x4{0.f, 0.f, 0.f, 0.f});
            s1[ni] = mfma16(kf[ni][1], qf11, s1[ni]);
        }
#pragma unroll
        for (int ni = 0; ni < 4; ni++) {
            bf16x4 p0;
#pragma unroll
            for (int r = 0; r < 4; r++) { float v = s0[ni][r]; p0[r] = (bf16)(v * v); }
            *(bf16x4*)&Pw[q15][ni * 16 + g * 4] = p0;
        }
        bf16x8 pf00 = *(const bf16x8*)&Pw[q15][g * 8];
        bf16x8 pf01 = *(const bf16x8*)&Pw[q15][32 + g * 8];
#pragma unroll
        for (int ni = 0; ni < 4; ni++) {
            bf16x4 p1;
#pragma unroll
            for (int r = 0; r < 4; r++) { float v = s1[ni][r]; p1[r] = (bf16)(v * v); }
            *(bf16x4*)&Pw[q15][ni * 16 + g * 4] = p1;
        }
        bf16x8 pf10 = *(const bf16x8*)&Pw[q15][g * 8];
        bf16x8 pf11 = *(const bf16x8*)&Pw[q15][32 + g * 8];
        bf16x8 vf[4][2];
#pragma unroll
        for (int ni = 0; ni < 4; ni++)
#pragma unroll
            for (int c = 0; c < 2; c++)
                vf[ni][c] = *(const bf16x8*)&Vl[cur][ni * 16 + q15][c * 32 + g * 8];
#pragma unroll
        for (int ni = 0; ni < 4; ni++) {
            o0[ni] = mfma16(pf00, vf[ni][0], o0[ni]);
            o0[ni] = mfma16(pf01, vf[ni][1], o0[ni]);
            o1[ni] = mfma16(pf10, vf[ni][0], o1[ni]);
            o1[ni] = mfma16(pf11, vf[ni][1], o1[ni]);
        }
    };

    gloadA(0);
    stageA(0);
    gloadB(64);
    __syncthreads();
    for (int t = 0; t <= NT - 4; t += 2) {
        stageB(1);
        gloadA((t + 2) * 64);
        compute(0);
        __syncthreads();
        stageA(0);
        if (t + 3 < NT) gloadB((t + 3) * 64);
        compute(1);
        __syncthreads();
    }
    stageB(1);
    compute(0);
    __syncthreads();
    compute(1);

    const int b = bh / 12, h = bh % 12;
#pragma unroll
    for (int ni = 0; ni < 4; ni++)
#pragma unroll
        for (int r = 0; r < 4; r++) {
            const int s0r = qbase + g * 4 + r;
            AOo[((long)b * S_ + s0r) * D_ + h * 64 + ni * 16 + q15] = (bf16)o0[ni][r];
            const int s1r = qbase + 16 + g * 4 + r;
            AOo[((long)b * S_ + s1r) * D_ + h * 64 + ni * 16 + q15] = (bf16)o1[ni][r];
        }
}

template<bool WB>
__global__ __launch_bounds__(256)
void ln_kernel(const bf16* __restrict__ y, const float* __restrict__ gamma,
               const float* __restrict__ beta, float* __restrict__ xo,
               bf16* __restrict__ xob) {
    __shared__ float sa[4], sb[4];
    const int row = blockIdx.x, t = threadIdx.x;
    const bf16* yr = y + (long)row * 768;
    float v0 = (float)yr[t], v1 = (float)yr[t + 256], v2 = (float)yr[t + 512];
    float s  = v0 + v1 + v2;
    float ss = v0 * v0 + v1 * v1 + v2 * v2;
#pragma unroll
    for (int o = 32; o; o >>= 1) { s += __shfl_xor(s, o); ss += __shfl_xor(ss, o); }
    if ((t & 63) == 0) { sa[t >> 6] = s; sb[t >> 6] = ss; }
    __syncthreads();
    s  = sa[0] + sa[1] + sa[2] + sa[3];
    ss = sb[0] + sb[1] + sb[2] + sb[3];
    const float mu   = s * (1.0f / 768.0f);
    const float var  = ss * (1.0f / 768.0f) - mu * mu;
    const float rstd = rsqrtf(var + 1e-5f);
#pragma unroll
    for (int i = 0; i < 3; i++) {
        const int c = t + i * 256;
        const float vv = (i == 0) ? v0 : (i == 1) ? v1 : v2;
        const float ov = (vv - mu) * rstd * gamma[c] + beta[c];
        if (WB) xob[(long)row * 768 + c] = (bf16)ov;
        else    xo[(long)row * 768 + c] = ov;
    }
}

extern "C" void kernel_launch(void* const* d_in, const int* in_sizes, int n_in,
                              void* d_out, int out_size, void* d_ws, size_t ws_size,
                              hipStream_t stream) {
    const float* x     = (const float*)d_in[0];
    const float* Wq    = (const float*)d_in[1];
    const float* bq    = (const float*)d_in[2];
    const float* Wk    = (const float*)d_in[3];
    const float* bk    = (const float*)d_in[4];
    const float* Wv    = (const float*)d_in[5];
    const float* bv    = (const float*)d_in[6];
    const float* Wo    = (const float*)d_in[7];
    const float* bo    = (const float*)d_in[8];
    const float* W1    = (const float*)d_in[9];
    const float* b1    = (const float*)d_in[10];
    const float* W2    = (const float*)d_in[11];
    const float* b2    = (const float*)d_in[12];
    const float* gamma = (const float*)d_in[13];
    const float* beta  = (const float*)d_in[14];

    char* p = (char*)d_ws;
    auto alloc = [&](size_t bytes) -> void* {
        void* r = p;
        p += (bytes + 255) & ~(size_t)255;
        return r;
    };
    bf16*  Xb    = (bf16*)alloc((size_t)M_ * D_ * 2);
    bf16*  Wqkvt = (bf16*)alloc((size_t)2304 * 768 * 2);
    bf16*  Wot   = (bf16*)alloc((size_t)768 * 768 * 2);
    bf16*  W1t   = (bf16*)alloc((size_t)3072 * 768 * 2);
    bf16*  W2t   = (bf16*)alloc((size_t)768 * 3072 * 2);
    bf16*  Qh    = (bf16*)alloc((size_t)BH_ * S_ * 64 * 2);
    bf16*  Kh    = (bf16*)alloc((size_t)BH_ * S_ * 64 * 2);
    bf16*  Vt    = (bf16*)alloc((size_t)BH_ * S_ * 64 * 2);
    bf16*  AOp   = (bf16*)alloc((size_t)2 * M_ * D_ * 2);  // two adjacent partials
    bf16*  AO    = (bf16*)alloc((size_t)M_ * D_ * 2);
    bf16*  y1b   = (bf16*)alloc((size_t)M_ * D_ * 2);
    bf16*  x1b   = (bf16*)alloc((size_t)M_ * D_ * 2);
    bf16*  hbuf  = (bf16*)alloc((size_t)M_ * DFF_ * 2);
    bf16*  y2b   = y1b;

    pack_x_kernel<<<(M_ * D_) / 1024, 256, 0, stream>>>(x, Xb);
    wt_all_kernel<<<1728, 256, 0, stream>>>(Wq, Wk, Wv, Wo, W1, W2,
                                            Wqkvt, Wot, W1t, W2t);

    gemm_bt<0, 768, 128, 128, 2, 2><<<18 * 32, 256, 0, stream>>>(
        Xb, Wqkvt, bq, bk, bv, nullptr, nullptr, nullptr, Qh, Kh, Vt);

    // attention: 768 blocks (2 kv-halves x 16 qblocks x 24 bh), then merge
    attn_kernel<<<2 * 16 * BH_, 256, 0, stream>>>(Qh, Kh, Vt, AOp);
    merge_ao_kernel<<<(M_ * D_) / 2048, 256, 0, stream>>>(
        AOp, AOp + (size_t)M_ * D_, AO);

    gemm_bt<1, 768, 64, 64, 2, 2><<<12 * 64, 256, 0, stream>>>(
        AO, Wot, bo, nullptr, nullptr, x, nullptr, y1b, nullptr, nullptr, nullptr);
    ln_kernel<true><<<M_, 256, 0, stream>>>(y1b, gamma, beta, nullptr, x1b);

    gemm_bt<2, 768, 128, 128, 2, 2><<<24 * 32, 256, 0, stream>>>(
        x1b, W1t, b1, nullptr, nullptr, nullptr, nullptr, hbuf, nullptr, nullptr, nullptr);
    gemm_bt<3, 3072, 64, 64, 2, 2><<<12 * 64, 256, 0, stream>>>(
        hbuf, W2t, b2, nullptr, nullptr, nullptr, x1b, y2b, nullptr, nullptr, nullptr);
    ln_kernel<false><<<M_, 256, 0, stream>>>(y2b, gamma, beta, (float*)d_out, nullptr);
}

// Round 14
// 162.718 us; speedup vs baseline: 1.6217x; 1.0762x over previous
//
#include <hip/hip_runtime.h>
#include <math.h>

using bf16   = __bf16;
using bf16x8 = __attribute__((ext_vector_type(8))) __bf16;
using bf16x4 = __attribute__((ext_vector_type(4))) __bf16;
using f32x4  = __attribute__((ext_vector_type(4))) float;

constexpr int S_   = 2048;
constexpr int D_   = 768;
constexpr int DFF_ = 3072;
constexpr int M_   = 4096;   // B*S
constexpr int BH_  = 24;     // B*H

__device__ __forceinline__ f32x4 mfma16(bf16x8 a, bf16x8 b, f32x4 c) {
    return __builtin_amdgcn_mfma_f32_16x16x32_bf16(a, b, c, 0, 0, 0);
}

__device__ __forceinline__ void gload16(const bf16* g, bf16* l) {
    __builtin_amdgcn_global_load_lds(
        (const __attribute__((address_space(1))) void*)g,
        (__attribute__((address_space(3))) void*)l, 16, 0, 0);
}

template<int N> __device__ __forceinline__ void wait_vmcnt() {
    if constexpr (N == 0)      asm volatile("s_waitcnt vmcnt(0)" ::: "memory");
    else if constexpr (N == 4) asm volatile("s_waitcnt vmcnt(4)" ::: "memory");
    else if constexpr (N == 6) asm volatile("s_waitcnt vmcnt(6)" ::: "memory");
    else if constexpr (N == 8) asm volatile("s_waitcnt vmcnt(8)" ::: "memory");
    else static_assert(N == 0, "unsupported vmcnt");
}
__device__ __forceinline__ void wait_lgkm0() {
    asm volatile("s_waitcnt lgkmcnt(0)" ::: "memory");
}

__device__ __forceinline__ int xcd_swz(int orig, int nwg) {
    return (orig & 7) * (nwg >> 3) + (orig >> 3);
}

__device__ __forceinline__ float gelu_f(float v) {
    float y = 1.5957691f * (v + 0.044715f * v * v * v);
    return v / (1.0f + __expf(-y));
}

__global__ __launch_bounds__(256)
void pack_x_kernel(const float* __restrict__ x, bf16* __restrict__ xb) {
    const int i = blockIdx.x * 256 + threadIdx.x;
    float4 v = ((const float4*)x)[i];
    bf16x4 o;
    o[0] = (bf16)v.x; o[1] = (bf16)v.y; o[2] = (bf16)v.z; o[3] = (bf16)v.w;
    ((bf16x4*)xb)[i] = o;
}

__global__ __launch_bounds__(256)
void merge_ao_kernel(const bf16* __restrict__ a, const bf16* __restrict__ b,
                     bf16* __restrict__ o) {
    const long i = ((long)blockIdx.x * 256 + threadIdx.x) * 8;
    bf16x8 va = *(const bf16x8*)&a[i];
    bf16x8 vb = *(const bf16x8*)&b[i];
    bf16x8 vo;
#pragma unroll
    for (int j = 0; j < 8; j++) vo[j] = (bf16)((float)va[j] + (float)vb[j]);
    *(bf16x8*)&o[i] = vo;
}

__global__ __launch_bounds__(256)
void wt_all_kernel(const float* __restrict__ Wq, const float* __restrict__ Wk,
                   const float* __restrict__ Wv, const float* __restrict__ Wo,
                   const float* __restrict__ W1, const float* __restrict__ W2,
                   bf16* __restrict__ Wqkvt, bf16* __restrict__ Wot,
                   bf16* __restrict__ W1t, bf16* __restrict__ W2t) {
    int bid = blockIdx.x;
    const float* in; bf16* out; int K, N, t;
    if (bid < 576) {
        int m = bid / 144; t = bid % 144; K = 768; N = 768;
        in  = (m == 0) ? Wq : (m == 1) ? Wk : (m == 2) ? Wv : Wo;
        out = (m == 3) ? Wot : Wqkvt + (size_t)m * 768 * 768;
    } else if (bid < 1152) {
        t = bid - 576; K = 768; N = 3072; in = W1; out = W1t;
    } else {
        t = bid - 1152; K = 3072; N = 768; in = W2; out = W2t;
    }
    const int ntx = N / 64;
    const int n0 = (t % ntx) * 64, k0 = (t / ntx) * 64;

    __shared__ __align__(16) bf16 T[64][72];
    const int tt = threadIdx.x;
    const int r  = tt >> 2, c0 = (tt & 3) * 16;
    const float* src = in + (size_t)(k0 + r) * N + n0 + c0;
#pragma unroll
    for (int j = 0; j < 16; j += 4) {
        float4 v = *(const float4*)(src + j);
        T[r][c0 + j + 0] = (bf16)v.x;
        T[r][c0 + j + 1] = (bf16)v.y;
        T[r][c0 + j + 2] = (bf16)v.z;
        T[r][c0 + j + 3] = (bf16)v.w;
    }
    __syncthreads();
    bf16x8 o0, o1;
#pragma unroll
    for (int j = 0; j < 8; j++) { o0[j] = T[c0 + j][r]; o1[j] = T[c0 + 8 + j][r]; }
    bf16* dst = out + (size_t)(n0 + r) * K + k0 + c0;
    *(bf16x8*)(dst)     = o0;
    *(bf16x8*)(dst + 8) = o1;
}

// ---------------------------------------------------------------------------
// GEMM: C = A[M,K] @ Bt[N,K]^T, BMxBN tile, BK=64, 4 waves in WRxWC grid.
// Coalesced global_load_lds staging with within-segment XOR swizzle (zero
// LDS bank conflicts both sides, coalescing intact). Counted-vmcnt dbuf
// pipeline (tiles t,t+1 in flight). 1D grid + bijective XCD swizzle.
// EPI: 0=QKV (+bias, fused Q/K row-L2-norm, V written transposed),
//      1=Wo(+bias+fp32 resid)->bf16, 2=FFN1 fast-gelu->bf16,
//      3=FFN2(+bias+bf16 resid)->bf16
// BM=64 everywhere now: dbuf LDS <= 48KB -> 3 blocks/CU (was 2 at 128^2).
// ---------------------------------------------------------------------------
template<int EPI, int K, int BM, int BN, int WR, int WC>
__global__ __launch_bounds__(256)
void gemm_bt(const bf16* __restrict__ A, const bf16* __restrict__ Bt,
             const float* __restrict__ bias0, const float* __restrict__ bias1,
             const float* __restrict__ bias2, const float* __restrict__ residf,
             const bf16* __restrict__ residb, bf16* __restrict__ outb,
             bf16* __restrict__ qo, bf16* __restrict__ ko, bf16* __restrict__ vo) {
    constexpr int MR  = BM / WR / 16;
    constexpr int NR  = BN / WC / 16;
    constexpr int GA  = BM / 32;
    constexpr int GB  = BN / 32;
    constexpr int NPT = GA + GB;
    constexpr int NCOL = (EPI == 0) ? 2304 : (EPI == 2) ? 3072 : 768;
    constexpr int NBX  = NCOL / BN;
    __shared__ __align__(16) bf16 Al[2 * BM * 64];
    __shared__ __align__(16) bf16 Bl[2 * BN * 64];
    const int tid  = threadIdx.x;
    const int lane = tid & 63, w = tid >> 6;
    const int wr = w / WC, wc = w % WC;
    const int wg = xcd_swz(blockIdx.x, gridDim.x);
    const int m0 = (wg / NBX) * BM, n0 = (wg % NBX) * BN;
    const int g = lane >> 4, q = lane & 15;
    const int srow = lane >> 3;
    const int schunk = (((lane & 7) ^ ((lane >> 3) & 7))) * 8;

    f32x4 acc[MR][NR] = {};

    const bf16* gaA = A  + (long)(m0 + w * (BM / 4) + srow) * K + schunk;
    const bf16* gaB = Bt + (long)(n0 + w * (BN / 4) + srow) * K + schunk;

    auto stage = [&](int buf, int kt) {
#pragma unroll
        for (int i = 0; i < GA; i++)
            gload16(gaA + kt + (long)i * 8 * K,
                    &Al[buf * BM * 64 + (w * (BM / 4) + i * 8) * 64]);
#pragma unroll
        for (int i = 0; i < GB; i++)
            gload16(gaB + kt + (long)i * 8 * K,
                    &Bl[buf * BN * 64 + (w * (BN / 4) + i * 8) * 64]);
    };
    auto compute = [&](int buf) {
#pragma unroll
        for (int c = 0; c < 2; c++) {
            const int rch = ((c * 4 + g) ^ (q & 7)) * 8;
            bf16x8 af[MR], bfr[NR];
#pragma unroll
            for (int i = 0; i < MR; i++)
                af[i] = *(const bf16x8*)
                    &Al[buf * BM * 64 + (wr * (BM / WR) + i * 16 + q) * 64 + rch];
#pragma unroll
            for (int i = 0; i < NR; i++)
                bfr[i] = *(const bf16x8*)
                    &Bl[buf * BN * 64 + (wc * (BN / WC) + i * 16 + q) * 64 + rch];
#pragma unroll
            for (int mi = 0; mi < MR; mi++)
#pragma unroll
                for (int ni = 0; ni < NR; ni++)
                    acc[mi][ni] = mfma16(af[mi], bfr[ni], acc[mi][ni]);
        }
    };

    stage(0, 0);
    stage(1, 64);
    int cur = 0;
    for (int kt = 0; kt < K - 64; kt += 64) {
        wait_vmcnt<NPT>();
        __builtin_amdgcn_s_barrier();
        compute(cur);
        wait_lgkm0();
        __builtin_amdgcn_s_barrier();
        if (kt + 128 < K) stage(cur, kt + 128);
        cur ^= 1;
    }
    wait_vmcnt<0>();
    __builtin_amdgcn_s_barrier();
    compute(cur);

#pragma unroll
    for (int mi = 0; mi < MR; mi++) {
        if (EPI == 0) {
            const int col0  = n0 + wc * 64;
            const int which = (col0 >= 1536) ? 2 : (col0 >= 768 ? 1 : 0);
            const int row0  = m0 + wr * (BM / WR) + mi * 16 + g * 4;
            float val[NR][4];
#pragma unroll
            for (int ni = 0; ni < NR; ni++) {
                const int dd = col0 + ni * 16 + q - which * 768;
                const float bias = (which == 0 ? bias0 : which == 1 ? bias1 : bias2)[dd];
#pragma unroll
                for (int r = 0; r < 4; r++) val[ni][r] = acc[mi][ni][r] + bias;
            }
            if (which <= 1) {
#pragma unroll
                for (int r = 0; r < 4; r++) {
                    float ss = val[0][r] * val[0][r];
#pragma unroll
                    for (int ni = 1; ni < NR; ni++) ss += val[ni][r] * val[ni][r];
                    ss += __shfl_xor(ss, 1);
                    ss += __shfl_xor(ss, 2);
                    ss += __shfl_xor(ss, 4);
                    ss += __shfl_xor(ss, 8);
                    const float rn = 1.0f / fmaxf(sqrtf(ss), 1e-12f);
#pragma unroll
                    for (int ni = 0; ni < NR; ni++) val[ni][r] *= rn;
                }
            }
            const int dd0 = col0 - which * 768;
            const int hh  = dd0 >> 6;
            const long bh = (long)(row0 >> 11) * 12 + hh;
#pragma unroll
            for (int ni = 0; ni < NR; ni++) {
                const int dk = ni * 16 + q;
                if (which == 2) {
                    bf16x4 pv;
#pragma unroll
                    for (int r = 0; r < 4; r++) pv[r] = (bf16)val[ni][r];
                    *(bf16x4*)&vo[(bh * 64 + dk) * 2048 + (row0 & 2047)] = pv;
                } else {
                    bf16* dst = (which == 0) ? qo : ko;
#pragma unroll
                    for (int r = 0; r < 4; r++)
                        dst[(bh * 2048 + ((row0 + r) & 2047)) * 64 + dk] = (bf16)val[ni][r];
                }
            }
        } else {
#pragma unroll
            for (int ni = 0; ni < NR; ni++) {
                const int col  = n0 + wc * (BN / WC) + ni * 16 + q;
                const int row0 = m0 + wr * (BM / WR) + mi * 16 + g * 4;
                const float bias = bias0[col];
                if (EPI == 1) {
#pragma unroll
                    for (int r = 0; r < 4; r++) {
                        const int row = row0 + r;
                        outb[(long)row * 768 + col] =
                            (bf16)(acc[mi][ni][r] + bias + residf[(long)row * 768 + col]);
                    }
                } else if (EPI == 3) {
#pragma unroll
                    for (int r = 0; r < 4; r++) {
                        const int row = row0 + r;
                        outb[(long)row * 768 + col] =
                            (bf16)(acc[mi][ni][r] + bias + (float)residb[(long)row * 768 + col]);
                    }
                } else {
#pragma unroll
                    for (int r = 0; r < 4; r++) {
                        const float v = acc[mi][ni][r] + bias;
                        outb[(long)(row0 + r) * 3072 + col] = (bf16)gelu_f(v);
                    }
                }
            }
        }
    }
}

// ---------------------------------------------------------------------------
// Attention split-K over keys (PV is linear, no softmax). Grid = 768 blocks
// (2 kv-halves x 16 qblocks x 24 bh) = 3 blocks/CU at LDS 45KB.
// Block = 4 waves x 32 q-rows; 16 key-tiles of 64; dbuf K/V staging.
// P round-trip reuses one [16][72] wave-private buffer for both q-halves
// sequentially (per-wave DS ops are in-order). Partial O -> AOp[kvhalf].
// ---------------------------------------------------------------------------
__global__ __launch_bounds__(256, 3)
void attn_kernel(const bf16* __restrict__ Qn, const bf16* __restrict__ Kn,
                 const bf16* __restrict__ Vt, bf16* __restrict__ AOp) {
    const int wg  = xcd_swz(blockIdx.x, gridDim.x);
    const int bh  = wg >> 5;
    const int rem = wg & 31;
    const int kvhalf = rem >> 4;
    const int qblk   = rem & 15;
    const int tid = threadIdx.x, lane = tid & 63, w = tid >> 6;
    const int g = lane >> 4, q15 = lane & 15;
    const int qbase = qblk * 128 + w * 32;
    const int kv0   = kvhalf * 1024;
    constexpr int NT = 16;

    __shared__ __align__(16) bf16 Kl[2][64][72];
    __shared__ __align__(16) bf16 Vl[2][64][72];
    __shared__ __align__(16) bf16 Pl[4][16][72];
    bf16 (*Pw)[72] = Pl[w];

    const bf16* Qp = Qn + (long)bh * S_ * 64;
    const bf16* Kp = Kn + (long)bh * S_ * 64 + (long)kv0 * 64;
    const bf16* Vp = Vt + (long)bh * 64 * S_ + kv0;
    bf16* AOo = AOp + (long)kvhalf * M_ * D_;

    const int srow = tid >> 3, scol = (tid & 7) * 8;

    bf16x8 qf00 = *(const bf16x8*)&Qp[(long)(qbase + q15) * 64 + g * 8];
    bf16x8 qf01 = *(const bf16x8*)&Qp[(long)(qbase + q15) * 64 + 32 + g * 8];
    bf16x8 qf10 = *(const bf16x8*)&Qp[(long)(qbase + 16 + q15) * 64 + g * 8];
    bf16x8 qf11 = *(const bf16x8*)&Qp[(long)(qbase + 16 + q15) * 64 + 32 + g * 8];

    f32x4 o0[4] = {}, o1[4] = {};

    bf16x8 aK0, aK1, aV0, aV1, bK0, bK1, bV0, bV1;
    auto gloadA = [&](int kt) {
        aK0 = *(const bf16x8*)&Kp[(long)(kt + srow) * 64 + scol];
        aK1 = *(const bf16x8*)&Kp[(long)(kt + 32 + srow) * 64 + scol];
        aV0 = *(const bf16x8*)&Vp[(long)srow * S_ + kt + scol];
        aV1 = *(const bf16x8*)&Vp[(long)(32 + srow) * S_ + kt + scol];
    };
    auto gloadB = [&](int kt) {
        bK0 = *(const bf16x8*)&Kp[(long)(kt + srow) * 64 + scol];
        bK1 = *(const bf16x8*)&Kp[(long)(kt + 32 + srow) * 64 + scol];
        bV0 = *(const bf16x8*)&Vp[(long)srow * S_ + kt + scol];
        bV1 = *(const bf16x8*)&Vp[(long)(32 + srow) * S_ + kt + scol];
    };
    auto stageA = [&](int buf) {
        *(bf16x8*)&Kl[buf][srow][scol]      = aK0;
        *(bf16x8*)&Kl[buf][32 + srow][scol] = aK1;
        *(bf16x8*)&Vl[buf][srow][scol]      = aV0;
        *(bf16x8*)&Vl[buf][32 + srow][scol] = aV1;
    };
    auto stageB = [&](int buf) {
        *(bf16x8*)&Kl[buf][srow][scol]      = bK0;
        *(bf16x8*)&Kl[buf][32 + srow][scol] = bK1;
        *(bf16x8*)&Vl[buf][srow][scol]      = bV0;
        *(bf16x8*)&Vl[buf][32 + srow][scol] = bV1;
    };

    auto compute = [&](int cur) {
        bf16x8 kf[4][2];
#pragma unroll
        for (int ni = 0; ni < 4; ni++)
#pragma unroll
            for (int c = 0; c < 2; c++)
                kf[ni][c] = *(const bf16x8*)&Kl[cur][ni * 16 + q15][c * 32 + g * 8];
        f32x4 s0[4], s1[4];
#pragma unroll
        for (int ni = 0; ni < 4; ni++) {
            s0[ni] = mfma16(kf[ni][0], qf00, f32x4{0.f, 0.f, 0.f, 0.f});
            s0[ni] = mfma16(kf[ni][1], qf01, s0[ni]);
            s1[ni] = mfma16(kf[ni][0], qf10, f32x4{0.f, 0.f, 0.f, 0.f});
            s1[ni] = mfma16(kf[ni][1], qf11, s1[ni]);
        }
#pragma unroll
        for (int ni = 0; ni < 4; ni++) {
            bf16x4 p0;
#pragma unroll
            for (int r = 0; r < 4; r++) { float v = s0[ni][r]; p0[r] = (bf16)(v * v); }
            *(bf16x4*)&Pw[q15][ni * 16 + g * 4] = p0;
        }
        bf16x8 pf00 = *(const bf16x8*)&Pw[q15][g * 8];
        bf16x8 pf01 = *(const bf16x8*)&Pw[q15][32 + g * 8];
#pragma unroll
        for (int ni = 0; ni < 4; ni++) {
            bf16x4 p1;
#pragma unroll
            for (int r = 0; r < 4; r++) { float v = s1[ni][r]; p1[r] = (bf16)(v * v); }
            *(bf16x4*)&Pw[q15][ni * 16 + g * 4] = p1;
        }
        bf16x8 pf10 = *(const bf16x8*)&Pw[q15][g * 8];
        bf16x8 pf11 = *(const bf16x8*)&Pw[q15][32 + g * 8];
        bf16x8 vf[4][2];
#pragma unroll
        for (int ni = 0; ni < 4; ni++)
#pragma unroll
            for (int c = 0; c < 2; c++)
                vf[ni][c] = *(const bf16x8*)&Vl[cur][ni * 16 + q15][c * 32 + g * 8];
#pragma unroll
        for (int ni = 0; ni < 4; ni++) {
            o0[ni] = mfma16(pf00, vf[ni][0], o0[ni]);
            o0[ni] = mfma16(pf01, vf[ni][1], o0[ni]);
            o1[ni] = mfma16(pf10, vf[ni][0], o1[ni]);
            o1[ni] = mfma16(pf11, vf[ni][1], o1[ni]);
        }
    };

    gloadA(0);
    stageA(0);
    gloadB(64);
    __syncthreads();
    for (int t = 0; t <= NT - 4; t += 2) {
        stageB(1);
        gloadA((t + 2) * 64);
        compute(0);
        __syncthreads();
        stageA(0);
        if (t + 3 < NT) gloadB((t + 3) * 64);
        compute(1);
        __syncthreads();
    }
    stageB(1);
    compute(0);
    __syncthreads();
    compute(1);

    const int b = bh / 12, h = bh % 12;
#pragma unroll
    for (int ni = 0; ni < 4; ni++)
#pragma unroll
        for (int r = 0; r < 4; r++) {
            const int s0r = qbase + g * 4 + r;
            AOo[((long)b * S_ + s0r) * D_ + h * 64 + ni * 16 + q15] = (bf16)o0[ni][r];
            const int s1r = qbase + 16 + g * 4 + r;
            AOo[((long)b * S_ + s1r) * D_ + h * 64 + ni * 16 + q15] = (bf16)o1[ni][r];
        }
}

template<bool WB>
__global__ __launch_bounds__(256)
void ln_kernel(const bf16* __restrict__ y, const float* __restrict__ gamma,
               const float* __restrict__ beta, float* __restrict__ xo,
               bf16* __restrict__ xob) {
    __shared__ float sa[4], sb[4];
    const int row = blockIdx.x, t = threadIdx.x;
    const bf16* yr = y + (long)row * 768;
    float v0 = (float)yr[t], v1 = (float)yr[t + 256], v2 = (float)yr[t + 512];
    float s  = v0 + v1 + v2;
    float ss = v0 * v0 + v1 * v1 + v2 * v2;
#pragma unroll
    for (int o = 32; o; o >>= 1) { s += __shfl_xor(s, o); ss += __shfl_xor(ss, o); }
    if ((t & 63) == 0) { sa[t >> 6] = s; sb[t >> 6] = ss; }
    __syncthreads();
    s  = sa[0] + sa[1] + sa[2] + sa[3];
    ss = sb[0] + sb[1] + sb[2] + sb[3];
    const float mu   = s * (1.0f / 768.0f);
    const float var  = ss * (1.0f / 768.0f) - mu * mu;
    const float rstd = rsqrtf(var + 1e-5f);
#pragma unroll
    for (int i = 0; i < 3; i++) {
        const int c = t + i * 256;
        const float vv = (i == 0) ? v0 : (i == 1) ? v1 : v2;
        const float ov = (vv - mu) * rstd * gamma[c] + beta[c];
        if (WB) xob[(long)row * 768 + c] = (bf16)ov;
        else    xo[(long)row * 768 + c] = ov;
    }
}

extern "C" void kernel_launch(void* const* d_in, const int* in_sizes, int n_in,
                              void* d_out, int out_size, void* d_ws, size_t ws_size,
                              hipStream_t stream) {
    const float* x     = (const float*)d_in[0];
    const float* Wq    = (const float*)d_in[1];
    const float* bq    = (const float*)d_in[2];
    const float* Wk    = (const float*)d_in[3];
    const float* bk    = (const float*)d_in[4];
    const float* Wv    = (const float*)d_in[5];
    const float* bv    = (const float*)d_in[6];
    const float* Wo    = (const float*)d_in[7];
    const float* bo    = (const float*)d_in[8];
    const float* W1    = (const float*)d_in[9];
    const float* b1    = (const float*)d_in[10];
    const float* W2    = (const float*)d_in[11];
    const float* b2    = (const float*)d_in[12];
    const float* gamma = (const float*)d_in[13];
    const float* beta  = (const float*)d_in[14];

    char* p = (char*)d_ws;
    auto alloc = [&](size_t bytes) -> void* {
        void* r = p;
        p += (bytes + 255) & ~(size_t)255;
        return r;
    };
    bf16*  Xb    = (bf16*)alloc((size_t)M_ * D_ * 2);
    bf16*  Wqkvt = (bf16*)alloc((size_t)2304 * 768 * 2);
    bf16*  Wot   = (bf16*)alloc((size_t)768 * 768 * 2);
    bf16*  W1t   = (bf16*)alloc((size_t)3072 * 768 * 2);
    bf16*  W2t   = (bf16*)alloc((size_t)768 * 3072 * 2);
    bf16*  Qh    = (bf16*)alloc((size_t)BH_ * S_ * 64 * 2);
    bf16*  Kh    = (bf16*)alloc((size_t)BH_ * S_ * 64 * 2);
    bf16*  Vt    = (bf16*)alloc((size_t)BH_ * S_ * 64 * 2);
    bf16*  AOp   = (bf16*)alloc((size_t)2 * M_ * D_ * 2);  // two adjacent partials
    bf16*  AO    = (bf16*)alloc((size_t)M_ * D_ * 2);
    bf16*  y1b   = (bf16*)alloc((size_t)M_ * D_ * 2);
    bf16*  x1b   = (bf16*)alloc((size_t)M_ * D_ * 2);
    bf16*  hbuf  = (bf16*)alloc((size_t)M_ * DFF_ * 2);
    bf16*  y2b   = y1b;

    pack_x_kernel<<<(M_ * D_) / 1024, 256, 0, stream>>>(x, Xb);
    wt_all_kernel<<<1728, 256, 0, stream>>>(Wq, Wk, Wv, Wo, W1, W2,
                                            Wqkvt, Wot, W1t, W2t);

    // QKV: 64x128 tiles -> 64*18 = 1152 blocks, 3 blocks/CU (48KB LDS)
    gemm_bt<0, 768, 64, 128, 2, 2><<<64 * 18, 256, 0, stream>>>(
        Xb, Wqkvt, bq, bk, bv, nullptr, nullptr, nullptr, Qh, Kh, Vt);

    // attention: 768 blocks (2 kv-halves x 16 qblocks x 24 bh), then merge
    attn_kernel<<<2 * 16 * BH_, 256, 0, stream>>>(Qh, Kh, Vt, AOp);
    merge_ao_kernel<<<(M_ * D_) / 2048, 256, 0, stream>>>(
        AOp, AOp + (size_t)M_ * D_, AO);

    gemm_bt<1, 768, 64, 64, 2, 2><<<12 * 64, 256, 0, stream>>>(
        AO, Wot, bo, nullptr, nullptr, x, nullptr, y1b, nullptr, nullptr, nullptr);
    ln_kernel<true><<<M_, 256, 0, stream>>>(y1b, gamma, beta, nullptr, x1b);

    // FFN1: 64x128 tiles -> 64*24 = 1536 blocks
    gemm_bt<2, 768, 64, 128, 2, 2><<<64 * 24, 256, 0, stream>>>(
        x1b, W1t, b1, nullptr, nullptr, nullptr, nullptr, hbuf, nullptr, nullptr, nullptr);
    gemm_bt<3, 3072, 64, 64, 2, 2><<<12 * 64, 256, 0, stream>>>(
        hbuf, W2t, b2, nullptr, nullptr, nullptr, x1b, y2b, nullptr, nullptr, nullptr);
    ln_kernel<false><<<M_, 256, 0, stream>>>(y2b, gamma, beta, (float*)d_out, nullptr);
}

// Round 15
// 156.296 us; speedup vs baseline: 1.6884x; 1.0411x over previous
//
#include <hip/hip_runtime.h>
#include <math.h>

using bf16   = __bf16;
using bf16x8 = __attribute__((ext_vector_type(8))) __bf16;
using bf16x4 = __attribute__((ext_vector_type(4))) __bf16;
using f32x4  = __attribute__((ext_vector_type(4))) float;

constexpr int S_   = 2048;
constexpr int D_   = 768;
constexpr int DFF_ = 3072;
constexpr int M_   = 4096;   // B*S
constexpr int BH_  = 24;     // B*H

__device__ __forceinline__ f32x4 mfma16(bf16x8 a, bf16x8 b, f32x4 c) {
    return __builtin_amdgcn_mfma_f32_16x16x32_bf16(a, b, c, 0, 0, 0);
}

__device__ __forceinline__ void gload16(const bf16* g, bf16* l) {
    __builtin_amdgcn_global_load_lds(
        (const __attribute__((address_space(1))) void*)g,
        (__attribute__((address_space(3))) void*)l, 16, 0, 0);
}

template<int N> __device__ __forceinline__ void wait_vmcnt() {
    if constexpr (N == 0)      asm volatile("s_waitcnt vmcnt(0)" ::: "memory");
    else if constexpr (N == 4) asm volatile("s_waitcnt vmcnt(4)" ::: "memory");
    else if constexpr (N == 6) asm volatile("s_waitcnt vmcnt(6)" ::: "memory");
    else if constexpr (N == 8) asm volatile("s_waitcnt vmcnt(8)" ::: "memory");
    else static_assert(N == 0, "unsupported vmcnt");
}
__device__ __forceinline__ void wait_lgkm0() {
    asm volatile("s_waitcnt lgkmcnt(0)" ::: "memory");
}

__device__ __forceinline__ int xcd_swz(int orig, int nwg) {
    return (orig & 7) * (nwg >> 3) + (orig >> 3);
}

__device__ __forceinline__ float gelu_f(float v) {
    float y = 1.5957691f * (v + 0.044715f * v * v * v);
    return v / (1.0f + __expf(-y));
}

__global__ __launch_bounds__(256)
void pack_x_kernel(const float* __restrict__ x, bf16* __restrict__ xb) {
    const int i = blockIdx.x * 256 + threadIdx.x;
    float4 v = ((const float4*)x)[i];
    bf16x4 o;
    o[0] = (bf16)v.x; o[1] = (bf16)v.y; o[2] = (bf16)v.z; o[3] = (bf16)v.w;
    ((bf16x4*)xb)[i] = o;
}

__global__ __launch_bounds__(256)
void merge_ao_kernel(const bf16* __restrict__ a, const bf16* __restrict__ b,
                     bf16* __restrict__ o) {
    const long i = ((long)blockIdx.x * 256 + threadIdx.x) * 8;
    bf16x8 va = *(const bf16x8*)&a[i];
    bf16x8 vb = *(const bf16x8*)&b[i];
    bf16x8 vo;
#pragma unroll
    for (int j = 0; j < 8; j++) vo[j] = (bf16)((float)va[j] + (float)vb[j]);
    *(bf16x8*)&o[i] = vo;
}

// ---------------------------------------------------------------------------
// merge split-K GEMM partials (+bias +residual), then LayerNorm over D=768.
// FIRST=true : resid = fp32 x, output bf16 x1b (post-LN1 activations).
// FIRST=false: resid = bf16 x1b, output fp32 d_out (final).
// One block per row.
// ---------------------------------------------------------------------------
template<bool FIRST>
__global__ __launch_bounds__(256)
void merge_ln_kernel(const bf16* __restrict__ pp, const float* __restrict__ bias,
                     const float* __restrict__ residf, const bf16* __restrict__ residb,
                     const float* __restrict__ gamma, const float* __restrict__ beta,
                     float* __restrict__ outf, bf16* __restrict__ outb) {
    __shared__ float sa[4], sb[4];
    const int row = blockIdx.x, t = threadIdx.x;
    const bf16* p0 = pp + (long)row * 768;
    const bf16* p1 = pp + (long)M_ * 768 + (long)row * 768;
    float v[3];
#pragma unroll
    for (int i = 0; i < 3; i++) {
        const int c = t + i * 256;
        float y = (float)p0[c] + (float)p1[c] + bias[c];
        if (FIRST) y += residf[(long)row * 768 + c];
        else       y += (float)residb[(long)row * 768 + c];
        v[i] = y;
    }
    float s  = v[0] + v[1] + v[2];
    float ss = v[0] * v[0] + v[1] * v[1] + v[2] * v[2];
#pragma unroll
    for (int o = 32; o; o >>= 1) { s += __shfl_xor(s, o); ss += __shfl_xor(ss, o); }
    if ((t & 63) == 0) { sa[t >> 6] = s; sb[t >> 6] = ss; }
    __syncthreads();
    s  = sa[0] + sa[1] + sa[2] + sa[3];
    ss = sb[0] + sb[1] + sb[2] + sb[3];
    const float mu   = s * (1.0f / 768.0f);
    const float var  = ss * (1.0f / 768.0f) - mu * mu;
    const float rstd = rsqrtf(var + 1e-5f);
#pragma unroll
    for (int i = 0; i < 3; i++) {
        const int c = t + i * 256;
        const float ov = (v[i] - mu) * rstd * gamma[c] + beta[c];
        if (FIRST) outb[(long)row * 768 + c] = (bf16)ov;
        else       outf[(long)row * 768 + c] = ov;
    }
}

__global__ __launch_bounds__(256)
void wt_all_kernel(const float* __restrict__ Wq, const float* __restrict__ Wk,
                   const float* __restrict__ Wv, const float* __restrict__ Wo,
                   const float* __restrict__ W1, const float* __restrict__ W2,
                   bf16* __restrict__ Wqkvt, bf16* __restrict__ Wot,
                   bf16* __restrict__ W1t, bf16* __restrict__ W2t) {
    int bid = blockIdx.x;
    const float* in; bf16* out; int K, N, t;
    if (bid < 576) {
        int m = bid / 144; t = bid % 144; K = 768; N = 768;
        in  = (m == 0) ? Wq : (m == 1) ? Wk : (m == 2) ? Wv : Wo;
        out = (m == 3) ? Wot : Wqkvt + (size_t)m * 768 * 768;
    } else if (bid < 1152) {
        t = bid - 576; K = 768; N = 3072; in = W1; out = W1t;
    } else {
        t = bid - 1152; K = 3072; N = 768; in = W2; out = W2t;
    }
    const int ntx = N / 64;
    const int n0 = (t % ntx) * 64, k0 = (t / ntx) * 64;

    __shared__ __align__(16) bf16 T[64][72];
    const int tt = threadIdx.x;
    const int r  = tt >> 2, c0 = (tt & 3) * 16;
    const float* src = in + (size_t)(k0 + r) * N + n0 + c0;
#pragma unroll
    for (int j = 0; j < 16; j += 4) {
        float4 v = *(const float4*)(src + j);
        T[r][c0 + j + 0] = (bf16)v.x;
        T[r][c0 + j + 1] = (bf16)v.y;
        T[r][c0 + j + 2] = (bf16)v.z;
        T[r][c0 + j + 3] = (bf16)v.w;
    }
    __syncthreads();
    bf16x8 o0, o1;
#pragma unroll
    for (int j = 0; j < 8; j++) { o0[j] = T[c0 + j][r]; o1[j] = T[c0 + 8 + j][r]; }
    bf16* dst = out + (size_t)(n0 + r) * K + k0 + c0;
    *(bf16x8*)(dst)     = o0;
    *(bf16x8*)(dst + 8) = o1;
}

// ---------------------------------------------------------------------------
// GEMM: C = A[M,K] @ Bt[N,K]^T, BMxBN tile, BK=64, 4 waves in WRxWC grid.
// Coalesced global_load_lds staging + within-segment XOR swizzle (zero LDS
// bank conflicts). Counted-vmcnt dbuf pipeline. 1D grid + XCD swizzle.
// KSPLIT>1: each block computes K/KSPLIT of the sum; EPI 1/3 then write a
// RAW bf16 partial to outb + ks*M*768 (bias/resid applied in merge_ln).
// EPI: 0=QKV (+bias, fused Q/K row-L2-norm, V transposed), 2=FFN1 gelu,
//      1=Wo partial, 3=FFN2 partial.
// ---------------------------------------------------------------------------
template<int EPI, int K, int BM, int BN, int WR, int WC, int KSPLIT>
__global__ __launch_bounds__(256)
void gemm_bt(const bf16* __restrict__ A, const bf16* __restrict__ Bt,
             const float* __restrict__ bias0, const float* __restrict__ bias1,
             const float* __restrict__ bias2,
             bf16* __restrict__ outb,
             bf16* __restrict__ qo, bf16* __restrict__ ko, bf16* __restrict__ vo) {
    constexpr int MR  = BM / WR / 16;
    constexpr int NR  = BN / WC / 16;
    constexpr int GA  = BM / 32;
    constexpr int GB  = BN / 32;
    constexpr int NPT = GA + GB;
    constexpr int KS  = K / KSPLIT;
    constexpr int NCOL = (EPI == 0) ? 2304 : (EPI == 2) ? 3072 : 768;
    constexpr int NBX  = NCOL / BN;
    __shared__ __align__(16) bf16 Al[2 * BM * 64];
    __shared__ __align__(16) bf16 Bl[2 * BN * 64];
    const int tid  = threadIdx.x;
    const int lane = tid & 63, w = tid >> 6;
    const int wr = w / WC, wc = w % WC;
    const int wg = xcd_swz(blockIdx.x, gridDim.x);
    const int ks = wg % KSPLIT;
    const int tt = wg / KSPLIT;
    const int m0 = (tt / NBX) * BM, n0 = (tt % NBX) * BN;
    const int kb = ks * KS;
    const int g = lane >> 4, q = lane & 15;
    const int srow = lane >> 3;
    const int schunk = (((lane & 7) ^ ((lane >> 3) & 7))) * 8;

    f32x4 acc[MR][NR] = {};

    const bf16* gaA = A  + (long)(m0 + w * (BM / 4) + srow) * K + kb + schunk;
    const bf16* gaB = Bt + (long)(n0 + w * (BN / 4) + srow) * K + kb + schunk;

    auto stage = [&](int buf, int kt) {
#pragma unroll
        for (int i = 0; i < GA; i++)
            gload16(gaA + kt + (long)i * 8 * K,
                    &Al[buf * BM * 64 + (w * (BM / 4) + i * 8) * 64]);
#pragma unroll
        for (int i = 0; i < GB; i++)
            gload16(gaB + kt + (long)i * 8 * K,
                    &Bl[buf * BN * 64 + (w * (BN / 4) + i * 8) * 64]);
    };
    auto compute = [&](int buf) {
#pragma unroll
        for (int c = 0; c < 2; c++) {
            const int rch = ((c * 4 + g) ^ (q & 7)) * 8;
            bf16x8 af[MR], bfr[NR];
#pragma unroll
            for (int i = 0; i < MR; i++)
                af[i] = *(const bf16x8*)
                    &Al[buf * BM * 64 + (wr * (BM / WR) + i * 16 + q) * 64 + rch];
#pragma unroll
            for (int i = 0; i < NR; i++)
                bfr[i] = *(const bf16x8*)
                    &Bl[buf * BN * 64 + (wc * (BN / WC) + i * 16 + q) * 64 + rch];
#pragma unroll
            for (int mi = 0; mi < MR; mi++)
#pragma unroll
                for (int ni = 0; ni < NR; ni++)
                    acc[mi][ni] = mfma16(af[mi], bfr[ni], acc[mi][ni]);
        }
    };

    stage(0, 0);
    stage(1, 64);
    int cur = 0;
    for (int kt = 0; kt < KS - 64; kt += 64) {
        wait_vmcnt<NPT>();
        __builtin_amdgcn_s_barrier();
        compute(cur);
        wait_lgkm0();
        __builtin_amdgcn_s_barrier();
        if (kt + 128 < KS) stage(cur, kt + 128);
        cur ^= 1;
    }
    wait_vmcnt<0>();
    __builtin_amdgcn_s_barrier();
    compute(cur);

#pragma unroll
    for (int mi = 0; mi < MR; mi++) {
        if (EPI == 0) {
            const int col0  = n0 + wc * 64;
            const int which = (col0 >= 1536) ? 2 : (col0 >= 768 ? 1 : 0);
            const int row0  = m0 + wr * (BM / WR) + mi * 16 + g * 4;
            float val[NR][4];
#pragma unroll
            for (int ni = 0; ni < NR; ni++) {
                const int dd = col0 + ni * 16 + q - which * 768;
                const float bias = (which == 0 ? bias0 : which == 1 ? bias1 : bias2)[dd];
#pragma unroll
                for (int r = 0; r < 4; r++) val[ni][r] = acc[mi][ni][r] + bias;
            }
            if (which <= 1) {
#pragma unroll
                for (int r = 0; r < 4; r++) {
                    float ss = val[0][r] * val[0][r];
#pragma unroll
                    for (int ni = 1; ni < NR; ni++) ss += val[ni][r] * val[ni][r];
                    ss += __shfl_xor(ss, 1);
                    ss += __shfl_xor(ss, 2);
                    ss += __shfl_xor(ss, 4);
                    ss += __shfl_xor(ss, 8);
                    const float rn = 1.0f / fmaxf(sqrtf(ss), 1e-12f);
#pragma unroll
                    for (int ni = 0; ni < NR; ni++) val[ni][r] *= rn;
                }
            }
            const int dd0 = col0 - which * 768;
            const int hh  = dd0 >> 6;
            const long bh = (long)(row0 >> 11) * 12 + hh;
#pragma unroll
            for (int ni = 0; ni < NR; ni++) {
                const int dk = ni * 16 + q;
                if (which == 2) {
                    bf16x4 pv;
#pragma unroll
                    for (int r = 0; r < 4; r++) pv[r] = (bf16)val[ni][r];
                    *(bf16x4*)&vo[(bh * 64 + dk) * 2048 + (row0 & 2047)] = pv;
                } else {
                    bf16* dst = (which == 0) ? qo : ko;
#pragma unroll
                    for (int r = 0; r < 4; r++)
                        dst[(bh * 2048 + ((row0 + r) & 2047)) * 64 + dk] = (bf16)val[ni][r];
                }
            }
        } else if (EPI == 2) {
#pragma unroll
            for (int ni = 0; ni < NR; ni++) {
                const int col  = n0 + wc * (BN / WC) + ni * 16 + q;
                const int row0 = m0 + wr * (BM / WR) + mi * 16 + g * 4;
                const float bias = bias0[col];
#pragma unroll
                for (int r = 0; r < 4; r++) {
                    const float v = acc[mi][ni][r] + bias;
                    outb[(long)(row0 + r) * 3072 + col] = (bf16)gelu_f(v);
                }
            }
        } else {  // EPI 1/3 with KSPLIT: raw bf16 partial
#pragma unroll
            for (int ni = 0; ni < NR; ni++) {
                const int col  = n0 + wc * (BN / WC) + ni * 16 + q;
                const int row0 = m0 + wr * (BM / WR) + mi * 16 + g * 4;
#pragma unroll
                for (int r = 0; r < 4; r++)
                    outb[(long)ks * M_ * 768 + (long)(row0 + r) * 768 + col] =
                        (bf16)acc[mi][ni][r];
            }
        }
    }
}

// ---------------------------------------------------------------------------
// Attention split-K over keys (PV linear, no softmax). Grid 768 blocks
// (2 kv-halves x 16 qblocks x 24 bh) = 3/CU at 45KB LDS.
// Block = 4 waves x 32 q-rows; 16 key-tiles; dbuf K/V staging; P round-trip
// reuses one wave-private [16][72] buffer for both q-halves sequentially.
// ---------------------------------------------------------------------------
__global__ __launch_bounds__(256, 3)
void attn_kernel(const bf16* __restrict__ Qn, const bf16* __restrict__ Kn,
                 const bf16* __restrict__ Vt, bf16* __restrict__ AOp) {
    const int wg  = xcd_swz(blockIdx.x, gridDim.x);
    const int bh  = wg >> 5;
    const int rem = wg & 31;
    const int kvhalf = rem >> 4;
    const int qblk   = rem & 15;
    const int tid = threadIdx.x, lane = tid & 63, w = tid >> 6;
    const int g = lane >> 4, q15 = lane & 15;
    const int qbase = qblk * 128 + w * 32;
    const int kv0   = kvhalf * 1024;
    constexpr int NT = 16;

    __shared__ __align__(16) bf16 Kl[2][64][72];
    __shared__ __align__(16) bf16 Vl[2][64][72];
    __shared__ __align__(16) bf16 Pl[4][16][72];
    bf16 (*Pw)[72] = Pl[w];

    const bf16* Qp = Qn + (long)bh * S_ * 64;
    const bf16* Kp = Kn + (long)bh * S_ * 64 + (long)kv0 * 64;
    const bf16* Vp = Vt + (long)bh * 64 * S_ + kv0;
    bf16* AOo = AOp + (long)kvhalf * M_ * D_;

    const int srow = tid >> 3, scol = (tid & 7) * 8;

    bf16x8 qf00 = *(const bf16x8*)&Qp[(long)(qbase + q15) * 64 + g * 8];
    bf16x8 qf01 = *(const bf16x8*)&Qp[(long)(qbase + q15) * 64 + 32 + g * 8];
    bf16x8 qf10 = *(const bf16x8*)&Qp[(long)(qbase + 16 + q15) * 64 + g * 8];
    bf16x8 qf11 = *(const bf16x8*)&Qp[(long)(qbase + 16 + q15) * 64 + 32 + g * 8];

    f32x4 o0[4] = {}, o1[4] = {};

    bf16x8 aK0, aK1, aV0, aV1, bK0, bK1, bV0, bV1;
    auto gloadA = [&](int kt) {
        aK0 = *(const bf16x8*)&Kp[(long)(kt + srow) * 64 + scol];
        aK1 = *(const bf16x8*)&Kp[(long)(kt + 32 + srow) * 64 + scol];
        aV0 = *(const bf16x8*)&Vp[(long)srow * S_ + kt + scol];
        aV1 = *(const bf16x8*)&Vp[(long)(32 + srow) * S_ + kt + scol];
    };
    auto gloadB = [&](int kt) {
        bK0 = *(const bf16x8*)&Kp[(long)(kt + srow) * 64 + scol];
        bK1 = *(const bf16x8*)&Kp[(long)(kt + 32 + srow) * 64 + scol];
        bV0 = *(const bf16x8*)&Vp[(long)srow * S_ + kt + scol];
        bV1 = *(const bf16x8*)&Vp[(long)(32 + srow) * S_ + kt + scol];
    };
    auto stageA = [&](int buf) {
        *(bf16x8*)&Kl[buf][srow][scol]      = aK0;
        *(bf16x8*)&Kl[buf][32 + srow][scol] = aK1;
        *(bf16x8*)&Vl[buf][srow][scol]      = aV0;
        *(bf16x8*)&Vl[buf][32 + srow][scol] = aV1;
    };
    auto stageB = [&](int buf) {
        *(bf16x8*)&Kl[buf][srow][scol]      = bK0;
        *(bf16x8*)&Kl[buf][32 + srow][scol] = bK1;
        *(bf16x8*)&Vl[buf][srow][scol]      = bV0;
        *(bf16x8*)&Vl[buf][32 + srow][scol] = bV1;
    };

    auto compute = [&](int cur) {
        bf16x8 kf[4][2];
#pragma unroll
        for (int ni = 0; ni < 4; ni++)
#pragma unroll
            for (int c = 0; c < 2; c++)
                kf[ni][c] = *(const bf16x8*)&Kl[cur][ni * 16 + q15][c * 32 + g * 8];
        f32x4 s0[4], s1[4];
#pragma unroll
        for (int ni = 0; ni < 4; ni++) {
            s0[ni] = mfma16(kf[ni][0], qf00, f32x4{0.f, 0.f, 0.f, 0.f});
            s0[ni] = mfma16(kf[ni][1], qf01, s0[ni]);
            s1[ni] = mfma16(kf[ni][0], qf10, f32x4{0.f, 0.f, 0.f, 0.f});
            s1[ni] = mfma16(kf[ni][1], qf11, s1[ni]);
        }
#pragma unroll
        for (int ni = 0; ni < 4; ni++) {
            bf16x4 p0;
#pragma unroll
            for (int r = 0; r < 4; r++) { float v = s0[ni][r]; p0[r] = (bf16)(v * v); }
            *(bf16x4*)&Pw[q15][ni * 16 + g * 4] = p0;
        }
        bf16x8 pf00 = *(const bf16x8*)&Pw[q15][g * 8];
        bf16x8 pf01 = *(const bf16x8*)&Pw[q15][32 + g * 8];
#pragma unroll
        for (int ni = 0; ni < 4; ni++) {
            bf16x4 p1;
#pragma unroll
            for (int r = 0; r < 4; r++) { float v = s1[ni][r]; p1[r] = (bf16)(v * v); }
            *(bf16x4*)&Pw[q15][ni * 16 + g * 4] = p1;
        }
        bf16x8 pf10 = *(const bf16x8*)&Pw[q15][g * 8];
        bf16x8 pf11 = *(const bf16x8*)&Pw[q15][32 + g * 8];
        bf16x8 vf[4][2];
#pragma unroll
        for (int ni = 0; ni < 4; ni++)
#pragma unroll
            for (int c = 0; c < 2; c++)
                vf[ni][c] = *(const bf16x8*)&Vl[cur][ni * 16 + q15][c * 32 + g * 8];
#pragma unroll
        for (int ni = 0; ni < 4; ni++) {
            o0[ni] = mfma16(pf00, vf[ni][0], o0[ni]);
            o0[ni] = mfma16(pf01, vf[ni][1], o0[ni]);
            o1[ni] = mfma16(pf10, vf[ni][0], o1[ni]);
            o1[ni] = mfma16(pf11, vf[ni][1], o1[ni]);
        }
    };

    gloadA(0);
    stageA(0);
    gloadB(64);
    __syncthreads();
    for (int t = 0; t <= NT - 4; t += 2) {
        stageB(1);
        gloadA((t + 2) * 64);
        compute(0);
        __syncthreads();
        stageA(0);
        if (t + 3 < NT) gloadB((t + 3) * 64);
        compute(1);
        __syncthreads();
    }
    stageB(1);
    compute(0);
    __syncthreads();
    compute(1);

    const int b = bh / 12, h = bh % 12;
#pragma unroll
    for (int ni = 0; ni < 4; ni++)
#pragma unroll
        for (int r = 0; r < 4; r++) {
            const int s0r = qbase + g * 4 + r;
            AOo[((long)b * S_ + s0r) * D_ + h * 64 + ni * 16 + q15] = (bf16)o0[ni][r];
            const int s1r = qbase + 16 + g * 4 + r;
            AOo[((long)b * S_ + s1r) * D_ + h * 64 + ni * 16 + q15] = (bf16)o1[ni][r];
        }
}

extern "C" void kernel_launch(void* const* d_in, const int* in_sizes, int n_in,
                              void* d_out, int out_size, void* d_ws, size_t ws_size,
                              hipStream_t stream) {
    const float* x     = (const float*)d_in[0];
    const float* Wq    = (const float*)d_in[1];
    const float* bq    = (const float*)d_in[2];
    const float* Wk    = (const float*)d_in[3];
    const float* bk    = (const float*)d_in[4];
    const float* Wv    = (const float*)d_in[5];
    const float* bv    = (const float*)d_in[6];
    const float* Wo    = (const float*)d_in[7];
    const float* bo    = (const float*)d_in[8];
    const float* W1    = (const float*)d_in[9];
    const float* b1    = (const float*)d_in[10];
    const float* W2    = (const float*)d_in[11];
    const float* b2    = (const float*)d_in[12];
    const float* gamma = (const float*)d_in[13];
    const float* beta  = (const float*)d_in[14];

    char* p = (char*)d_ws;
    auto alloc = [&](size_t bytes) -> void* {
        void* r = p;
        p += (bytes + 255) & ~(size_t)255;
        return r;
    };
    bf16*  Xb    = (bf16*)alloc((size_t)M_ * D_ * 2);
    bf16*  Wqkvt = (bf16*)alloc((size_t)2304 * 768 * 2);
    bf16*  Wot   = (bf16*)alloc((size_t)768 * 768 * 2);
    bf16*  W1t   = (bf16*)alloc((size_t)3072 * 768 * 2);
    bf16*  W2t   = (bf16*)alloc((size_t)768 * 3072 * 2);
    bf16*  Qh    = (bf16*)alloc((size_t)BH_ * S_ * 64 * 2);
    bf16*  Kh    = (bf16*)alloc((size_t)BH_ * S_ * 64 * 2);
    bf16*  Vt    = (bf16*)alloc((size_t)BH_ * S_ * 64 * 2);
    bf16*  AOp   = (bf16*)alloc((size_t)2 * M_ * D_ * 2);  // attn partials
    bf16*  AO    = (bf16*)alloc((size_t)M_ * D_ * 2);
    bf16*  pp    = (bf16*)alloc((size_t)2 * M_ * 768 * 2); // GEMM K-split partials
    bf16*  x1b   = (bf16*)alloc((size_t)M_ * D_ * 2);
    bf16*  hbuf  = (bf16*)alloc((size_t)M_ * DFF_ * 2);

    pack_x_kernel<<<(M_ * D_) / 1024, 256, 0, stream>>>(x, Xb);
    wt_all_kernel<<<1728, 256, 0, stream>>>(Wq, Wk, Wv, Wo, W1, W2,
                                            Wqkvt, Wot, W1t, W2t);

    // QKV: 64x128 tiles -> 1152 blocks (48KB LDS, 3/CU)
    gemm_bt<0, 768, 64, 128, 2, 2, 1><<<64 * 18, 256, 0, stream>>>(
        Xb, Wqkvt, bq, bk, bv, nullptr, Qh, Kh, Vt);

    // attention: 768 blocks, split-K over keys, then merge
    attn_kernel<<<2 * 16 * BH_, 256, 0, stream>>>(Qh, Kh, Vt, AOp);
    merge_ao_kernel<<<(M_ * D_) / 2048, 256, 0, stream>>>(
        AOp, AOp + (size_t)M_ * D_, AO);

    // Wo: 64x128 tiles + K-split x2 -> 768 blocks; merge + bias + resid + LN1
    gemm_bt<1, 768, 64, 128, 2, 2, 2><<<64 * 6 * 2, 256, 0, stream>>>(
        AO, Wot, nullptr, nullptr, nullptr, pp, nullptr, nullptr, nullptr);
    merge_ln_kernel<true><<<M_, 256, 0, stream>>>(
        pp, bo, x, nullptr, gamma, beta, nullptr, x1b);

    // FFN1: 64x128 tiles -> 1536 blocks
    gemm_bt<2, 768, 64, 128, 2, 2, 1><<<64 * 24, 256, 0, stream>>>(
        x1b, W1t, b1, nullptr, nullptr, hbuf, nullptr, nullptr, nullptr);

    // FFN2: 64x128 tiles + K-split x2 -> 768 blocks; merge + bias + resid + LN2
    gemm_bt<3, 3072, 64, 128, 2, 2, 2><<<64 * 6 * 2, 256, 0, stream>>>(
        hbuf, W2t, nullptr, nullptr, nullptr, pp, nullptr, nullptr, nullptr);
    merge_ln_kernel<false><<<M_, 256, 0, stream>>>(
        pp, b2, nullptr, x1b, gamma, beta, (float*)d_out, nullptr);
}

// Round 16
// 156.244 us; speedup vs baseline: 1.6889x; 1.0003x over previous
//
#include <hip/hip_runtime.h>
#include <math.h>

using bf16   = __bf16;
using bf16x8 = __attribute__((ext_vector_type(8))) __bf16;
using bf16x4 = __attribute__((ext_vector_type(4))) __bf16;
using f32x4  = __attribute__((ext_vector_type(4))) float;

constexpr int S_   = 2048;
constexpr int D_   = 768;
constexpr int DFF_ = 3072;
constexpr int M_   = 4096;   // B*S
constexpr int BH_  = 24;     // B*H

__device__ __forceinline__ f32x4 mfma16(bf16x8 a, bf16x8 b, f32x4 c) {
    return __builtin_amdgcn_mfma_f32_16x16x32_bf16(a, b, c, 0, 0, 0);
}

__device__ __forceinline__ void gload16(const bf16* g, bf16* l) {
    __builtin_amdgcn_global_load_lds(
        (const __attribute__((address_space(1))) void*)g,
        (__attribute__((address_space(3))) void*)l, 16, 0, 0);
}

template<int N> __device__ __forceinline__ void wait_vmcnt() {
    if constexpr (N == 0)      asm volatile("s_waitcnt vmcnt(0)" ::: "memory");
    else if constexpr (N == 4) asm volatile("s_waitcnt vmcnt(4)" ::: "memory");
    else if constexpr (N == 6) asm volatile("s_waitcnt vmcnt(6)" ::: "memory");
    else if constexpr (N == 8) asm volatile("s_waitcnt vmcnt(8)" ::: "memory");
    else static_assert(N == 0, "unsupported vmcnt");
}
__device__ __forceinline__ void wait_lgkm0() {
    asm volatile("s_waitcnt lgkmcnt(0)" ::: "memory");
}

__device__ __forceinline__ int xcd_swz(int orig, int nwg) {
    return (orig & 7) * (nwg >> 3) + (orig >> 3);
}

__device__ __forceinline__ float gelu_f(float v) {
    float y = 1.5957691f * (v + 0.044715f * v * v * v);
    return v / (1.0f + __expf(-y));
}

__global__ __launch_bounds__(256)
void pack_x_kernel(const float* __restrict__ x, bf16* __restrict__ xb) {
    const int i = blockIdx.x * 256 + threadIdx.x;
    float4 v = ((const float4*)x)[i];
    bf16x4 o;
    o[0] = (bf16)v.x; o[1] = (bf16)v.y; o[2] = (bf16)v.z; o[3] = (bf16)v.w;
    ((bf16x4*)xb)[i] = o;
}

__global__ __launch_bounds__(256)
void merge_ao_kernel(const bf16* __restrict__ a, const bf16* __restrict__ b,
                     bf16* __restrict__ o) {
    const long i = ((long)blockIdx.x * 256 + threadIdx.x) * 8;
    bf16x8 va = *(const bf16x8*)&a[i];
    bf16x8 vb = *(const bf16x8*)&b[i];
    bf16x8 vo;
#pragma unroll
    for (int j = 0; j < 8; j++) vo[j] = (bf16)((float)va[j] + (float)vb[j]);
    *(bf16x8*)&o[i] = vo;
}

// ---------------------------------------------------------------------------
// merge split-K GEMM partials (+bias +residual), then LayerNorm over D=768.
// ---------------------------------------------------------------------------
template<bool FIRST>
__global__ __launch_bounds__(256)
void merge_ln_kernel(const bf16* __restrict__ pp, const float* __restrict__ bias,
                     const float* __restrict__ residf, const bf16* __restrict__ residb,
                     const float* __restrict__ gamma, const float* __restrict__ beta,
                     float* __restrict__ outf, bf16* __restrict__ outb) {
    __shared__ float sa[4], sb[4];
    const int row = blockIdx.x, t = threadIdx.x;
    const bf16* p0 = pp + (long)row * 768;
    const bf16* p1 = pp + (long)M_ * 768 + (long)row * 768;
    float v[3];
#pragma unroll
    for (int i = 0; i < 3; i++) {
        const int c = t + i * 256;
        float y = (float)p0[c] + (float)p1[c] + bias[c];
        if (FIRST) y += residf[(long)row * 768 + c];
        else       y += (float)residb[(long)row * 768 + c];
        v[i] = y;
    }
    float s  = v[0] + v[1] + v[2];
    float ss = v[0] * v[0] + v[1] * v[1] + v[2] * v[2];
#pragma unroll
    for (int o = 32; o; o >>= 1) { s += __shfl_xor(s, o); ss += __shfl_xor(ss, o); }
    if ((t & 63) == 0) { sa[t >> 6] = s; sb[t >> 6] = ss; }
    __syncthreads();
    s  = sa[0] + sa[1] + sa[2] + sa[3];
    ss = sb[0] + sb[1] + sb[2] + sb[3];
    const float mu   = s * (1.0f / 768.0f);
    const float var  = ss * (1.0f / 768.0f) - mu * mu;
    const float rstd = rsqrtf(var + 1e-5f);
#pragma unroll
    for (int i = 0; i < 3; i++) {
        const int c = t + i * 256;
        const float ov = (v[i] - mu) * rstd * gamma[c] + beta[c];
        if (FIRST) outb[(long)row * 768 + c] = (bf16)ov;
        else       outf[(long)row * 768 + c] = ov;
    }
}

__global__ __launch_bounds__(256)
void wt_all_kernel(const float* __restrict__ Wq, const float* __restrict__ Wk,
                   const float* __restrict__ Wv, const float* __restrict__ Wo,
                   const float* __restrict__ W1, const float* __restrict__ W2,
                   bf16* __restrict__ Wqkvt, bf16* __restrict__ Wot,
                   bf16* __restrict__ W1t, bf16* __restrict__ W2t) {
    int bid = blockIdx.x;
    const float* in; bf16* out; int K, N, t;
    if (bid < 576) {
        int m = bid / 144; t = bid % 144; K = 768; N = 768;
        in  = (m == 0) ? Wq : (m == 1) ? Wk : (m == 2) ? Wv : Wo;
        out = (m == 3) ? Wot : Wqkvt + (size_t)m * 768 * 768;
    } else if (bid < 1152) {
        t = bid - 576; K = 768; N = 3072; in = W1; out = W1t;
    } else {
        t = bid - 1152; K = 3072; N = 768; in = W2; out = W2t;
    }
    const int ntx = N / 64;
    const int n0 = (t % ntx) * 64, k0 = (t / ntx) * 64;

    __shared__ __align__(16) bf16 T[64][72];
    const int tt = threadIdx.x;
    const int r  = tt >> 2, c0 = (tt & 3) * 16;
    const float* src = in + (size_t)(k0 + r) * N + n0 + c0;
#pragma unroll
    for (int j = 0; j < 16; j += 4) {
        float4 v = *(const float4*)(src + j);
        T[r][c0 + j + 0] = (bf16)v.x;
        T[r][c0 + j + 1] = (bf16)v.y;
        T[r][c0 + j + 2] = (bf16)v.z;
        T[r][c0 + j + 3] = (bf16)v.w;
    }
    __syncthreads();
    bf16x8 o0, o1;
#pragma unroll
    for (int j = 0; j < 8; j++) { o0[j] = T[c0 + j][r]; o1[j] = T[c0 + 8 + j][r]; }
    bf16* dst = out + (size_t)(n0 + r) * K + k0 + c0;
    *(bf16x8*)(dst)     = o0;
    *(bf16x8*)(dst + 8) = o1;
}

// ---------------------------------------------------------------------------
// GEMM: C = A[M,K] @ Bt[N,K]^T (unchanged from R15).
// ---------------------------------------------------------------------------
template<int EPI, int K, int BM, int BN, int WR, int WC, int KSPLIT>
__global__ __launch_bounds__(256)
void gemm_bt(const bf16* __restrict__ A, const bf16* __restrict__ Bt,
             const float* __restrict__ bias0, const float* __restrict__ bias1,
             const float* __restrict__ bias2,
             bf16* __restrict__ outb,
             bf16* __restrict__ qo, bf16* __restrict__ ko, bf16* __restrict__ vo) {
    constexpr int MR  = BM / WR / 16;
    constexpr int NR  = BN / WC / 16;
    constexpr int GA  = BM / 32;
    constexpr int GB  = BN / 32;
    constexpr int NPT = GA + GB;
    constexpr int KS  = K / KSPLIT;
    constexpr int NCOL = (EPI == 0) ? 2304 : (EPI == 2) ? 3072 : 768;
    constexpr int NBX  = NCOL / BN;
    __shared__ __align__(16) bf16 Al[2 * BM * 64];
    __shared__ __align__(16) bf16 Bl[2 * BN * 64];
    const int tid  = threadIdx.x;
    const int lane = tid & 63, w = tid >> 6;
    const int wr = w / WC, wc = w % WC;
    const int wg = xcd_swz(blockIdx.x, gridDim.x);
    const int ks = wg % KSPLIT;
    const int tt = wg / KSPLIT;
    const int m0 = (tt / NBX) * BM, n0 = (tt % NBX) * BN;
    const int kb = ks * KS;
    const int g = lane >> 4, q = lane & 15;
    const int srow = lane >> 3;
    const int schunk = (((lane & 7) ^ ((lane >> 3) & 7))) * 8;

    f32x4 acc[MR][NR] = {};

    const bf16* gaA = A  + (long)(m0 + w * (BM / 4) + srow) * K + kb + schunk;
    const bf16* gaB = Bt + (long)(n0 + w * (BN / 4) + srow) * K + kb + schunk;

    auto stage = [&](int buf, int kt) {
#pragma unroll
        for (int i = 0; i < GA; i++)
            gload16(gaA + kt + (long)i * 8 * K,
                    &Al[buf * BM * 64 + (w * (BM / 4) + i * 8) * 64]);
#pragma unroll
        for (int i = 0; i < GB; i++)
            gload16(gaB + kt + (long)i * 8 * K,
                    &Bl[buf * BN * 64 + (w * (BN / 4) + i * 8) * 64]);
    };
    auto compute = [&](int buf) {
#pragma unroll
        for (int c = 0; c < 2; c++) {
            const int rch = ((c * 4 + g) ^ (q & 7)) * 8;
            bf16x8 af[MR], bfr[NR];
#pragma unroll
            for (int i = 0; i < MR; i++)
                af[i] = *(const bf16x8*)
                    &Al[buf * BM * 64 + (wr * (BM / WR) + i * 16 + q) * 64 + rch];
#pragma unroll
            for (int i = 0; i < NR; i++)
                bfr[i] = *(const bf16x8*)
                    &Bl[buf * BN * 64 + (wc * (BN / WC) + i * 16 + q) * 64 + rch];
#pragma unroll
            for (int mi = 0; mi < MR; mi++)
#pragma unroll
                for (int ni = 0; ni < NR; ni++)
                    acc[mi][ni] = mfma16(af[mi], bfr[ni], acc[mi][ni]);
        }
    };

    stage(0, 0);
    stage(1, 64);
    int cur = 0;
    for (int kt = 0; kt < KS - 64; kt += 64) {
        wait_vmcnt<NPT>();
        __builtin_amdgcn_s_barrier();
        compute(cur);
        wait_lgkm0();
        __builtin_amdgcn_s_barrier();
        if (kt + 128 < KS) stage(cur, kt + 128);
        cur ^= 1;
    }
    wait_vmcnt<0>();
    __builtin_amdgcn_s_barrier();
    compute(cur);

#pragma unroll
    for (int mi = 0; mi < MR; mi++) {
        if (EPI == 0) {
            const int col0  = n0 + wc * 64;
            const int which = (col0 >= 1536) ? 2 : (col0 >= 768 ? 1 : 0);
            const int row0  = m0 + wr * (BM / WR) + mi * 16 + g * 4;
            float val[NR][4];
#pragma unroll
            for (int ni = 0; ni < NR; ni++) {
                const int dd = col0 + ni * 16 + q - which * 768;
                const float bias = (which == 0 ? bias0 : which == 1 ? bias1 : bias2)[dd];
#pragma unroll
                for (int r = 0; r < 4; r++) val[ni][r] = acc[mi][ni][r] + bias;
            }
            if (which <= 1) {
#pragma unroll
                for (int r = 0; r < 4; r++) {
                    float ss = val[0][r] * val[0][r];
#pragma unroll
                    for (int ni = 1; ni < NR; ni++) ss += val[ni][r] * val[ni][r];
                    ss += __shfl_xor(ss, 1);
                    ss += __shfl_xor(ss, 2);
                    ss += __shfl_xor(ss, 4);
                    ss += __shfl_xor(ss, 8);
                    const float rn = 1.0f / fmaxf(sqrtf(ss), 1e-12f);
#pragma unroll
                    for (int ni = 0; ni < NR; ni++) val[ni][r] *= rn;
                }
            }
            const int dd0 = col0 - which * 768;
            const int hh  = dd0 >> 6;
            const long bh = (long)(row0 >> 11) * 12 + hh;
#pragma unroll
            for (int ni = 0; ni < NR; ni++) {
                const int dk = ni * 16 + q;
                if (which == 2) {
                    bf16x4 pv;
#pragma unroll
                    for (int r = 0; r < 4; r++) pv[r] = (bf16)val[ni][r];
                    *(bf16x4*)&vo[(bh * 64 + dk) * 2048 + (row0 & 2047)] = pv;
                } else {
                    bf16* dst = (which == 0) ? qo : ko;
#pragma unroll
                    for (int r = 0; r < 4; r++)
                        dst[(bh * 2048 + ((row0 + r) & 2047)) * 64 + dk] = (bf16)val[ni][r];
                }
            }
        } else if (EPI == 2) {
#pragma unroll
            for (int ni = 0; ni < NR; ni++) {
                const int col  = n0 + wc * (BN / WC) + ni * 16 + q;
                const int row0 = m0 + wr * (BM / WR) + mi * 16 + g * 4;
                const float bias = bias0[col];
#pragma unroll
                for (int r = 0; r < 4; r++) {
                    const float v = acc[mi][ni][r] + bias;
                    outb[(long)(row0 + r) * 3072 + col] = (bf16)gelu_f(v);
                }
            }
        } else {  // EPI 1/3 with KSPLIT: raw bf16 partial
#pragma unroll
            for (int ni = 0; ni < NR; ni++) {
                const int col  = n0 + wc * (BN / WC) + ni * 16 + q;
                const int row0 = m0 + wr * (BM / WR) + mi * 16 + g * 4;
#pragma unroll
                for (int r = 0; r < 4; r++)
                    outb[(long)ks * M_ * 768 + (long)(row0 + r) * 768 + col] =
                        (bf16)acc[mi][ni][r];
            }
        }
    }
}

// ---------------------------------------------------------------------------
// Attention split-K over keys (PV linear, no softmax), SKEWED qk||pv pipe:
// each iteration runs pv(tile t-1, half1) and qk/pv/qk of tile t -- the
// pv(prev) chain is independent of qk(cur) so MFMA/VALU/LDS interleave.
// V and K consumed via persistent register fragments (vf/kf); single
// wave-private P buffer is safe because every P-read precedes the next
// P-write in per-wave program order. One lgkm0+barrier per tile; gloads
// issued one tile ahead (reg-staged; compiler inserts vmcnt on use).
// LDS 46KB -> 3 blocks/CU. Grid 768 = 2 kv-halves x 16 qblocks x 24 bh.
// ---------------------------------------------------------------------------
__global__ __launch_bounds__(256, 3)
void attn_kernel(const bf16* __restrict__ Qn, const bf16* __restrict__ Kn,
                 const bf16* __restrict__ Vt, bf16* __restrict__ AOp) {
    const int wg  = xcd_swz(blockIdx.x, gridDim.x);
    const int bh  = wg >> 5;
    const int rem = wg & 31;
    const int kvhalf = rem >> 4;
    const int qblk   = rem & 15;
    const int tid = threadIdx.x, lane = tid & 63, w = tid >> 6;
    const int g = lane >> 4, q15 = lane & 15;
    const int qbase = qblk * 128 + w * 32;
    const int kv0   = kvhalf * 1024;
    constexpr int NT = 16;

    __shared__ __align__(16) bf16 Kl[2][64][72];
    __shared__ __align__(16) bf16 Vl[2][64][72];
    __shared__ __align__(16) bf16 Pl[4][16][72];
    bf16 (*Pw)[72] = Pl[w];

    const bf16* Qp = Qn + (long)bh * S_ * 64;
    const bf16* Kp = Kn + (long)bh * S_ * 64 + (long)kv0 * 64;
    const bf16* Vp = Vt + (long)bh * 64 * S_ + kv0;
    bf16* AOo = AOp + (long)kvhalf * M_ * D_;

    const int srow = tid >> 3, scol = (tid & 7) * 8;

    bf16x8 qf00 = *(const bf16x8*)&Qp[(long)(qbase + q15) * 64 + g * 8];
    bf16x8 qf01 = *(const bf16x8*)&Qp[(long)(qbase + q15) * 64 + 32 + g * 8];
    bf16x8 qf10 = *(const bf16x8*)&Qp[(long)(qbase + 16 + q15) * 64 + g * 8];
    bf16x8 qf11 = *(const bf16x8*)&Qp[(long)(qbase + 16 + q15) * 64 + 32 + g * 8];

    f32x4 o0[4] = {}, o1[4] = {};
    bf16x8 kf[4][2], vf[4][2];
    bf16x8 aK0, aK1, aV0, aV1, bK0, bK1, bV0, bV1;

    auto gloadA = [&](int kt) {
        aK0 = *(const bf16x8*)&Kp[(long)(kt + srow) * 64 + scol];
        aK1 = *(const bf16x8*)&Kp[(long)(kt + 32 + srow) * 64 + scol];
        aV0 = *(const bf16x8*)&Vp[(long)srow * S_ + kt + scol];
        aV1 = *(const bf16x8*)&Vp[(long)(32 + srow) * S_ + kt + scol];
    };
    auto gloadB = [&](int kt) {
        bK0 = *(const bf16x8*)&Kp[(long)(kt + srow) * 64 + scol];
        bK1 = *(const bf16x8*)&Kp[(long)(kt + 32 + srow) * 64 + scol];
        bV0 = *(const bf16x8*)&Vp[(long)srow * S_ + kt + scol];
        bV1 = *(const bf16x8*)&Vp[(long)(32 + srow) * S_ + kt + scol];
    };
    auto stageA = [&](int buf) {
        *(bf16x8*)&Kl[buf][srow][scol]      = aK0;
        *(bf16x8*)&Kl[buf][32 + srow][scol] = aK1;
        *(bf16x8*)&Vl[buf][srow][scol]      = aV0;
        *(bf16x8*)&Vl[buf][32 + srow][scol] = aV1;
    };
    auto stageB = [&](int buf) {
        *(bf16x8*)&Kl[buf][srow][scol]      = bK0;
        *(bf16x8*)&Kl[buf][32 + srow][scol] = bK1;
        *(bf16x8*)&Vl[buf][srow][scol]      = bV0;
        *(bf16x8*)&Vl[buf][32 + srow][scol] = bV1;
    };

    auto loadKf = [&](int cur) {
#pragma unroll
        for (int ni = 0; ni < 4; ni++)
#pragma unroll
            for (int c = 0; c < 2; c++)
                kf[ni][c] = *(const bf16x8*)&Kl[cur][ni * 16 + q15][c * 32 + g * 8];
    };
    auto loadVf = [&](int cur) {
#pragma unroll
        for (int ni = 0; ni < 4; ni++)
#pragma unroll
            for (int c = 0; c < 2; c++)
                vf[ni][c] = *(const bf16x8*)&Vl[cur][ni * 16 + q15][c * 32 + g * 8];
    };
    auto qk = [&](bf16x8 qa, bf16x8 qb) {
        f32x4 s[4];
#pragma unroll
        for (int ni = 0; ni < 4; ni++) {
            s[ni] = mfma16(kf[ni][0], qa, f32x4{0.f, 0.f, 0.f, 0.f});
            s[ni] = mfma16(kf[ni][1], qb, s[ni]);
        }
#pragma unroll
        for (int ni = 0; ni < 4; ni++) {
            bf16x4 p4;
#pragma unroll
            for (int r = 0; r < 4; r++) { float v = s[ni][r]; p4[r] = (bf16)(v * v); }
            *(bf16x4*)&Pw[q15][ni * 16 + g * 4] = p4;
        }
    };
    auto pv = [&](f32x4 (&o)[4]) {
        bf16x8 pf0 = *(const bf16x8*)&Pw[q15][g * 8];
        bf16x8 pf1 = *(const bf16x8*)&Pw[q15][32 + g * 8];
#pragma unroll
        for (int ni = 0; ni < 4; ni++) {
            o[ni] = mfma16(pf0, vf[ni][0], o[ni]);
            o[ni] = mfma16(pf1, vf[ni][1], o[ni]);
        }
    };

    // prologue: tile 0 (slot 0), tile1 regs in B, tile2 gload into A
    gloadA(0);
    stageA(0);
    gloadB(64);
    wait_lgkm0(); __builtin_amdgcn_s_barrier();
    stageB(1);                       // tile1 -> slot1 (disjoint from slot0 reads)
    gloadA(2 * 64);                  // tile2 -> regs A
    loadKf(0); qk(qf00, qf01);       // tile0 h0
    loadVf(0); pv(o0);               // tile0 h0 PV
    qk(qf10, qf11);                  // tile0 h1

    // main pairs: t = 1,3,...,13 covering tiles 1..14
    for (int t = 1; t <= NT - 3; t += 2) {
        // ---- iter t (odd tile, slot 1) ----
        pv(o1);                               // pv(t-1, h1)  [vf = tile t-1 regs]
        wait_lgkm0(); __builtin_amdgcn_s_barrier();
        stageA(0);                            // tile t+1 (even) -> slot 0
        gloadB((t + 2) * 64);                 // tile t+2 (odd)
        loadKf(1); qk(qf00, qf01);            // tile t h0
        loadVf(1); pv(o0);                    // tile t h0 PV
        qk(qf10, qf11);                       // tile t h1
        // ---- iter t+1 (even tile, slot 0) ----
        pv(o1);                               // pv(t, h1)
        wait_lgkm0(); __builtin_amdgcn_s_barrier();
        stageB(1);                            // tile t+2 -> slot 1
        if (t + 3 < NT) gloadA((t + 3) * 64); // tile t+3 (even)
        loadKf(0); qk(qf00, qf01);            // tile t+1 h0
        loadVf(0); pv(o0);                    // tile t+1 h0 PV
        qk(qf10, qf11);                       // tile t+1 h1
    }
    // peeled iter t = 15 (odd, slot 1; staged at iter 14)
    pv(o1);                                   // pv(14, h1)
    wait_lgkm0(); __builtin_amdgcn_s_barrier();
    loadKf(1); qk(qf00, qf01);
    loadVf(1); pv(o0);
    qk(qf10, qf11);
    pv(o1);                                   // pv(15, h1)

    const int b = bh / 12, h = bh % 12;
#pragma unroll
    for (int ni = 0; ni < 4; ni++)
#pragma unroll
        for (int r = 0; r < 4; r++) {
            const int s0r = qbase + g * 4 + r;
            AOo[((long)b * S_ + s0r) * D_ + h * 64 + ni * 16 + q15] = (bf16)o0[ni][r];
            const int s1r = qbase + 16 + g * 4 + r;
            AOo[((long)b * S_ + s1r) * D_ + h * 64 + ni * 16 + q15] = (bf16)o1[ni][r];
        }
}

extern "C" void kernel_launch(void* const* d_in, const int* in_sizes, int n_in,
                              void* d_out, int out_size, void* d_ws, size_t ws_size,
                              hipStream_t stream) {
    const float* x     = (const float*)d_in[0];
    const float* Wq    = (const float*)d_in[1];
    const float* bq    = (const float*)d_in[2];
    const float* Wk    = (const float*)d_in[3];
    const float* bk    = (const float*)d_in[4];
    const float* Wv    = (const float*)d_in[5];
    const float* bv    = (const float*)d_in[6];
    const float* Wo    = (const float*)d_in[7];
    const float* bo    = (const float*)d_in[8];
    const float* W1    = (const float*)d_in[9];
    const float* b1    = (const float*)d_in[10];
    const float* W2    = (const float*)d_in[11];
    const float* b2    = (const float*)d_in[12];
    const float* gamma = (const float*)d_in[13];
    const float* beta  = (const float*)d_in[14];

    char* p = (char*)d_ws;
    auto alloc = [&](size_t bytes) -> void* {
        void* r = p;
        p += (bytes + 255) & ~(size_t)255;
        return r;
    };
    bf16*  Xb    = (bf16*)alloc((size_t)M_ * D_ * 2);
    bf16*  Wqkvt = (bf16*)alloc((size_t)2304 * 768 * 2);
    bf16*  Wot   = (bf16*)alloc((size_t)768 * 768 * 2);
    bf16*  W1t   = (bf16*)alloc((size_t)3072 * 768 * 2);
    bf16*  W2t   = (bf16*)alloc((size_t)768 * 3072 * 2);
    bf16*  Qh    = (bf16*)alloc((size_t)BH_ * S_ * 64 * 2);
    bf16*  Kh    = (bf16*)alloc((size_t)BH_ * S_ * 64 * 2);
    bf16*  Vt    = (bf16*)alloc((size_t)BH_ * S_ * 64 * 2);
    bf16*  AOp   = (bf16*)alloc((size_t)2 * M_ * D_ * 2);  // attn partials
    bf16*  AO    = (bf16*)alloc((size_t)M_ * D_ * 2);
    bf16*  pp    = (bf16*)alloc((size_t)2 * M_ * 768 * 2); // GEMM K-split partials
    bf16*  x1b   = (bf16*)alloc((size_t)M_ * D_ * 2);
    bf16*  hbuf  = (bf16*)alloc((size_t)M_ * DFF_ * 2);

    pack_x_kernel<<<(M_ * D_) / 1024, 256, 0, stream>>>(x, Xb);
    wt_all_kernel<<<1728, 256, 0, stream>>>(Wq, Wk, Wv, Wo, W1, W2,
                                            Wqkvt, Wot, W1t, W2t);

    // QKV: 64x128 tiles -> 1152 blocks (48KB LDS, 3/CU)
    gemm_bt<0, 768, 64, 128, 2, 2, 1><<<64 * 18, 256, 0, stream>>>(
        Xb, Wqkvt, bq, bk, bv, nullptr, Qh, Kh, Vt);

    // attention: 768 blocks, split-K over keys, then merge
    attn_kernel<<<2 * 16 * BH_, 256, 0, stream>>>(Qh, Kh, Vt, AOp);
    merge_ao_kernel<<<(M_ * D_) / 2048, 256, 0, stream>>>(
        AOp, AOp + (size_t)M_ * D_, AO);

    // Wo: 64x128 tiles + K-split x2 -> 768 blocks; merge + bias + resid + LN1
    gemm_bt<1, 768, 64, 128, 2, 2, 2><<<64 * 6 * 2, 256, 0, stream>>>(
        AO, Wot, nullptr, nullptr, nullptr, pp, nullptr, nullptr, nullptr);
    merge_ln_kernel<true><<<M_, 256, 0, stream>>>(
        pp, bo, x, nullptr, gamma, beta, nullptr, x1b);

    // FFN1: 64x128 tiles -> 1536 blocks
    gemm_bt<2, 768, 64, 128, 2, 2, 1><<<64 * 24, 256, 0, stream>>>(
        x1b, W1t, b1, nullptr, nullptr, hbuf, nullptr, nullptr, nullptr);

    // FFN2: 64x128 tiles + K-split x2 -> 768 blocks; merge + bias + resid + LN2
    gemm_bt<3, 3072, 64, 128, 2, 2, 2><<<64 * 6 * 2, 256, 0, stream>>>(
        hbuf, W2t, nullptr, nullptr, nullptr, pp, nullptr, nullptr, nullptr);
    merge_ln_kernel<false><<<M_, 256, 0, stream>>>(
        pp, b2, nullptr, x1b, gamma, beta, (float*)d_out, nullptr);
}